// Round 1
// baseline (967.652 us; speedup 1.0000x reference)
//
#include <hip/hip_runtime.h>
#include <math.h>

#define NN 50000
#define NE 800000
#define FD 128
#define CIN 256
#define NCLS 16

__device__ __forceinline__ float sigmoidf_(float x) {
  return 1.0f / (1.0f + expf(-x));
}

// ---------------- small prep kernels ----------------

__global__ void k_wsum(const float* __restrict__ a0, const float* __restrict__ a1,
                       const float* __restrict__ b0, const float* __restrict__ b1,
                       const float* __restrict__ c0, const float* __restrict__ c1,
                       float* __restrict__ A, float* __restrict__ B, float* __restrict__ C) {
  int i = blockIdx.x * blockDim.x + threadIdx.x;
  if (i < CIN * FD) {
    A[i] = a0[i] + a1[i];
    B[i] = b0[i] + b1[i];
    C[i] = c0[i] + c1[i];
  }
}

__global__ void k_deg_init(float* __restrict__ deg) {
  int i = blockIdx.x * blockDim.x + threadIdx.x;
  if (i < NN) deg[i] = 1.0f;  // self-loop weight
}

__global__ void k_deg(const int* __restrict__ dst, const float* __restrict__ ew,
                      float* __restrict__ deg) {
  int i = blockIdx.x * blockDim.x + threadIdx.x;
  int stride = gridDim.x * blockDim.x;
  for (int e = i; e < NE; e += stride) atomicAdd(&deg[dst[e]], ew[e]);
}

__global__ void k_dinv(float* __restrict__ deg) {
  int i = blockIdx.x * blockDim.x + threadIdx.x;
  if (i < NN) deg[i] = rsqrtf(deg[i]);  // deg >= 1 always
}

// ---------------- xw = x @ Wg ; agg = xw * dinv^2 (self loop) ----------------
// 64 nodes x 128 outs per block, 256 thr, thread tile 4 nodes x 8 outs
// out cols for thread: c = tc*4 + q*64, q in {0,1}

__global__ __launch_bounds__(256) void k_gemm_xw(
    const float* __restrict__ x, const float* __restrict__ Wg,
    const float* __restrict__ dinv, float* __restrict__ xw, float* __restrict__ agg) {
  __shared__ float As[64][33];
  __shared__ float Ws[32][FD];
  const int tid = threadIdx.x;
  const int n0 = blockIdx.x * 64;
  const int tr = tid >> 4, tc = tid & 15;

  float acc[4][8];
#pragma unroll
  for (int i = 0; i < 4; ++i)
#pragma unroll
    for (int j = 0; j < 8; ++j) acc[i][j] = 0.f;

  for (int kc = 0; kc < FD; kc += 32) {
#pragma unroll
    for (int l = 0; l < 2; ++l) {
      int idx = tid + l * 256;         // 512 float4 units: 64 rows x 8
      int row = idx >> 3;
      int col = (idx & 7) << 2;
      float4 v = make_float4(0.f, 0.f, 0.f, 0.f);
      int n = n0 + row;
      if (n < NN) v = *(const float4*)(x + n * FD + kc + col);
      As[row][col] = v.x; As[row][col + 1] = v.y;
      As[row][col + 2] = v.z; As[row][col + 3] = v.w;
    }
#pragma unroll
    for (int l = 0; l < 4; ++l) {
      int idx = tid + l * 256;         // 1024 float4: 32 rows x 32
      int row = idx >> 5;
      int col = (idx & 31) << 2;
      *(float4*)(&Ws[row][col]) = *(const float4*)(Wg + (kc + row) * FD + col);
    }
    __syncthreads();
#pragma unroll 4
    for (int k = 0; k < 32; ++k) {
      float4 w0 = *(const float4*)&Ws[k][tc * 4];
      float4 w1 = *(const float4*)&Ws[k][tc * 4 + 64];
#pragma unroll
      for (int i = 0; i < 4; ++i) {
        float a = As[tr * 4 + i][k];
        acc[i][0] += a * w0.x; acc[i][1] += a * w0.y;
        acc[i][2] += a * w0.z; acc[i][3] += a * w0.w;
        acc[i][4] += a * w1.x; acc[i][5] += a * w1.y;
        acc[i][6] += a * w1.z; acc[i][7] += a * w1.w;
      }
    }
    __syncthreads();
  }
#pragma unroll
  for (int i = 0; i < 4; ++i) {
    int n = n0 + tr * 4 + i;
    if (n >= NN) continue;
    float di = dinv[n], d2 = di * di;
#pragma unroll
    for (int q = 0; q < 2; ++q) {
      int c = tc * 4 + q * 64;
      float4 v = make_float4(acc[i][q * 4], acc[i][q * 4 + 1], acc[i][q * 4 + 2], acc[i][q * 4 + 3]);
      *(float4*)(xw + n * FD + c) = v;
      float4 g = make_float4(v.x * d2, v.y * d2, v.z * d2, v.w * d2);
      *(float4*)(agg + n * FD + c) = g;
    }
  }
}

// ---------------- edge scatter: agg[dst] += norm * xw[src] ----------------
// one wave per edge iteration; lane handles 2 features

__global__ __launch_bounds__(256) void k_scatter(
    const int* __restrict__ ei, const float* __restrict__ ew,
    const float* __restrict__ dinv, const float* __restrict__ xw,
    float* __restrict__ agg) {
  const int lane = threadIdx.x & 63;
  const int wid = blockIdx.x * (blockDim.x >> 6) + (threadIdx.x >> 6);
  const int nw = gridDim.x * (blockDim.x >> 6);
  const int* __restrict__ src = ei;
  const int* __restrict__ dst = ei + NE;
  for (int e = wid; e < NE; e += nw) {
    int s = src[e], d = dst[e];
    float nrm = dinv[s] * ew[e] * dinv[d];
    float2 v = *(const float2*)(xw + s * FD + lane * 2);
    atomicAdd(agg + d * FD + lane * 2, nrm * v.x);
    atomicAdd(agg + d * FD + lane * 2 + 1, nrm * v.y);
  }
}

// ---------------- ZR gates: [h|Hs] @ [Wz|Wr], sigmoid; write Z, hsr=Hs*R ----
// 64 nodes x 256 outs, thread tile 4 x 16; out cols c = tc*4 + q*64, q 0..3

__global__ __launch_bounds__(256) void k_zr(
    const float* __restrict__ agg, const float* __restrict__ bg,
    const float* __restrict__ hs,
    const float* __restrict__ Wz, const float* __restrict__ Wr,
    const float* __restrict__ bz, const float* __restrict__ br,
    float* __restrict__ Zb, float* __restrict__ hsr) {
  __shared__ float As[64][33];
  __shared__ float Ws[32][CIN];
  const int tid = threadIdx.x;
  const int n0 = blockIdx.x * 64;
  const int tr = tid >> 4, tc = tid & 15;

  float acc[4][16];
#pragma unroll
  for (int i = 0; i < 4; ++i)
#pragma unroll
    for (int j = 0; j < 16; ++j) acc[i][j] = 0.f;

  for (int kc = 0; kc < CIN; kc += 32) {
#pragma unroll
    for (int l = 0; l < 2; ++l) {
      int idx = tid + l * 256;
      int row = idx >> 3;
      int col = (idx & 7) << 2;
      int n = n0 + row;
      float4 v = make_float4(0.f, 0.f, 0.f, 0.f);
      if (n < NN) {
        if (kc < FD) {
          float4 a4 = *(const float4*)(agg + n * FD + kc + col);
          float4 b4 = *(const float4*)(bg + kc + col);
          v = make_float4(a4.x + b4.x, a4.y + b4.y, a4.z + b4.z, a4.w + b4.w);
        } else {
          v = *(const float4*)(hs + n * FD + (kc - FD) + col);
        }
      }
      As[row][col] = v.x; As[row][col + 1] = v.y;
      As[row][col + 2] = v.z; As[row][col + 3] = v.w;
    }
#pragma unroll
    for (int l = 0; l < 8; ++l) {
      int idx = tid + l * 256;        // 2048 float4: 32 rows x 64
      int row = idx >> 6;
      int col = (idx & 63) << 2;
      const float* srcp = (col < FD) ? (Wz + (kc + row) * FD + col)
                                     : (Wr + (kc + row) * FD + (col - FD));
      *(float4*)(&Ws[row][col]) = *(const float4*)srcp;
    }
    __syncthreads();
#pragma unroll 4
    for (int k = 0; k < 32; ++k) {
      float4 w0 = *(const float4*)&Ws[k][tc * 4];
      float4 w1 = *(const float4*)&Ws[k][tc * 4 + 64];
      float4 w2 = *(const float4*)&Ws[k][tc * 4 + 128];
      float4 w3 = *(const float4*)&Ws[k][tc * 4 + 192];
#pragma unroll
      for (int i = 0; i < 4; ++i) {
        float a = As[tr * 4 + i][k];
        acc[i][0] += a * w0.x;  acc[i][1] += a * w0.y;
        acc[i][2] += a * w0.z;  acc[i][3] += a * w0.w;
        acc[i][4] += a * w1.x;  acc[i][5] += a * w1.y;
        acc[i][6] += a * w1.z;  acc[i][7] += a * w1.w;
        acc[i][8] += a * w2.x;  acc[i][9] += a * w2.y;
        acc[i][10] += a * w2.z; acc[i][11] += a * w2.w;
        acc[i][12] += a * w3.x; acc[i][13] += a * w3.y;
        acc[i][14] += a * w3.z; acc[i][15] += a * w3.w;
      }
    }
    __syncthreads();
  }
#pragma unroll
  for (int i = 0; i < 4; ++i) {
    int n = n0 + tr * 4 + i;
    if (n >= NN) continue;
#pragma unroll
    for (int q = 0; q < 4; ++q) {
      int c = tc * 4 + q * 64;
      if (c < FD) {
        float4 o;
        o.x = sigmoidf_(acc[i][q * 4 + 0] + bz[c + 0]);
        o.y = sigmoidf_(acc[i][q * 4 + 1] + bz[c + 1]);
        o.z = sigmoidf_(acc[i][q * 4 + 2] + bz[c + 2]);
        o.w = sigmoidf_(acc[i][q * 4 + 3] + bz[c + 3]);
        *(float4*)(Zb + n * FD + c) = o;
      } else {
        int cc = c - FD;
        float4 hv = *(const float4*)(hs + n * FD + cc);
        float4 o;
        o.x = sigmoidf_(acc[i][q * 4 + 0] + br[cc + 0]) * hv.x;
        o.y = sigmoidf_(acc[i][q * 4 + 1] + br[cc + 1]) * hv.y;
        o.z = sigmoidf_(acc[i][q * 4 + 2] + br[cc + 2]) * hv.z;
        o.w = sigmoidf_(acc[i][q * 4 + 3] + br[cc + 3]) * hv.w;
        *(float4*)(hsr + n * FD + cc) = o;
      }
    }
  }
}

// ---------------- Ht GEMM + Hn + classifier + softmax ----------------

__global__ __launch_bounds__(256) void k_ht(
    const float* __restrict__ agg, const float* __restrict__ bg,
    const float* __restrict__ hsr, const float* __restrict__ Wh,
    const float* __restrict__ bh, const float* __restrict__ Zb,
    const float* __restrict__ hs, const float* __restrict__ Wl,
    const float* __restrict__ bl, float* __restrict__ probs,
    float* __restrict__ Hn) {
  __shared__ __align__(16) char smem[45568];
  float (*As)[33] = (float(*)[33])smem;                 // [64][33]  @0     (GEMM phase)
  float (*Ws)[FD] = (float(*)[FD])(smem + 8448);        // [32][128] @8448  (GEMM phase)
  float (*HnS)[129] = (float(*)[129])smem;              // [64][129] @0     (post phase)
  float (*lg)[17] = (float(*)[17])(smem + 33024);       // [64][17]  @33024 (post phase)
  float (*WlS)[NCLS] = (float(*)[NCLS])(smem + 37376);  // [128][16] @37376 (persistent)

  const int tid = threadIdx.x;
  const int n0 = blockIdx.x * 64;
  const int tr = tid >> 4, tc = tid & 15;

  // stage Wl once (read only after later barriers)
#pragma unroll
  for (int l = 0; l < 2; ++l) {
    int idx = tid + l * 256;  // 512 float4 = 2048 floats
    ((float4*)WlS)[idx] = ((const float4*)Wl)[idx];
  }

  float acc[4][8];
#pragma unroll
  for (int i = 0; i < 4; ++i)
#pragma unroll
    for (int j = 0; j < 8; ++j) acc[i][j] = 0.f;

  for (int kc = 0; kc < CIN; kc += 32) {
#pragma unroll
    for (int l = 0; l < 2; ++l) {
      int idx = tid + l * 256;
      int row = idx >> 3;
      int col = (idx & 7) << 2;
      int n = n0 + row;
      float4 v = make_float4(0.f, 0.f, 0.f, 0.f);
      if (n < NN) {
        if (kc < FD) {
          float4 a4 = *(const float4*)(agg + n * FD + kc + col);
          float4 b4 = *(const float4*)(bg + kc + col);
          v = make_float4(a4.x + b4.x, a4.y + b4.y, a4.z + b4.z, a4.w + b4.w);
        } else {
          v = *(const float4*)(hsr + n * FD + (kc - FD) + col);
        }
      }
      As[row][col] = v.x; As[row][col + 1] = v.y;
      As[row][col + 2] = v.z; As[row][col + 3] = v.w;
    }
#pragma unroll
    for (int l = 0; l < 4; ++l) {
      int idx = tid + l * 256;
      int row = idx >> 5;
      int col = (idx & 31) << 2;
      *(float4*)(&Ws[row][col]) = *(const float4*)(Wh + (kc + row) * FD + col);
    }
    __syncthreads();
#pragma unroll 4
    for (int k = 0; k < 32; ++k) {
      float4 w0 = *(const float4*)&Ws[k][tc * 4];
      float4 w1 = *(const float4*)&Ws[k][tc * 4 + 64];
#pragma unroll
      for (int i = 0; i < 4; ++i) {
        float a = As[tr * 4 + i][k];
        acc[i][0] += a * w0.x; acc[i][1] += a * w0.y;
        acc[i][2] += a * w0.z; acc[i][3] += a * w0.w;
        acc[i][4] += a * w1.x; acc[i][5] += a * w1.y;
        acc[i][6] += a * w1.z; acc[i][7] += a * w1.w;
      }
    }
    __syncthreads();   // also protects the As/Ws -> HnS overlap
  }

  // Hn epilogue
#pragma unroll
  for (int i = 0; i < 4; ++i) {
    int lr = tr * 4 + i;
    int n = n0 + lr;
    if (n < NN) {
#pragma unroll
      for (int q = 0; q < 2; ++q) {
        int c = tc * 4 + q * 64;
        float4 z4 = *(const float4*)(Zb + n * FD + c);
        float4 h4 = *(const float4*)(hs + n * FD + c);
        float4 o;
        o.x = z4.x * h4.x + (1.f - z4.x) * tanhf(acc[i][q * 4 + 0] + bh[c + 0]);
        o.y = z4.y * h4.y + (1.f - z4.y) * tanhf(acc[i][q * 4 + 1] + bh[c + 1]);
        o.z = z4.z * h4.z + (1.f - z4.z) * tanhf(acc[i][q * 4 + 2] + bh[c + 2]);
        o.w = z4.w * h4.w + (1.f - z4.w) * tanhf(acc[i][q * 4 + 3] + bh[c + 3]);
        *(float4*)(Hn + n * FD + c) = o;
        HnS[lr][c + 0] = o.x; HnS[lr][c + 1] = o.y;
        HnS[lr][c + 2] = o.z; HnS[lr][c + 3] = o.w;
      }
    } else {
#pragma unroll
      for (int q = 0; q < 2; ++q) {
        int c = tc * 4 + q * 64;
        HnS[lr][c + 0] = 0.f; HnS[lr][c + 1] = 0.f;
        HnS[lr][c + 2] = 0.f; HnS[lr][c + 3] = 0.f;
      }
    }
  }
  __syncthreads();

  // logits: 64 nodes x 16 classes; thread -> (node tid>>2, 4 classes)
  {
    int nl = tid >> 2;
    int cq = (tid & 3) << 2;
    float l0 = bl[cq + 0], l1 = bl[cq + 1], l2 = bl[cq + 2], l3 = bl[cq + 3];
#pragma unroll 8
    for (int k = 0; k < FD; ++k) {
      float hv = fmaxf(HnS[nl][k], 0.f);
      float4 wv = *(const float4*)&WlS[k][cq];
      l0 += hv * wv.x; l1 += hv * wv.y; l2 += hv * wv.z; l3 += hv * wv.w;
    }
    lg[nl][cq + 0] = l0; lg[nl][cq + 1] = l1;
    lg[nl][cq + 2] = l2; lg[nl][cq + 3] = l3;
  }
  __syncthreads();

  if (tid < 64) {
    int n = n0 + tid;
    if (n < NN) {
      float m = lg[tid][0];
#pragma unroll
      for (int j = 1; j < NCLS; ++j) m = fmaxf(m, lg[tid][j]);
      float e[NCLS];
      float s = 0.f;
#pragma unroll
      for (int j = 0; j < NCLS; ++j) { e[j] = expf(lg[tid][j] - m); s += e[j]; }
      float inv = 1.f / s;
#pragma unroll
      for (int q = 0; q < 4; ++q) {
        float4 o = make_float4(e[q * 4] * inv, e[q * 4 + 1] * inv,
                               e[q * 4 + 2] * inv, e[q * 4 + 3] * inv);
        *(float4*)(probs + n * NCLS + q * 4) = o;
      }
    }
  }
}

// ---------------- launch ----------------

extern "C" void kernel_launch(void* const* d_in, const int* in_sizes, int n_in,
                              void* d_out, int out_size, void* d_ws, size_t ws_size,
                              hipStream_t stream) {
  (void)in_sizes; (void)n_in; (void)out_size; (void)ws_size;
  const float* x   = (const float*)d_in[0];
  const int*   ei  = (const int*)d_in[1];
  const float* ew  = (const float*)d_in[2];
  const float* hs  = (const float*)d_in[3];
  const float* Wg  = (const float*)d_in[4];
  const float* bg  = (const float*)d_in[5];
  const float* Wz0 = (const float*)d_in[6];
  const float* Wz1 = (const float*)d_in[7];
  const float* bz  = (const float*)d_in[8];
  const float* Wr0 = (const float*)d_in[9];
  const float* Wr1 = (const float*)d_in[10];
  const float* br  = (const float*)d_in[11];
  const float* Wh0 = (const float*)d_in[12];
  const float* Wh1 = (const float*)d_in[13];
  const float* bh  = (const float*)d_in[14];
  const float* Wl  = (const float*)d_in[15];
  const float* bl  = (const float*)d_in[16];

  float* out   = (float*)d_out;
  float* probs = out;                 // [NN,16]
  float* Hn    = out + (size_t)NN * NCLS;  // [NN,128]

  float* w    = (float*)d_ws;
  float* dinv = w;                            // [NN] (deg then dinv in place)
  float* xw   = w + 50048;                    // [NN*FD]; reused as Zb after scatter
  float* agg  = xw + (size_t)NN * FD;         // [NN*FD]
  float* hsr  = agg + (size_t)NN * FD;        // [NN*FD]
  float* Wz   = hsr + (size_t)NN * FD;        // [CIN*FD]
  float* Wr   = Wz + CIN * FD;
  float* Wh   = Wr + CIN * FD;
  float* Zb   = xw;

  k_wsum<<<128, 256, 0, stream>>>(Wz0, Wz1, Wr0, Wr1, Wh0, Wh1, Wz, Wr, Wh);
  k_deg_init<<<196, 256, 0, stream>>>(dinv);
  k_deg<<<1024, 256, 0, stream>>>(ei + NE, ew, dinv);
  k_dinv<<<196, 256, 0, stream>>>(dinv);
  k_gemm_xw<<<782, 256, 0, stream>>>(x, Wg, dinv, xw, agg);
  k_scatter<<<2048, 256, 0, stream>>>(ei, ew, dinv, xw, agg);
  k_zr<<<782, 256, 0, stream>>>(agg, bg, hs, Wz, Wr, bz, br, Zb, hsr);
  k_ht<<<782, 256, 0, stream>>>(agg, bg, hsr, Wh, bh, Zb, hs, Wl, bl, probs, Hn);
}

// Round 4
// 519.237 us; speedup vs baseline: 1.8636x; 1.8636x over previous
//
#include <hip/hip_runtime.h>
#include <math.h>

#define NN 50000
#define NE 800000
#define FD 128
#define CIN 256
#define NCLS 16

__device__ __forceinline__ float sigmoidf_(float x) {
  return 1.0f / (1.0f + expf(-x));
}

// ---------------- small prep kernels ----------------

__global__ void k_wsum(const float* __restrict__ a0, const float* __restrict__ a1,
                       const float* __restrict__ b0, const float* __restrict__ b1,
                       const float* __restrict__ c0, const float* __restrict__ c1,
                       float* __restrict__ A, float* __restrict__ B, float* __restrict__ C) {
  int i = blockIdx.x * blockDim.x + threadIdx.x;
  if (i < CIN * FD) {
    A[i] = a0[i] + a1[i];
    B[i] = b0[i] + b1[i];
    C[i] = c0[i] + c1[i];
  }
}

// deg = 1 (self loop), cnt = 0, fill = 0
__global__ void k_init(float* __restrict__ deg, int* __restrict__ cnt,
                       int* __restrict__ fill) {
  int i = blockIdx.x * blockDim.x + threadIdx.x;
  if (i < NN) { deg[i] = 1.0f; cnt[i] = 0; fill[i] = 0; }
}

__global__ void k_deg_hist(const int* __restrict__ dst, const float* __restrict__ ew,
                           float* __restrict__ deg, int* __restrict__ cnt) {
  int i = blockIdx.x * blockDim.x + threadIdx.x;
  int stride = gridDim.x * blockDim.x;
  for (int e = i; e < NE; e += stride) {
    int d = dst[e];
    atomicAdd(&deg[d], ew[e]);
    atomicAdd(&cnt[d], 1);
  }
}

__global__ void k_dinv(float* __restrict__ deg) {
  int i = blockIdx.x * blockDim.x + threadIdx.x;
  if (i < NN) deg[i] = rsqrtf(deg[i]);  // deg >= 1 always
}

// exclusive prefix sum of cnt[NN] -> base[NN+1], single block 1024 threads
__global__ __launch_bounds__(1024) void k_scan(const int* __restrict__ cnt,
                                               int* __restrict__ base) {
  __shared__ int ts[1024];
  const int tid = threadIdx.x;
  const int per = (NN + 1023) / 1024;  // 49
  int s0 = tid * per;
  int s1 = s0 + per; if (s1 > NN) s1 = NN;
  int sum = 0;
  for (int i = s0; i < s1; ++i) sum += cnt[i];
  ts[tid] = sum;
  __syncthreads();
  for (int off = 1; off < 1024; off <<= 1) {
    int v = (tid >= off) ? ts[tid - off] : 0;
    __syncthreads();
    ts[tid] += v;
    __syncthreads();
  }
  int run = (tid == 0) ? 0 : ts[tid - 1];
  for (int i = s0; i < s1; ++i) { base[i] = run; run += cnt[i]; }
  if (tid == 1023) base[NN] = run;  // == NE
}

// scatter edges into dst-sorted order; precompute per-edge norm
__global__ void k_reorder(const int* __restrict__ ei, const float* __restrict__ ew,
                          const float* __restrict__ dinv, const int* __restrict__ base,
                          int* __restrict__ fill, int* __restrict__ src_s,
                          float* __restrict__ nrm_s) {
  int i = blockIdx.x * blockDim.x + threadIdx.x;
  int stride = gridDim.x * blockDim.x;
  const int* __restrict__ src = ei;
  const int* __restrict__ dst = ei + NE;
  for (int e = i; e < NE; e += stride) {
    int s = src[e], d = dst[e];
    int pos = base[d] + atomicAdd(&fill[d], 1);
    src_s[pos] = s;
    nrm_s[pos] = dinv[s] * ew[e] * dinv[d];
  }
}

// ---------------- xw = x @ Wg ; agg = xw * dinv^2 (self loop) ----------------
// 64 nodes x 128 outs per block, 256 thr, thread tile 4 nodes x 8 outs

__global__ __launch_bounds__(256) void k_gemm_xw(
    const float* __restrict__ x, const float* __restrict__ Wg,
    const float* __restrict__ dinv, float* __restrict__ xw, float* __restrict__ agg) {
  __shared__ float As[64][33];
  __shared__ float Ws[32][FD];
  const int tid = threadIdx.x;
  const int n0 = blockIdx.x * 64;
  const int tr = tid >> 4, tc = tid & 15;

  float acc[4][8];
#pragma unroll
  for (int i = 0; i < 4; ++i)
#pragma unroll
    for (int j = 0; j < 8; ++j) acc[i][j] = 0.f;

  for (int kc = 0; kc < FD; kc += 32) {
#pragma unroll
    for (int l = 0; l < 2; ++l) {
      int idx = tid + l * 256;         // 512 float4 units: 64 rows x 8
      int row = idx >> 3;
      int col = (idx & 7) << 2;
      float4 v = make_float4(0.f, 0.f, 0.f, 0.f);
      int n = n0 + row;
      if (n < NN) v = *(const float4*)(x + n * FD + kc + col);
      As[row][col] = v.x; As[row][col + 1] = v.y;
      As[row][col + 2] = v.z; As[row][col + 3] = v.w;
    }
#pragma unroll
    for (int l = 0; l < 4; ++l) {
      int idx = tid + l * 256;         // 1024 float4: 32 rows x 32
      int row = idx >> 5;
      int col = (idx & 31) << 2;
      *(float4*)(&Ws[row][col]) = *(const float4*)(Wg + (kc + row) * FD + col);
    }
    __syncthreads();
#pragma unroll 4
    for (int k = 0; k < 32; ++k) {
      float4 w0 = *(const float4*)&Ws[k][tc * 4];
      float4 w1 = *(const float4*)&Ws[k][tc * 4 + 64];
#pragma unroll
      for (int i = 0; i < 4; ++i) {
        float a = As[tr * 4 + i][k];
        acc[i][0] += a * w0.x; acc[i][1] += a * w0.y;
        acc[i][2] += a * w0.z; acc[i][3] += a * w0.w;
        acc[i][4] += a * w1.x; acc[i][5] += a * w1.y;
        acc[i][6] += a * w1.z; acc[i][7] += a * w1.w;
      }
    }
    __syncthreads();
  }
#pragma unroll
  for (int i = 0; i < 4; ++i) {
    int n = n0 + tr * 4 + i;
    if (n >= NN) continue;
    float di = dinv[n], d2 = di * di;
#pragma unroll
    for (int q = 0; q < 2; ++q) {
      int c = tc * 4 + q * 64;
      float4 v = make_float4(acc[i][q * 4], acc[i][q * 4 + 1], acc[i][q * 4 + 2], acc[i][q * 4 + 3]);
      *(float4*)(xw + n * FD + c) = v;
      float4 g = make_float4(v.x * d2, v.y * d2, v.z * d2, v.w * d2);
      *(float4*)(agg + n * FD + c) = g;
    }
  }
}

// ---------------- CSR gather: agg[n] += sum_e nrm_s[e] * xw[src_s[e]] ------
// one wave per node, 2 features per lane, no atomics

__global__ __launch_bounds__(256) void k_gather(
    const int* __restrict__ base, const int* __restrict__ src_s,
    const float* __restrict__ nrm_s, const float* __restrict__ xw,
    float* __restrict__ agg) {
  const int lane = threadIdx.x & 63;
  const int n = blockIdx.x * 4 + (threadIdx.x >> 6);
  if (n >= NN) return;
  const int e0 = base[n], e1 = base[n + 1];
  const int c = lane * 2;
  float* ap = agg + (size_t)n * FD + c;
  float2 acc = *(const float2*)ap;
  int e = e0;
  for (; e + 4 <= e1; e += 4) {
    int s0 = src_s[e], s1 = src_s[e + 1], s2 = src_s[e + 2], s3 = src_s[e + 3];
    float w0 = nrm_s[e], w1 = nrm_s[e + 1], w2 = nrm_s[e + 2], w3 = nrm_s[e + 3];
    float2 v0 = *(const float2*)(xw + (size_t)s0 * FD + c);
    float2 v1 = *(const float2*)(xw + (size_t)s1 * FD + c);
    float2 v2 = *(const float2*)(xw + (size_t)s2 * FD + c);
    float2 v3 = *(const float2*)(xw + (size_t)s3 * FD + c);
    acc.x = fmaf(w0, v0.x, acc.x); acc.y = fmaf(w0, v0.y, acc.y);
    acc.x = fmaf(w1, v1.x, acc.x); acc.y = fmaf(w1, v1.y, acc.y);
    acc.x = fmaf(w2, v2.x, acc.x); acc.y = fmaf(w2, v2.y, acc.y);
    acc.x = fmaf(w3, v3.x, acc.x); acc.y = fmaf(w3, v3.y, acc.y);
  }
  for (; e < e1; ++e) {
    int s = src_s[e];
    float wv = nrm_s[e];
    float2 v = *(const float2*)(xw + (size_t)s * FD + c);
    acc.x = fmaf(wv, v.x, acc.x); acc.y = fmaf(wv, v.y, acc.y);
  }
  *(float2*)ap = acc;
}

// ---------------- ZR gates: [h|Hs] @ [Wz|Wr], sigmoid; write Z, hsr=Hs*R ----

__global__ __launch_bounds__(256) void k_zr(
    const float* __restrict__ agg, const float* __restrict__ bg,
    const float* __restrict__ hs,
    const float* __restrict__ Wz, const float* __restrict__ Wr,
    const float* __restrict__ bz, const float* __restrict__ br,
    float* __restrict__ Zb, float* __restrict__ hsr) {
  __shared__ float As[64][33];
  __shared__ float Ws[32][CIN];
  const int tid = threadIdx.x;
  const int n0 = blockIdx.x * 64;
  const int tr = tid >> 4, tc = tid & 15;

  float acc[4][16];
#pragma unroll
  for (int i = 0; i < 4; ++i)
#pragma unroll
    for (int j = 0; j < 16; ++j) acc[i][j] = 0.f;

  for (int kc = 0; kc < CIN; kc += 32) {
#pragma unroll
    for (int l = 0; l < 2; ++l) {
      int idx = tid + l * 256;
      int row = idx >> 3;
      int col = (idx & 7) << 2;
      int n = n0 + row;
      float4 v = make_float4(0.f, 0.f, 0.f, 0.f);
      if (n < NN) {
        if (kc < FD) {
          float4 a4 = *(const float4*)(agg + n * FD + kc + col);
          float4 b4 = *(const float4*)(bg + kc + col);
          v = make_float4(a4.x + b4.x, a4.y + b4.y, a4.z + b4.z, a4.w + b4.w);
        } else {
          v = *(const float4*)(hs + n * FD + (kc - FD) + col);
        }
      }
      As[row][col] = v.x; As[row][col + 1] = v.y;
      As[row][col + 2] = v.z; As[row][col + 3] = v.w;
    }
#pragma unroll
    for (int l = 0; l < 8; ++l) {
      int idx = tid + l * 256;        // 2048 float4: 32 rows x 64
      int row = idx >> 6;
      int col = (idx & 63) << 2;
      const float* srcp = (col < FD) ? (Wz + (kc + row) * FD + col)
                                     : (Wr + (kc + row) * FD + (col - FD));
      *(float4*)(&Ws[row][col]) = *(const float4*)srcp;
    }
    __syncthreads();
#pragma unroll 4
    for (int k = 0; k < 32; ++k) {
      float4 w0 = *(const float4*)&Ws[k][tc * 4];
      float4 w1 = *(const float4*)&Ws[k][tc * 4 + 64];
      float4 w2 = *(const float4*)&Ws[k][tc * 4 + 128];
      float4 w3 = *(const float4*)&Ws[k][tc * 4 + 192];
#pragma unroll
      for (int i = 0; i < 4; ++i) {
        float a = As[tr * 4 + i][k];
        acc[i][0] += a * w0.x;  acc[i][1] += a * w0.y;
        acc[i][2] += a * w0.z;  acc[i][3] += a * w0.w;
        acc[i][4] += a * w1.x;  acc[i][5] += a * w1.y;
        acc[i][6] += a * w1.z;  acc[i][7] += a * w1.w;
        acc[i][8] += a * w2.x;  acc[i][9] += a * w2.y;
        acc[i][10] += a * w2.z; acc[i][11] += a * w2.w;
        acc[i][12] += a * w3.x; acc[i][13] += a * w3.y;
        acc[i][14] += a * w3.z; acc[i][15] += a * w3.w;
      }
    }
    __syncthreads();
  }
#pragma unroll
  for (int i = 0; i < 4; ++i) {
    int n = n0 + tr * 4 + i;
    if (n >= NN) continue;
#pragma unroll
    for (int q = 0; q < 4; ++q) {
      int c = tc * 4 + q * 64;
      if (c < FD) {
        float4 o;
        o.x = sigmoidf_(acc[i][q * 4 + 0] + bz[c + 0]);
        o.y = sigmoidf_(acc[i][q * 4 + 1] + bz[c + 1]);
        o.z = sigmoidf_(acc[i][q * 4 + 2] + bz[c + 2]);
        o.w = sigmoidf_(acc[i][q * 4 + 3] + bz[c + 3]);
        *(float4*)(Zb + n * FD + c) = o;
      } else {
        int cc = c - FD;
        float4 hv = *(const float4*)(hs + n * FD + cc);
        float4 o;
        o.x = sigmoidf_(acc[i][q * 4 + 0] + br[cc + 0]) * hv.x;
        o.y = sigmoidf_(acc[i][q * 4 + 1] + br[cc + 1]) * hv.y;
        o.z = sigmoidf_(acc[i][q * 4 + 2] + br[cc + 2]) * hv.z;
        o.w = sigmoidf_(acc[i][q * 4 + 3] + br[cc + 3]) * hv.w;
        *(float4*)(hsr + n * FD + cc) = o;
      }
    }
  }
}

// ---------------- Ht GEMM + Hn + classifier + softmax ----------------

__global__ __launch_bounds__(256) void k_ht(
    const float* __restrict__ agg, const float* __restrict__ bg,
    const float* __restrict__ hsr, const float* __restrict__ Wh,
    const float* __restrict__ bh, const float* __restrict__ Zb,
    const float* __restrict__ hs, const float* __restrict__ Wl,
    const float* __restrict__ bl, float* __restrict__ probs,
    float* __restrict__ Hn) {
  __shared__ __align__(16) char smem[45568];
  float (*As)[33] = (float(*)[33])smem;                 // [64][33]  @0     (GEMM phase)
  float (*Ws)[FD] = (float(*)[FD])(smem + 8448);        // [32][128] @8448  (GEMM phase)
  float (*HnS)[129] = (float(*)[129])smem;              // [64][129] @0     (post phase)
  float (*lg)[17] = (float(*)[17])(smem + 33024);       // [64][17]  @33024 (post phase)
  float (*WlS)[NCLS] = (float(*)[NCLS])(smem + 37376);  // [128][16] @37376 (persistent)

  const int tid = threadIdx.x;
  const int n0 = blockIdx.x * 64;
  const int tr = tid >> 4, tc = tid & 15;

#pragma unroll
  for (int l = 0; l < 2; ++l) {
    int idx = tid + l * 256;  // 512 float4 = 2048 floats
    ((float4*)WlS)[idx] = ((const float4*)Wl)[idx];
  }

  float acc[4][8];
#pragma unroll
  for (int i = 0; i < 4; ++i)
#pragma unroll
    for (int j = 0; j < 8; ++j) acc[i][j] = 0.f;

  for (int kc = 0; kc < CIN; kc += 32) {
#pragma unroll
    for (int l = 0; l < 2; ++l) {
      int idx = tid + l * 256;
      int row = idx >> 3;
      int col = (idx & 7) << 2;
      int n = n0 + row;
      float4 v = make_float4(0.f, 0.f, 0.f, 0.f);
      if (n < NN) {
        if (kc < FD) {
          float4 a4 = *(const float4*)(agg + n * FD + kc + col);
          float4 b4 = *(const float4*)(bg + kc + col);
          v = make_float4(a4.x + b4.x, a4.y + b4.y, a4.z + b4.z, a4.w + b4.w);
        } else {
          v = *(const float4*)(hsr + n * FD + (kc - FD) + col);
        }
      }
      As[row][col] = v.x; As[row][col + 1] = v.y;
      As[row][col + 2] = v.z; As[row][col + 3] = v.w;
    }
#pragma unroll
    for (int l = 0; l < 4; ++l) {
      int idx = tid + l * 256;
      int row = idx >> 5;
      int col = (idx & 31) << 2;
      *(float4*)(&Ws[row][col]) = *(const float4*)(Wh + (kc + row) * FD + col);
    }
    __syncthreads();
#pragma unroll 4
    for (int k = 0; k < 32; ++k) {
      float4 w0 = *(const float4*)&Ws[k][tc * 4];
      float4 w1 = *(const float4*)&Ws[k][tc * 4 + 64];
#pragma unroll
      for (int i = 0; i < 4; ++i) {
        float a = As[tr * 4 + i][k];
        acc[i][0] += a * w0.x; acc[i][1] += a * w0.y;
        acc[i][2] += a * w0.z; acc[i][3] += a * w0.w;
        acc[i][4] += a * w1.x; acc[i][5] += a * w1.y;
        acc[i][6] += a * w1.z; acc[i][7] += a * w1.w;
      }
    }
    __syncthreads();
  }

#pragma unroll
  for (int i = 0; i < 4; ++i) {
    int lr = tr * 4 + i;
    int n = n0 + lr;
    if (n < NN) {
#pragma unroll
      for (int q = 0; q < 2; ++q) {
        int c = tc * 4 + q * 64;
        float4 z4 = *(const float4*)(Zb + n * FD + c);
        float4 h4 = *(const float4*)(hs + n * FD + c);
        float4 o;
        o.x = z4.x * h4.x + (1.f - z4.x) * tanhf(acc[i][q * 4 + 0] + bh[c + 0]);
        o.y = z4.y * h4.y + (1.f - z4.y) * tanhf(acc[i][q * 4 + 1] + bh[c + 1]);
        o.z = z4.z * h4.z + (1.f - z4.z) * tanhf(acc[i][q * 4 + 2] + bh[c + 2]);
        o.w = z4.w * h4.w + (1.f - z4.w) * tanhf(acc[i][q * 4 + 3] + bh[c + 3]);
        *(float4*)(Hn + n * FD + c) = o;
        HnS[lr][c + 0] = o.x; HnS[lr][c + 1] = o.y;
        HnS[lr][c + 2] = o.z; HnS[lr][c + 3] = o.w;
      }
    } else {
#pragma unroll
      for (int q = 0; q < 2; ++q) {
        int c = tc * 4 + q * 64;
        HnS[lr][c + 0] = 0.f; HnS[lr][c + 1] = 0.f;
        HnS[lr][c + 2] = 0.f; HnS[lr][c + 3] = 0.f;
      }
    }
  }
  __syncthreads();

  {
    int nl = tid >> 2;
    int cq = (tid & 3) << 2;
    float l0 = bl[cq + 0], l1 = bl[cq + 1], l2 = bl[cq + 2], l3 = bl[cq + 3];
#pragma unroll 8
    for (int k = 0; k < FD; ++k) {
      float hv = fmaxf(HnS[nl][k], 0.f);
      float4 wv = *(const float4*)&WlS[k][cq];
      l0 += hv * wv.x; l1 += hv * wv.y; l2 += hv * wv.z; l3 += hv * wv.w;
    }
    lg[nl][cq + 0] = l0; lg[nl][cq + 1] = l1;
    lg[nl][cq + 2] = l2; lg[nl][cq + 3] = l3;
  }
  __syncthreads();

  if (tid < 64) {
    int n = n0 + tid;
    if (n < NN) {
      float m = lg[tid][0];
#pragma unroll
      for (int j = 1; j < NCLS; ++j) m = fmaxf(m, lg[tid][j]);
      float e[NCLS];
      float s = 0.f;
#pragma unroll
      for (int j = 0; j < NCLS; ++j) { e[j] = expf(lg[tid][j] - m); s += e[j]; }
      float inv = 1.f / s;
#pragma unroll
      for (int q = 0; q < 4; ++q) {
        float4 o = make_float4(e[q * 4] * inv, e[q * 4 + 1] * inv,
                               e[q * 4 + 2] * inv, e[q * 4 + 3] * inv);
        *(float4*)(probs + n * NCLS + q * 4) = o;
      }
    }
  }
}

// ---------------- launch ----------------

extern "C" void kernel_launch(void* const* d_in, const int* in_sizes, int n_in,
                              void* d_out, int out_size, void* d_ws, size_t ws_size,
                              hipStream_t stream) {
  (void)in_sizes; (void)n_in; (void)out_size; (void)ws_size;
  const float* x   = (const float*)d_in[0];
  const int*   ei  = (const int*)d_in[1];
  const float* ew  = (const float*)d_in[2];
  const float* hs  = (const float*)d_in[3];
  const float* Wg  = (const float*)d_in[4];
  const float* bg  = (const float*)d_in[5];
  const float* Wz0 = (const float*)d_in[6];
  const float* Wz1 = (const float*)d_in[7];
  const float* bz  = (const float*)d_in[8];
  const float* Wr0 = (const float*)d_in[9];
  const float* Wr1 = (const float*)d_in[10];
  const float* br  = (const float*)d_in[11];
  const float* Wh0 = (const float*)d_in[12];
  const float* Wh1 = (const float*)d_in[13];
  const float* bh  = (const float*)d_in[14];
  const float* Wl  = (const float*)d_in[15];
  const float* bl  = (const float*)d_in[16];

  float* out   = (float*)d_out;
  float* probs = out;                      // [NN,16]
  float* Hn    = out + (size_t)NN * NCLS;  // [NN,128]

  float* w    = (float*)d_ws;
  float* dinv = w;                             // [NN] (deg then dinv in place)
  float* xw   = w + 50048;                     // [NN*FD]; reused as Zb after gather
  float* agg  = xw + (size_t)NN * FD;          // [NN*FD]
  float* hsr  = agg + (size_t)NN * FD;         // [NN*FD]; CSR arrays alias this pre-k_zr
  float* Wz   = hsr + (size_t)NN * FD;         // [CIN*FD]
  float* Wr   = Wz + CIN * FD;
  float* Wh   = Wr + CIN * FD;
  float* Zb   = xw;

  // CSR scratch aliased onto hsr region (dead until k_zr writes hsr)
  int*   src_s = (int*)hsr;                    // [NE]
  float* nrm_s = hsr + NE;                     // [NE]
  int*   cnt   = (int*)(hsr + 2 * NE);         // [NN]
  int*   basep = (int*)(hsr + 2 * NE + NN);    // [NN+1]
  int*   fill  = (int*)(hsr + 2 * NE + 2 * NN + 1);  // [NN]

  k_wsum<<<128, 256, 0, stream>>>(Wz0, Wz1, Wr0, Wr1, Wh0, Wh1, Wz, Wr, Wh);
  k_init<<<196, 256, 0, stream>>>(dinv, cnt, fill);
  k_deg_hist<<<1024, 256, 0, stream>>>(ei + NE, ew, dinv, cnt);
  k_dinv<<<196, 256, 0, stream>>>(dinv);
  k_scan<<<1, 1024, 0, stream>>>(cnt, basep);
  k_reorder<<<1024, 256, 0, stream>>>(ei, ew, dinv, basep, fill, src_s, nrm_s);
  k_gemm_xw<<<782, 256, 0, stream>>>(x, Wg, dinv, xw, agg);
  k_gather<<<12500, 256, 0, stream>>>(basep, src_s, nrm_s, xw, agg);
  k_zr<<<782, 256, 0, stream>>>(agg, bg, hs, Wz, Wr, bz, br, Zb, hsr);
  k_ht<<<782, 256, 0, stream>>>(agg, bg, hsr, Wh, bh, Zb, hs, Wl, bl, probs, Hn);
}

// Round 5
// 378.311 us; speedup vs baseline: 2.5578x; 1.3725x over previous
//
#include <hip/hip_runtime.h>
#include <math.h>

#define NN 50000
#define NE 800000
#define FD 128
#define CIN 256
#define NCLS 16

typedef short s16x8 __attribute__((ext_vector_type(8)));
typedef float f32x4 __attribute__((ext_vector_type(4)));

__device__ __forceinline__ unsigned short f2bf(float f) {
  union { float f; unsigned u; } v; v.f = f;
  unsigned r = v.u + 0x7fffu + ((v.u >> 16) & 1u);
  return (unsigned short)(r >> 16);
}

__device__ __forceinline__ float sigmoidf_(float x) {
  return 1.0f / (1.0f + expf(-x));
}

// ---------------- weight prep: bf16 transposed WT[col][k] ----------------
// wtzr [256][256]: cols 0-127 = Wz0+Wz1, cols 128-255 = Wr0+Wr1 (k = 0..255)
// wth  [128][256]: Wh0+Wh1 ; wtg [128][128]: Wg ; wtl [16][128]: Wl

__global__ void k_prep_w(const float* __restrict__ Wz0, const float* __restrict__ Wz1,
                         const float* __restrict__ Wr0, const float* __restrict__ Wr1,
                         const float* __restrict__ Wh0, const float* __restrict__ Wh1,
                         const float* __restrict__ Wg, const float* __restrict__ Wl,
                         short* __restrict__ wtzr, short* __restrict__ wth,
                         short* __restrict__ wtg, short* __restrict__ wtl) {
  int i = blockIdx.x * blockDim.x + threadIdx.x;
  if (i < 65536) {
    int n = i >> 8, k = i & 255;
    float v = (n < 128) ? (Wz0[k * 128 + n] + Wz1[k * 128 + n])
                        : (Wr0[k * 128 + (n - 128)] + Wr1[k * 128 + (n - 128)]);
    wtzr[i] = (short)f2bf(v);
  } else if (i < 98304) {
    int j = i - 65536; int n = j >> 8, k = j & 255;
    wth[j] = (short)f2bf(Wh0[k * 128 + n] + Wh1[k * 128 + n]);
  } else if (i < 114688) {
    int j = i - 98304; int n = j >> 7, k = j & 127;
    wtg[j] = (short)f2bf(Wg[k * 128 + n]);
  } else if (i < 116736) {
    int j = i - 114688; int n = j >> 7, k = j & 127;
    wtl[j] = (short)f2bf(Wl[k * 16 + n]);
  }
}

// fold bg into gate biases: b'[c] = b[c] + sum_k bg[k] * (W0+W1)[k][c]
__global__ void k_prep_bias(const float* __restrict__ bg,
                            const float* __restrict__ Wz0, const float* __restrict__ Wz1,
                            const float* __restrict__ Wr0, const float* __restrict__ Wr1,
                            const float* __restrict__ Wh0, const float* __restrict__ Wh1,
                            const float* __restrict__ bz, const float* __restrict__ br,
                            const float* __restrict__ bh,
                            float* __restrict__ bzp, float* __restrict__ brp,
                            float* __restrict__ bhp) {
  int c = threadIdx.x;
  if (c >= 128) return;
  float sz = bz[c], sr = br[c], sh = bh[c];
  for (int k = 0; k < 128; ++k) {
    float g = bg[k];
    sz += g * (Wz0[k * 128 + c] + Wz1[k * 128 + c]);
    sr += g * (Wr0[k * 128 + c] + Wr1[k * 128 + c]);
    sh += g * (Wh0[k * 128 + c] + Wh1[k * 128 + c]);
  }
  bzp[c] = sz; brp[c] = sr; bhp[c] = sh;
}

// ---------------- CSR build (unchanged, verified) ----------------

__global__ void k_init(float* __restrict__ deg, int* __restrict__ cnt,
                       int* __restrict__ fill) {
  int i = blockIdx.x * blockDim.x + threadIdx.x;
  if (i < NN) { deg[i] = 1.0f; cnt[i] = 0; fill[i] = 0; }
}

__global__ void k_deg_hist(const int* __restrict__ dst, const float* __restrict__ ew,
                           float* __restrict__ deg, int* __restrict__ cnt) {
  int i = blockIdx.x * blockDim.x + threadIdx.x;
  int stride = gridDim.x * blockDim.x;
  for (int e = i; e < NE; e += stride) {
    int d = dst[e];
    atomicAdd(&deg[d], ew[e]);
    atomicAdd(&cnt[d], 1);
  }
}

__global__ void k_dinv(float* __restrict__ deg) {
  int i = blockIdx.x * blockDim.x + threadIdx.x;
  if (i < NN) deg[i] = rsqrtf(deg[i]);
}

__global__ __launch_bounds__(1024) void k_scan(const int* __restrict__ cnt,
                                               int* __restrict__ base) {
  __shared__ int ts[1024];
  const int tid = threadIdx.x;
  const int per = (NN + 1023) / 1024;
  int s0 = tid * per;
  int s1 = s0 + per; if (s1 > NN) s1 = NN;
  int sum = 0;
  for (int i = s0; i < s1; ++i) sum += cnt[i];
  ts[tid] = sum;
  __syncthreads();
  for (int off = 1; off < 1024; off <<= 1) {
    int v = (tid >= off) ? ts[tid - off] : 0;
    __syncthreads();
    ts[tid] += v;
    __syncthreads();
  }
  int run = (tid == 0) ? 0 : ts[tid - 1];
  for (int i = s0; i < s1; ++i) { base[i] = run; run += cnt[i]; }
  if (tid == 1023) base[NN] = run;
}

__global__ void k_reorder(const int* __restrict__ ei, const float* __restrict__ ew,
                          const float* __restrict__ dinv, const int* __restrict__ base,
                          int* __restrict__ fill, int* __restrict__ src_s,
                          float* __restrict__ nrm_s) {
  int i = blockIdx.x * blockDim.x + threadIdx.x;
  int stride = gridDim.x * blockDim.x;
  const int* __restrict__ src = ei;
  const int* __restrict__ dst = ei + NE;
  for (int e = i; e < NE; e += stride) {
    int s = src[e], d = dst[e];
    int pos = base[d] + atomicAdd(&fill[d], 1);
    src_s[pos] = s;
    nrm_s[pos] = dinv[s] * ew[e] * dinv[d];
  }
}

// ---------------- MFMA GEMM: xw = x @ Wg ; agg = xw * dinv^2 --------------
// block = 64 rows x 128 cols, 4 waves, wave w -> cols [w*32, w*32+32)

__global__ __launch_bounds__(256) void k_xw_mfma(
    const float* __restrict__ x, const short* __restrict__ wtg,
    const float* __restrict__ dinv, float* __restrict__ xw, float* __restrict__ agg) {
  __shared__ __align__(16) short As[64][40];
  const int tid = threadIdx.x;
  const int w = tid >> 6, l = tid & 63, g = l >> 4, ln = l & 15;
  const int n0 = blockIdx.x * 64;
  const int srow = tid >> 2, sk0 = (tid & 3) << 3;
  const s16x8* wt8 = (const s16x8*)wtg;  // row = 128 shorts = 16 units

  f32x4 acc[4][2];
#pragma unroll
  for (int mi = 0; mi < 4; ++mi)
#pragma unroll
    for (int ni = 0; ni < 2; ++ni) acc[mi][ni] = (f32x4){0.f, 0.f, 0.f, 0.f};

  for (int kci = 0; kci < 4; ++kci) {
    int kg = kci * 32 + sk0;
    int n = n0 + srow;
    s16x8 av = {0, 0, 0, 0, 0, 0, 0, 0};
    if (n < NN) {
      const float* src = x + (size_t)n * FD + kg;
      float4 f0 = *(const float4*)src;
      float4 f1 = *(const float4*)(src + 4);
      av[0] = (short)f2bf(f0.x); av[1] = (short)f2bf(f0.y);
      av[2] = (short)f2bf(f0.z); av[3] = (short)f2bf(f0.w);
      av[4] = (short)f2bf(f1.x); av[5] = (short)f2bf(f1.y);
      av[6] = (short)f2bf(f1.z); av[7] = (short)f2bf(f1.w);
    }
    __syncthreads();
    *(s16x8*)&As[srow][sk0] = av;
    __syncthreads();
    s16x8 b[2], a[4];
#pragma unroll
    for (int ni = 0; ni < 2; ++ni) {
      int col = w * 32 + ni * 16 + ln;
      b[ni] = wt8[(size_t)col * 16 + kci * 4 + g];
    }
#pragma unroll
    for (int mi = 0; mi < 4; ++mi) a[mi] = *(const s16x8*)&As[mi * 16 + ln][g * 8];
#pragma unroll
    for (int mi = 0; mi < 4; ++mi)
#pragma unroll
      for (int ni = 0; ni < 2; ++ni)
        acc[mi][ni] = __builtin_amdgcn_mfma_f32_16x16x32_bf16(a[mi], b[ni], acc[mi][ni], 0, 0, 0);
  }
#pragma unroll
  for (int mi = 0; mi < 4; ++mi) {
#pragma unroll
    for (int r = 0; r < 4; ++r) {
      int n = n0 + mi * 16 + g * 4 + r;
      if (n >= NN) continue;
      float di = dinv[n];
      float d2 = di * di;
#pragma unroll
      for (int ni = 0; ni < 2; ++ni) {
        int c = w * 32 + ni * 16 + ln;
        float v = acc[mi][ni][r];
        xw[(size_t)n * FD + c] = v;
        agg[(size_t)n * FD + c] = v * d2;
      }
    }
  }
}

// ---------------- CSR gather (unchanged, verified) ----------------

__global__ __launch_bounds__(256) void k_gather(
    const int* __restrict__ base, const int* __restrict__ src_s,
    const float* __restrict__ nrm_s, const float* __restrict__ xw,
    float* __restrict__ agg) {
  const int lane = threadIdx.x & 63;
  const int n = blockIdx.x * 4 + (threadIdx.x >> 6);
  if (n >= NN) return;
  const int e0 = base[n], e1 = base[n + 1];
  const int c = lane * 2;
  float* ap = agg + (size_t)n * FD + c;
  float2 acc = *(const float2*)ap;
  int e = e0;
  for (; e + 4 <= e1; e += 4) {
    int s0 = src_s[e], s1 = src_s[e + 1], s2 = src_s[e + 2], s3 = src_s[e + 3];
    float w0 = nrm_s[e], w1 = nrm_s[e + 1], w2 = nrm_s[e + 2], w3 = nrm_s[e + 3];
    float2 v0 = *(const float2*)(xw + (size_t)s0 * FD + c);
    float2 v1 = *(const float2*)(xw + (size_t)s1 * FD + c);
    float2 v2 = *(const float2*)(xw + (size_t)s2 * FD + c);
    float2 v3 = *(const float2*)(xw + (size_t)s3 * FD + c);
    acc.x = fmaf(w0, v0.x, acc.x); acc.y = fmaf(w0, v0.y, acc.y);
    acc.x = fmaf(w1, v1.x, acc.x); acc.y = fmaf(w1, v1.y, acc.y);
    acc.x = fmaf(w2, v2.x, acc.x); acc.y = fmaf(w2, v2.y, acc.y);
    acc.x = fmaf(w3, v3.x, acc.x); acc.y = fmaf(w3, v3.y, acc.y);
  }
  for (; e < e1; ++e) {
    int s = src_s[e];
    float wv = nrm_s[e];
    float2 v = *(const float2*)(xw + (size_t)s * FD + c);
    acc.x = fmaf(wv, v.x, acc.x); acc.y = fmaf(wv, v.y, acc.y);
  }
  *(float2*)ap = acc;
}

// ---------------- MFMA ZR: [agg|hs] @ wtzr^T -> Z (fp32), hsr (bf16) ------
// block = 64 rows x 256 cols, wave w -> cols [w*64, w*64+64)

__global__ __launch_bounds__(256) void k_zr_mfma(
    const float* __restrict__ agg, const float* __restrict__ hs,
    const short* __restrict__ wtzr, const float* __restrict__ bzp,
    const float* __restrict__ brp, float* __restrict__ Zb,
    short* __restrict__ hsr16) {
  __shared__ __align__(16) short As[64][40];
  const int tid = threadIdx.x;
  const int w = tid >> 6, l = tid & 63, g = l >> 4, ln = l & 15;
  const int n0 = blockIdx.x * 64;
  const int srow = tid >> 2, sk0 = (tid & 3) << 3;
  const s16x8* wt8 = (const s16x8*)wtzr;  // row = 256 shorts = 32 units

  f32x4 acc[4][4];
#pragma unroll
  for (int mi = 0; mi < 4; ++mi)
#pragma unroll
    for (int ni = 0; ni < 4; ++ni) acc[mi][ni] = (f32x4){0.f, 0.f, 0.f, 0.f};

  for (int kci = 0; kci < 8; ++kci) {
    int kg = kci * 32 + sk0;
    int n = n0 + srow;
    s16x8 av = {0, 0, 0, 0, 0, 0, 0, 0};
    if (n < NN) {
      const float* src = (kg < FD) ? (agg + (size_t)n * FD + kg)
                                   : (hs + (size_t)n * FD + (kg - FD));
      float4 f0 = *(const float4*)src;
      float4 f1 = *(const float4*)(src + 4);
      av[0] = (short)f2bf(f0.x); av[1] = (short)f2bf(f0.y);
      av[2] = (short)f2bf(f0.z); av[3] = (short)f2bf(f0.w);
      av[4] = (short)f2bf(f1.x); av[5] = (short)f2bf(f1.y);
      av[6] = (short)f2bf(f1.z); av[7] = (short)f2bf(f1.w);
    }
    __syncthreads();
    *(s16x8*)&As[srow][sk0] = av;
    __syncthreads();
    s16x8 b[4], a[4];
#pragma unroll
    for (int ni = 0; ni < 4; ++ni) {
      int col = w * 64 + ni * 16 + ln;
      b[ni] = wt8[(size_t)col * 32 + kci * 4 + g];
    }
#pragma unroll
    for (int mi = 0; mi < 4; ++mi) a[mi] = *(const s16x8*)&As[mi * 16 + ln][g * 8];
#pragma unroll
    for (int mi = 0; mi < 4; ++mi)
#pragma unroll
      for (int ni = 0; ni < 4; ++ni)
        acc[mi][ni] = __builtin_amdgcn_mfma_f32_16x16x32_bf16(a[mi], b[ni], acc[mi][ni], 0, 0, 0);
  }
  float bias[4];
  int colv[4];
#pragma unroll
  for (int ni = 0; ni < 4; ++ni) {
    colv[ni] = w * 64 + ni * 16 + ln;
    bias[ni] = (colv[ni] < FD) ? bzp[colv[ni]] : brp[colv[ni] - FD];
  }
#pragma unroll
  for (int mi = 0; mi < 4; ++mi) {
#pragma unroll
    for (int r = 0; r < 4; ++r) {
      int n = n0 + mi * 16 + g * 4 + r;
      if (n >= NN) continue;
#pragma unroll
      for (int ni = 0; ni < 4; ++ni) {
        float sv = sigmoidf_(acc[mi][ni][r] + bias[ni]);
        if (colv[ni] < FD) {
          Zb[(size_t)n * FD + colv[ni]] = sv;
        } else {
          int cc = colv[ni] - FD;
          hsr16[(size_t)n * FD + cc] = (short)f2bf(sv * hs[(size_t)n * FD + cc]);
        }
      }
    }
  }
}

// ---------------- MFMA Ht + Hn + classifier + softmax --------------------
// block = 64 rows x 128 cols, wave w -> cols [w*32, w*32+32)

__global__ __launch_bounds__(256) void k_ht_mfma(
    const float* __restrict__ agg, const short* __restrict__ hsr16,
    const short* __restrict__ wth, const float* __restrict__ bhp,
    const float* __restrict__ Zb, const float* __restrict__ hs,
    const short* __restrict__ wtl, const float* __restrict__ bl,
    float* __restrict__ probs, float* __restrict__ Hn) {
  __shared__ __align__(16) short As[64][40];
  __shared__ __align__(16) short HnL[64][136];
  const int tid = threadIdx.x;
  const int w = tid >> 6, l = tid & 63, g = l >> 4, ln = l & 15;
  const int n0 = blockIdx.x * 64;
  const int srow = tid >> 2, sk0 = (tid & 3) << 3;
  const s16x8* wt8 = (const s16x8*)wth;  // row = 256 shorts = 32 units

  f32x4 acc[4][2];
#pragma unroll
  for (int mi = 0; mi < 4; ++mi)
#pragma unroll
    for (int ni = 0; ni < 2; ++ni) acc[mi][ni] = (f32x4){0.f, 0.f, 0.f, 0.f};

  for (int kci = 0; kci < 8; ++kci) {
    int kg = kci * 32 + sk0;
    int n = n0 + srow;
    s16x8 av = {0, 0, 0, 0, 0, 0, 0, 0};
    if (n < NN) {
      if (kg < FD) {
        const float* src = agg + (size_t)n * FD + kg;
        float4 f0 = *(const float4*)src;
        float4 f1 = *(const float4*)(src + 4);
        av[0] = (short)f2bf(f0.x); av[1] = (short)f2bf(f0.y);
        av[2] = (short)f2bf(f0.z); av[3] = (short)f2bf(f0.w);
        av[4] = (short)f2bf(f1.x); av[5] = (short)f2bf(f1.y);
        av[6] = (short)f2bf(f1.z); av[7] = (short)f2bf(f1.w);
      } else {
        av = *(const s16x8*)(hsr16 + (size_t)n * FD + (kg - FD));
      }
    }
    __syncthreads();
    *(s16x8*)&As[srow][sk0] = av;
    __syncthreads();
    s16x8 b[2], a[4];
#pragma unroll
    for (int ni = 0; ni < 2; ++ni) {
      int col = w * 32 + ni * 16 + ln;
      b[ni] = wt8[(size_t)col * 32 + kci * 4 + g];
    }
#pragma unroll
    for (int mi = 0; mi < 4; ++mi) a[mi] = *(const s16x8*)&As[mi * 16 + ln][g * 8];
#pragma unroll
    for (int mi = 0; mi < 4; ++mi)
#pragma unroll
      for (int ni = 0; ni < 2; ++ni)
        acc[mi][ni] = __builtin_amdgcn_mfma_f32_16x16x32_bf16(a[mi], b[ni], acc[mi][ni], 0, 0, 0);
  }

  float bh_c[2];
#pragma unroll
  for (int ni = 0; ni < 2; ++ni) bh_c[ni] = bhp[w * 32 + ni * 16 + ln];

#pragma unroll
  for (int mi = 0; mi < 4; ++mi) {
#pragma unroll
    for (int r = 0; r < 4; ++r) {
      int lr = mi * 16 + g * 4 + r;
      int n = n0 + lr;
#pragma unroll
      for (int ni = 0; ni < 2; ++ni) {
        int c = w * 32 + ni * 16 + ln;
        if (n < NN) {
          float z = Zb[(size_t)n * FD + c];
          float hv = hs[(size_t)n * FD + c];
          float ht = tanhf(acc[mi][ni][r] + bh_c[ni]);
          float hn = z * hv + (1.f - z) * ht;
          Hn[(size_t)n * FD + c] = hn;
          HnL[lr][c] = (short)f2bf(fmaxf(hn, 0.f));
        } else {
          HnL[lr][c] = 0;
        }
      }
    }
  }
  __syncthreads();

  // classifier: wave w handles rows [w*16, w*16+16); 16 output classes
  f32x4 ac = (f32x4){0.f, 0.f, 0.f, 0.f};
  const s16x8* wtl8 = (const s16x8*)wtl;  // row = 128 shorts = 16 units
#pragma unroll
  for (int kci = 0; kci < 4; ++kci) {
    s16x8 a = *(const s16x8*)&HnL[w * 16 + ln][kci * 32 + g * 8];
    s16x8 bfr = wtl8[ln * 16 + kci * 4 + g];
    ac = __builtin_amdgcn_mfma_f32_16x16x32_bf16(a, bfr, ac, 0, 0, 0);
  }
  float blv = bl[ln];
#pragma unroll
  for (int r = 0; r < 4; ++r) {
    int n = n0 + w * 16 + g * 4 + r;
    float v = ac[r] + blv;
    float m = v;
#pragma unroll
    for (int msk = 1; msk < 16; msk <<= 1) m = fmaxf(m, __shfl_xor(m, msk, 64));
    float e = expf(v - m);
    float s = e;
#pragma unroll
    for (int msk = 1; msk < 16; msk <<= 1) s += __shfl_xor(s, msk, 64);
    if (n < NN) probs[(size_t)n * NCLS + ln] = e / s;
  }
}

// ---------------- launch ----------------

extern "C" void kernel_launch(void* const* d_in, const int* in_sizes, int n_in,
                              void* d_out, int out_size, void* d_ws, size_t ws_size,
                              hipStream_t stream) {
  (void)in_sizes; (void)n_in; (void)out_size; (void)ws_size;
  const float* x   = (const float*)d_in[0];
  const int*   ei  = (const int*)d_in[1];
  const float* ew  = (const float*)d_in[2];
  const float* hs  = (const float*)d_in[3];
  const float* Wg  = (const float*)d_in[4];
  const float* bg  = (const float*)d_in[5];
  const float* Wz0 = (const float*)d_in[6];
  const float* Wz1 = (const float*)d_in[7];
  const float* bz  = (const float*)d_in[8];
  const float* Wr0 = (const float*)d_in[9];
  const float* Wr1 = (const float*)d_in[10];
  const float* br  = (const float*)d_in[11];
  const float* Wh0 = (const float*)d_in[12];
  const float* Wh1 = (const float*)d_in[13];
  const float* bh  = (const float*)d_in[14];
  const float* Wl  = (const float*)d_in[15];
  const float* bl  = (const float*)d_in[16];

  float* out   = (float*)d_out;
  float* probs = out;                      // [NN,16]
  float* Hn    = out + (size_t)NN * NCLS;  // [NN,128]

  float* w    = (float*)d_ws;
  float* dinv = w;                             // [NN]
  float* xw   = w + 50048;                     // [NN*FD]; reused as Zb
  float* agg  = xw + (size_t)NN * FD;          // [NN*FD]
  float* hsrf = agg + (size_t)NN * FD;         // [NN*FD] region: CSR scratch, then hsr16
  float* wsp  = hsrf + (size_t)NN * FD;        // tail: bf16 weights + biases
  float* Zb   = xw;
  short* hsr16 = (short*)hsrf;

  short* wtzr = (short*)wsp;                       // 65536 shorts
  short* wth  = (short*)(wsp + 32768);             // 32768 shorts
  short* wtg  = (short*)(wsp + 32768 + 16384);     // 16384 shorts
  short* wtl  = (short*)(wsp + 32768 + 16384 + 8192);  // 2048 shorts
  float* bzp  = wsp + 32768 + 16384 + 8192 + 1024;
  float* brp  = bzp + 128;
  float* bhp  = brp + 128;

  // CSR scratch aliased onto hsr region (dead before k_zr writes hsr16)
  int*   src_s = (int*)hsrf;                        // [NE]
  float* nrm_s = hsrf + NE;                         // [NE]
  int*   cnt   = (int*)(hsrf + 2 * NE);             // [NN]
  int*   basep = (int*)(hsrf + 2 * NE + NN);        // [NN+1]
  int*   fill  = (int*)(hsrf + 2 * NE + 2 * NN + 1);// [NN]

  k_prep_w<<<456, 256, 0, stream>>>(Wz0, Wz1, Wr0, Wr1, Wh0, Wh1, Wg, Wl,
                                    wtzr, wth, wtg, wtl);
  k_prep_bias<<<1, 128, 0, stream>>>(bg, Wz0, Wz1, Wr0, Wr1, Wh0, Wh1,
                                     bz, br, bh, bzp, brp, bhp);
  k_init<<<196, 256, 0, stream>>>(dinv, cnt, fill);
  k_deg_hist<<<1024, 256, 0, stream>>>(ei + NE, ew, dinv, cnt);
  k_dinv<<<196, 256, 0, stream>>>(dinv);
  k_scan<<<1, 1024, 0, stream>>>(cnt, basep);
  k_reorder<<<1024, 256, 0, stream>>>(ei, ew, dinv, basep, fill, src_s, nrm_s);
  k_xw_mfma<<<782, 256, 0, stream>>>(x, wtg, dinv, xw, agg);
  k_gather<<<12500, 256, 0, stream>>>(basep, src_s, nrm_s, xw, agg);
  k_zr_mfma<<<782, 256, 0, stream>>>(agg, hs, wtzr, bzp, brp, Zb, hsr16);
  k_ht_mfma<<<782, 256, 0, stream>>>(agg, hsr16, wth, bhp, Zb, hs, wtl, bl, probs, Hn);
}

// Round 7
// 310.258 us; speedup vs baseline: 3.1189x; 1.2193x over previous
//
#include <hip/hip_runtime.h>
#include <math.h>

#define NN 50000
#define NE 800000
#define FD 128
#define CIN 256
#define NCLS 16
#define SCAN_B 196  // ceil(NN/256)

typedef short s16x8 __attribute__((ext_vector_type(8)));
typedef float f32x4 __attribute__((ext_vector_type(4)));

__device__ __forceinline__ unsigned short f2bf(float f) {
  union { float f; unsigned u; } v; v.f = f;
  unsigned r = v.u + 0x7fffu + ((v.u >> 16) & 1u);
  return (unsigned short)(r >> 16);
}

__device__ __forceinline__ float sigmoidf_(float x) {
  return 1.0f / (1.0f + expf(-x));
}

// ---------------- weight prep: bf16 transposed WT[col][k] ----------------
// wtzr [256][256]: cols 0-127 = Wz0+Wz1, cols 128-255 = Wr0+Wr1 (k = 0..255)
// wth  [128][256]: Wh0+Wh1 ; wtg [128][128]: Wg ; wtl [16][128]: Wl

__global__ void k_prep_w(const float* __restrict__ Wz0, const float* __restrict__ Wz1,
                         const float* __restrict__ Wr0, const float* __restrict__ Wr1,
                         const float* __restrict__ Wh0, const float* __restrict__ Wh1,
                         const float* __restrict__ Wg, const float* __restrict__ Wl,
                         short* __restrict__ wtzr, short* __restrict__ wth,
                         short* __restrict__ wtg, short* __restrict__ wtl) {
  int i = blockIdx.x * blockDim.x + threadIdx.x;
  if (i < 65536) {
    int n = i >> 8, k = i & 255;
    float v = (n < 128) ? (Wz0[k * 128 + n] + Wz1[k * 128 + n])
                        : (Wr0[k * 128 + (n - 128)] + Wr1[k * 128 + (n - 128)]);
    wtzr[i] = (short)f2bf(v);
  } else if (i < 98304) {
    int j = i - 65536; int n = j >> 8, k = j & 255;
    wth[j] = (short)f2bf(Wh0[k * 128 + n] + Wh1[k * 128 + n]);
  } else if (i < 114688) {
    int j = i - 98304; int n = j >> 7, k = j & 127;
    wtg[j] = (short)f2bf(Wg[k * 128 + n]);
  } else if (i < 116736) {
    int j = i - 114688; int n = j >> 7, k = j & 127;
    wtl[j] = (short)f2bf(Wl[k * 16 + n]);
  }
}

// fold bg into gate biases: b'[c] = b[c] + sum_k bg[k] * (W0+W1)[k][c]
__global__ void k_prep_bias(const float* __restrict__ bg,
                            const float* __restrict__ Wz0, const float* __restrict__ Wz1,
                            const float* __restrict__ Wr0, const float* __restrict__ Wr1,
                            const float* __restrict__ Wh0, const float* __restrict__ Wh1,
                            const float* __restrict__ bz, const float* __restrict__ br,
                            const float* __restrict__ bh,
                            float* __restrict__ bzp, float* __restrict__ brp,
                            float* __restrict__ bhp) {
  int c = threadIdx.x;
  if (c >= 128) return;
  float sz = bz[c], sr = br[c], sh = bh[c];
  for (int k = 0; k < 128; ++k) {
    float g = bg[k];
    sz += g * (Wz0[k * 128 + c] + Wz1[k * 128 + c]);
    sr += g * (Wr0[k * 128 + c] + Wr1[k * 128 + c]);
    sh += g * (Wh0[k * 128 + c] + Wh1[k * 128 + c]);
  }
  bzp[c] = sz; brp[c] = sr; bhp[c] = sh;
}

// ---------------- CSR build ----------------

__global__ void k_init(float* __restrict__ deg, int* __restrict__ cnt,
                       int* __restrict__ fill) {
  int i = blockIdx.x * blockDim.x + threadIdx.x;
  if (i < NN) { deg[i] = 1.0f; cnt[i] = 0; fill[i] = 0; }
}

__global__ void k_deg_hist(const int* __restrict__ dst, const float* __restrict__ ew,
                           float* __restrict__ deg, int* __restrict__ cnt) {
  int i = blockIdx.x * blockDim.x + threadIdx.x;
  int stride = gridDim.x * blockDim.x;
  for (int e = i; e < NE; e += stride) {
    int d = dst[e];
    atomicAdd(&deg[d], ew[e]);
    atomicAdd(&cnt[d], 1);
  }
}

__global__ void k_dinv(float* __restrict__ deg) {
  int i = blockIdx.x * blockDim.x + threadIdx.x;
  if (i < NN) deg[i] = rsqrtf(deg[i]);
}

// hierarchical exclusive scan of cnt[NN] -> base[NN+1]
// level 1: per-block (256 elems) exclusive scan + block sums
__global__ __launch_bounds__(256) void k_scan1(const int* __restrict__ cnt,
                                               int* __restrict__ base,
                                               int* __restrict__ bsum) {
  __shared__ int ts[256];
  const int t = threadIdx.x, b = blockIdx.x;
  const int i = b * 256 + t;
  int v = (i < NN) ? cnt[i] : 0;
  ts[t] = v;
  __syncthreads();
#pragma unroll
  for (int off = 1; off < 256; off <<= 1) {
    int u = (t >= off) ? ts[t - off] : 0;
    __syncthreads();
    ts[t] += u;
    __syncthreads();
  }
  if (i < NN) base[i] = ts[t] - v;
  if (t == 255) bsum[b] = ts[255];
}

// level 2: scan the 196 block sums; also writes base[NN] = total (== NE)
__global__ __launch_bounds__(256) void k_scan2(const int* __restrict__ bsum,
                                               int* __restrict__ boff,
                                               int* __restrict__ base) {
  __shared__ int ts[256];
  const int t = threadIdx.x;
  int v = (t < SCAN_B) ? bsum[t] : 0;
  ts[t] = v;
  __syncthreads();
#pragma unroll
  for (int off = 1; off < 256; off <<= 1) {
    int u = (t >= off) ? ts[t - off] : 0;
    __syncthreads();
    ts[t] += u;
    __syncthreads();
  }
  if (t < SCAN_B) boff[t] = ts[t] - v;
  if (t == 255) base[NN] = ts[255];
}

// level 3: add block offsets
__global__ __launch_bounds__(256) void k_scan3(int* __restrict__ base,
                                               const int* __restrict__ boff) {
  const int i = blockIdx.x * 256 + threadIdx.x;
  if (i < NN) base[i] += boff[blockIdx.x];
}

__global__ void k_reorder(const int* __restrict__ ei, const float* __restrict__ ew,
                          const float* __restrict__ dinv, const int* __restrict__ base,
                          int* __restrict__ fill, int* __restrict__ src_s,
                          float* __restrict__ nrm_s) {
  int i = blockIdx.x * blockDim.x + threadIdx.x;
  int stride = gridDim.x * blockDim.x;
  const int* __restrict__ src = ei;
  const int* __restrict__ dst = ei + NE;
  for (int e = i; e < NE; e += stride) {
    int s = src[e], d = dst[e];
    int pos = base[d] + atomicAdd(&fill[d], 1);
    src_s[pos] = s;
    nrm_s[pos] = dinv[s] * ew[e] * dinv[d];
  }
}

// ---------------- MFMA GEMM: xw = x @ Wg ; agg = xw * dinv^2 --------------
// block = 64 rows x 128 cols, 4 waves, wave w -> cols [w*32, w*32+32)

__global__ __launch_bounds__(256) void k_xw_mfma(
    const float* __restrict__ x, const short* __restrict__ wtg,
    const float* __restrict__ dinv, float* __restrict__ xw, float* __restrict__ agg) {
  __shared__ __align__(16) short As[64][40];
  const int tid = threadIdx.x;
  const int w = tid >> 6, l = tid & 63, g = l >> 4, ln = l & 15;
  const int n0 = blockIdx.x * 64;
  const int srow = tid >> 2, sk0 = (tid & 3) << 3;
  const s16x8* wt8 = (const s16x8*)wtg;  // row = 128 shorts = 16 units

  f32x4 acc[4][2];
#pragma unroll
  for (int mi = 0; mi < 4; ++mi)
#pragma unroll
    for (int ni = 0; ni < 2; ++ni) acc[mi][ni] = (f32x4){0.f, 0.f, 0.f, 0.f};

  for (int kci = 0; kci < 4; ++kci) {
    int kg = kci * 32 + sk0;
    int n = n0 + srow;
    s16x8 av = {0, 0, 0, 0, 0, 0, 0, 0};
    if (n < NN) {
      const float* src = x + (size_t)n * FD + kg;
      float4 f0 = *(const float4*)src;
      float4 f1 = *(const float4*)(src + 4);
      av[0] = (short)f2bf(f0.x); av[1] = (short)f2bf(f0.y);
      av[2] = (short)f2bf(f0.z); av[3] = (short)f2bf(f0.w);
      av[4] = (short)f2bf(f1.x); av[5] = (short)f2bf(f1.y);
      av[6] = (short)f2bf(f1.z); av[7] = (short)f2bf(f1.w);
    }
    __syncthreads();
    *(s16x8*)&As[srow][sk0] = av;
    __syncthreads();
    s16x8 b[2], a[4];
#pragma unroll
    for (int ni = 0; ni < 2; ++ni) {
      int col = w * 32 + ni * 16 + ln;
      b[ni] = wt8[(size_t)col * 16 + kci * 4 + g];
    }
#pragma unroll
    for (int mi = 0; mi < 4; ++mi) a[mi] = *(const s16x8*)&As[mi * 16 + ln][g * 8];
#pragma unroll
    for (int mi = 0; mi < 4; ++mi)
#pragma unroll
      for (int ni = 0; ni < 2; ++ni)
        acc[mi][ni] = __builtin_amdgcn_mfma_f32_16x16x32_bf16(a[mi], b[ni], acc[mi][ni], 0, 0, 0);
  }
#pragma unroll
  for (int mi = 0; mi < 4; ++mi) {
#pragma unroll
    for (int r = 0; r < 4; ++r) {
      int n = n0 + mi * 16 + g * 4 + r;
      if (n >= NN) continue;
      float di = dinv[n];
      float d2 = di * di;
#pragma unroll
      for (int ni = 0; ni < 2; ++ni) {
        int c = w * 32 + ni * 16 + ln;
        float v = acc[mi][ni][r];
        xw[(size_t)n * FD + c] = v;
        agg[(size_t)n * FD + c] = v * d2;
      }
    }
  }
}

// ---------------- CSR gather (verified) ----------------

__global__ __launch_bounds__(256) void k_gather(
    const int* __restrict__ base, const int* __restrict__ src_s,
    const float* __restrict__ nrm_s, const float* __restrict__ xw,
    float* __restrict__ agg) {
  const int lane = threadIdx.x & 63;
  const int n = blockIdx.x * 4 + (threadIdx.x >> 6);
  if (n >= NN) return;
  const int e0 = base[n], e1 = base[n + 1];
  const int c = lane * 2;
  float* ap = agg + (size_t)n * FD + c;
  float2 acc = *(const float2*)ap;
  int e = e0;
  for (; e + 4 <= e1; e += 4) {
    int s0 = src_s[e], s1 = src_s[e + 1], s2 = src_s[e + 2], s3 = src_s[e + 3];
    float w0 = nrm_s[e], w1 = nrm_s[e + 1], w2 = nrm_s[e + 2], w3 = nrm_s[e + 3];
    float2 v0 = *(const float2*)(xw + (size_t)s0 * FD + c);
    float2 v1 = *(const float2*)(xw + (size_t)s1 * FD + c);
    float2 v2 = *(const float2*)(xw + (size_t)s2 * FD + c);
    float2 v3 = *(const float2*)(xw + (size_t)s3 * FD + c);
    acc.x = fmaf(w0, v0.x, acc.x); acc.y = fmaf(w0, v0.y, acc.y);
    acc.x = fmaf(w1, v1.x, acc.x); acc.y = fmaf(w1, v1.y, acc.y);
    acc.x = fmaf(w2, v2.x, acc.x); acc.y = fmaf(w2, v2.y, acc.y);
    acc.x = fmaf(w3, v3.x, acc.x); acc.y = fmaf(w3, v3.y, acc.y);
  }
  for (; e < e1; ++e) {
    int s = src_s[e];
    float wv = nrm_s[e];
    float2 v = *(const float2*)(xw + (size_t)s * FD + c);
    acc.x = fmaf(wv, v.x, acc.x); acc.y = fmaf(wv, v.y, acc.y);
  }
  *(float2*)ap = acc;
}

// ---------------- MFMA ZR: [agg|hs] @ wtzr^T -> Z (fp32), hsr (bf16) ------
// block = 64 rows x 256 cols, wave w -> cols [w*64, w*64+64)

__global__ __launch_bounds__(256) void k_zr_mfma(
    const float* __restrict__ agg, const float* __restrict__ hs,
    const short* __restrict__ wtzr, const float* __restrict__ bzp,
    const float* __restrict__ brp, float* __restrict__ Zb,
    short* __restrict__ hsr16) {
  __shared__ __align__(16) short As[64][40];
  const int tid = threadIdx.x;
  const int w = tid >> 6, l = tid & 63, g = l >> 4, ln = l & 15;
  const int n0 = blockIdx.x * 64;
  const int srow = tid >> 2, sk0 = (tid & 3) << 3;
  const s16x8* wt8 = (const s16x8*)wtzr;  // row = 256 shorts = 32 units

  f32x4 acc[4][4];
#pragma unroll
  for (int mi = 0; mi < 4; ++mi)
#pragma unroll
    for (int ni = 0; ni < 4; ++ni) acc[mi][ni] = (f32x4){0.f, 0.f, 0.f, 0.f};

  for (int kci = 0; kci < 8; ++kci) {
    int kg = kci * 32 + sk0;
    int n = n0 + srow;
    s16x8 av = {0, 0, 0, 0, 0, 0, 0, 0};
    if (n < NN) {
      const float* src = (kg < FD) ? (agg + (size_t)n * FD + kg)
                                   : (hs + (size_t)n * FD + (kg - FD));
      float4 f0 = *(const float4*)src;
      float4 f1 = *(const float4*)(src + 4);
      av[0] = (short)f2bf(f0.x); av[1] = (short)f2bf(f0.y);
      av[2] = (short)f2bf(f0.z); av[3] = (short)f2bf(f0.w);
      av[4] = (short)f2bf(f1.x); av[5] = (short)f2bf(f1.y);
      av[6] = (short)f2bf(f1.z); av[7] = (short)f2bf(f1.w);
    }
    __syncthreads();
    *(s16x8*)&As[srow][sk0] = av;
    __syncthreads();
    s16x8 b[4], a[4];
#pragma unroll
    for (int ni = 0; ni < 4; ++ni) {
      int col = w * 64 + ni * 16 + ln;
      b[ni] = wt8[(size_t)col * 32 + kci * 4 + g];
    }
#pragma unroll
    for (int mi = 0; mi < 4; ++mi) a[mi] = *(const s16x8*)&As[mi * 16 + ln][g * 8];
#pragma unroll
    for (int mi = 0; mi < 4; ++mi)
#pragma unroll
      for (int ni = 0; ni < 4; ++ni)
        acc[mi][ni] = __builtin_amdgcn_mfma_f32_16x16x32_bf16(a[mi], b[ni], acc[mi][ni], 0, 0, 0);
  }
  float bias[4];
  int colv[4];
#pragma unroll
  for (int ni = 0; ni < 4; ++ni) {
    colv[ni] = w * 64 + ni * 16 + ln;
    bias[ni] = (colv[ni] < FD) ? bzp[colv[ni]] : brp[colv[ni] - FD];
  }
#pragma unroll
  for (int mi = 0; mi < 4; ++mi) {
#pragma unroll
    for (int r = 0; r < 4; ++r) {
      int n = n0 + mi * 16 + g * 4 + r;
      if (n >= NN) continue;
#pragma unroll
      for (int ni = 0; ni < 4; ++ni) {
        float sv = sigmoidf_(acc[mi][ni][r] + bias[ni]);
        if (colv[ni] < FD) {
          Zb[(size_t)n * FD + colv[ni]] = sv;
        } else {
          int cc = colv[ni] - FD;
          hsr16[(size_t)n * FD + cc] = (short)f2bf(sv * hs[(size_t)n * FD + cc]);
        }
      }
    }
  }
}

// ---------------- MFMA Ht + Hn + classifier + softmax --------------------
// block = 64 rows x 128 cols, wave w -> cols [w*32, w*32+32)

__global__ __launch_bounds__(256) void k_ht_mfma(
    const float* __restrict__ agg, const short* __restrict__ hsr16,
    const short* __restrict__ wth, const float* __restrict__ bhp,
    const float* __restrict__ Zb, const float* __restrict__ hs,
    const short* __restrict__ wtl, const float* __restrict__ bl,
    float* __restrict__ probs, float* __restrict__ Hn) {
  __shared__ __align__(16) short As[64][40];
  __shared__ __align__(16) short HnL[64][136];
  const int tid = threadIdx.x;
  const int w = tid >> 6, l = tid & 63, g = l >> 4, ln = l & 15;
  const int n0 = blockIdx.x * 64;
  const int srow = tid >> 2, sk0 = (tid & 3) << 3;
  const s16x8* wt8 = (const s16x8*)wth;  // row = 256 shorts = 32 units

  f32x4 acc[4][2];
#pragma unroll
  for (int mi = 0; mi < 4; ++mi)
#pragma unroll
    for (int ni = 0; ni < 2; ++ni) acc[mi][ni] = (f32x4){0.f, 0.f, 0.f, 0.f};

  for (int kci = 0; kci < 8; ++kci) {
    int kg = kci * 32 + sk0;
    int n = n0 + srow;
    s16x8 av = {0, 0, 0, 0, 0, 0, 0, 0};
    if (n < NN) {
      if (kg < FD) {
        const float* src = agg + (size_t)n * FD + kg;
        float4 f0 = *(const float4*)src;
        float4 f1 = *(const float4*)(src + 4);
        av[0] = (short)f2bf(f0.x); av[1] = (short)f2bf(f0.y);
        av[2] = (short)f2bf(f0.z); av[3] = (short)f2bf(f0.w);
        av[4] = (short)f2bf(f1.x); av[5] = (short)f2bf(f1.y);
        av[6] = (short)f2bf(f1.z); av[7] = (short)f2bf(f1.w);
      } else {
        av = *(const s16x8*)(hsr16 + (size_t)n * FD + (kg - FD));
      }
    }
    __syncthreads();
    *(s16x8*)&As[srow][sk0] = av;
    __syncthreads();
    s16x8 b[2], a[4];
#pragma unroll
    for (int ni = 0; ni < 2; ++ni) {
      int col = w * 32 + ni * 16 + ln;
      b[ni] = wt8[(size_t)col * 32 + kci * 4 + g];
    }
#pragma unroll
    for (int mi = 0; mi < 4; ++mi) a[mi] = *(const s16x8*)&As[mi * 16 + ln][g * 8];
#pragma unroll
    for (int mi = 0; mi < 4; ++mi)
#pragma unroll
      for (int ni = 0; ni < 2; ++ni)
        acc[mi][ni] = __builtin_amdgcn_mfma_f32_16x16x32_bf16(a[mi], b[ni], acc[mi][ni], 0, 0, 0);
  }

  float bh_c[2];
#pragma unroll
  for (int ni = 0; ni < 2; ++ni) bh_c[ni] = bhp[w * 32 + ni * 16 + ln];

#pragma unroll
  for (int mi = 0; mi < 4; ++mi) {
#pragma unroll
    for (int r = 0; r < 4; ++r) {
      int lr = mi * 16 + g * 4 + r;
      int n = n0 + lr;
#pragma unroll
      for (int ni = 0; ni < 2; ++ni) {
        int c = w * 32 + ni * 16 + ln;
        if (n < NN) {
          float z = Zb[(size_t)n * FD + c];
          float hv = hs[(size_t)n * FD + c];
          float ht = tanhf(acc[mi][ni][r] + bh_c[ni]);
          float hn = z * hv + (1.f - z) * ht;
          Hn[(size_t)n * FD + c] = hn;
          HnL[lr][c] = (short)f2bf(fmaxf(hn, 0.f));
        } else {
          HnL[lr][c] = 0;
        }
      }
    }
  }
  __syncthreads();

  // classifier: wave w handles rows [w*16, w*16+16); 16 output classes
  f32x4 ac = (f32x4){0.f, 0.f, 0.f, 0.f};
  const s16x8* wtl8 = (const s16x8*)wtl;  // row = 128 shorts = 16 units
#pragma unroll
  for (int kci = 0; kci < 4; ++kci) {
    s16x8 a = *(const s16x8*)&HnL[w * 16 + ln][kci * 32 + g * 8];
    s16x8 bfr = wtl8[ln * 16 + kci * 4 + g];
    ac = __builtin_amdgcn_mfma_f32_16x16x32_bf16(a, bfr, ac, 0, 0, 0);
  }
  float blv = bl[ln];
#pragma unroll
  for (int r = 0; r < 4; ++r) {
    int n = n0 + w * 16 + g * 4 + r;
    float v = ac[r] + blv;
    float m = v;
#pragma unroll
    for (int msk = 1; msk < 16; msk <<= 1) m = fmaxf(m, __shfl_xor(m, msk, 64));
    float e = expf(v - m);
    float s = e;
#pragma unroll
    for (int msk = 1; msk < 16; msk <<= 1) s += __shfl_xor(s, msk, 64);
    if (n < NN) probs[(size_t)n * NCLS + ln] = e / s;
  }
}

// ---------------- launch ----------------

extern "C" void kernel_launch(void* const* d_in, const int* in_sizes, int n_in,
                              void* d_out, int out_size, void* d_ws, size_t ws_size,
                              hipStream_t stream) {
  (void)in_sizes; (void)n_in; (void)out_size; (void)ws_size;
  const float* x   = (const float*)d_in[0];
  const int*   ei  = (const int*)d_in[1];
  const float* ew  = (const float*)d_in[2];
  const float* hs  = (const float*)d_in[3];
  const float* Wg  = (const float*)d_in[4];
  const float* bg  = (const float*)d_in[5];
  const float* Wz0 = (const float*)d_in[6];
  const float* Wz1 = (const float*)d_in[7];
  const float* bz  = (const float*)d_in[8];
  const float* Wr0 = (const float*)d_in[9];
  const float* Wr1 = (const float*)d_in[10];
  const float* br  = (const float*)d_in[11];
  const float* Wh0 = (const float*)d_in[12];
  const float* Wh1 = (const float*)d_in[13];
  const float* bh  = (const float*)d_in[14];
  const float* Wl  = (const float*)d_in[15];
  const float* bl  = (const float*)d_in[16];

  float* out   = (float*)d_out;
  float* probs = out;                      // [NN,16]
  float* Hn    = out + (size_t)NN * NCLS;  // [NN,128]

  float* w    = (float*)d_ws;
  float* dinv = w;                             // [NN]
  float* xw   = w + 50048;                     // [NN*FD]; reused as Zb
  float* agg  = xw + (size_t)NN * FD;          // [NN*FD]
  float* hsrf = agg + (size_t)NN * FD;         // [NN*FD] region: CSR scratch, then hsr16
  float* wsp  = hsrf + (size_t)NN * FD;        // tail: bf16 weights + biases
  float* Zb   = xw;
  short* hsr16 = (short*)hsrf;

  short* wtzr = (short*)wsp;                       // 65536 shorts
  short* wth  = (short*)(wsp + 32768);             // 32768 shorts
  short* wtg  = (short*)(wsp + 32768 + 16384);     // 16384 shorts
  short* wtl  = (short*)(wsp + 32768 + 16384 + 8192);  // 2048 shorts
  float* bzp  = wsp + 32768 + 16384 + 8192 + 1024;
  float* brp  = bzp + 128;
  float* bhp  = brp + 128;

  // CSR scratch aliased onto hsr region (dead before k_zr writes hsr16)
  int*   src_s = (int*)hsrf;                        // [NE]
  float* nrm_s = hsrf + NE;                         // [NE]
  int*   cnt   = (int*)(hsrf + 2 * NE);             // [NN]
  int*   basep = (int*)(hsrf + 2 * NE + NN);        // [NN+1]
  int*   fill  = (int*)(hsrf + 2 * NE + 2 * NN + 1);// [NN]
  int*   bsum  = (int*)(hsrf + 2 * NE + 3 * NN + 1);// [SCAN_B]
  int*   boff  = bsum + 256;                        // [SCAN_B]

  k_prep_w<<<456, 256, 0, stream>>>(Wz0, Wz1, Wr0, Wr1, Wh0, Wh1, Wg, Wl,
                                    wtzr, wth, wtg, wtl);
  k_prep_bias<<<1, 128, 0, stream>>>(bg, Wz0, Wz1, Wr0, Wr1, Wh0, Wh1,
                                     bz, br, bh, bzp, brp, bhp);
  k_init<<<196, 256, 0, stream>>>(dinv, cnt, fill);
  k_deg_hist<<<1024, 256, 0, stream>>>(ei + NE, ew, dinv, cnt);
  k_dinv<<<196, 256, 0, stream>>>(dinv);
  k_scan1<<<SCAN_B, 256, 0, stream>>>(cnt, basep, bsum);
  k_scan2<<<1, 256, 0, stream>>>(bsum, boff, basep);
  k_scan3<<<SCAN_B, 256, 0, stream>>>(basep, boff);
  k_reorder<<<1024, 256, 0, stream>>>(ei, ew, dinv, basep, fill, src_s, nrm_s);
  k_xw_mfma<<<782, 256, 0, stream>>>(x, wtg, dinv, xw, agg);
  k_gather<<<12500, 256, 0, stream>>>(basep, src_s, nrm_s, xw, agg);
  k_zr_mfma<<<782, 256, 0, stream>>>(agg, hs, wtzr, bzp, brp, Zb, hsr16);
  k_ht_mfma<<<782, 256, 0, stream>>>(agg, hsr16, wth, bhp, Zb, hs, wtl, bl, probs, Hn);
}

// Round 10
// 270.375 us; speedup vs baseline: 3.5789x; 1.1475x over previous
//
#include <hip/hip_runtime.h>
#include <math.h>

#define NN 50000
#define NE 800000
#define FD 128
#define CIN 256
#define NCLS 16
#define SCAN_B 196   // ceil(NN/256)
#define NCOPY 16

typedef short s16x8 __attribute__((ext_vector_type(8)));
typedef float f32x4 __attribute__((ext_vector_type(4)));

__device__ __forceinline__ unsigned short f2bf(float f) {
  union { float f; unsigned u; } v; v.f = f;
  unsigned r = v.u + 0x7fffu + ((v.u >> 16) & 1u);
  return (unsigned short)(r >> 16);
}

__device__ __forceinline__ float sigmoidf_(float x) {
  return 1.0f / (1.0f + expf(-x));
}

// ---------------- weight prep: bf16 transposed WT[col][k] ----------------

__global__ void k_prep_w(const float* __restrict__ Wz0, const float* __restrict__ Wz1,
                         const float* __restrict__ Wr0, const float* __restrict__ Wr1,
                         const float* __restrict__ Wh0, const float* __restrict__ Wh1,
                         const float* __restrict__ Wg, const float* __restrict__ Wl,
                         short* __restrict__ wtzr, short* __restrict__ wth,
                         short* __restrict__ wtg, short* __restrict__ wtl) {
  int i = blockIdx.x * blockDim.x + threadIdx.x;
  if (i < 65536) {
    int n = i >> 8, k = i & 255;
    float v = (n < 128) ? (Wz0[k * 128 + n] + Wz1[k * 128 + n])
                        : (Wr0[k * 128 + (n - 128)] + Wr1[k * 128 + (n - 128)]);
    wtzr[i] = (short)f2bf(v);
  } else if (i < 98304) {
    int j = i - 65536; int n = j >> 8, k = j & 255;
    wth[j] = (short)f2bf(Wh0[k * 128 + n] + Wh1[k * 128 + n]);
  } else if (i < 114688) {
    int j = i - 98304; int n = j >> 7, k = j & 127;
    wtg[j] = (short)f2bf(Wg[k * 128 + n]);
  } else if (i < 116736) {
    int j = i - 114688; int n = j >> 7, k = j & 127;
    wtl[j] = (short)f2bf(Wl[k * 16 + n]);
  }
}

// fold bg into gate biases: b'[c] = b[c] + sum_k bg[k] * (W0+W1)[k][c]
__global__ void k_prep_bias(const float* __restrict__ bg,
                            const float* __restrict__ Wz0, const float* __restrict__ Wz1,
                            const float* __restrict__ Wr0, const float* __restrict__ Wr1,
                            const float* __restrict__ Wh0, const float* __restrict__ Wh1,
                            const float* __restrict__ bz, const float* __restrict__ br,
                            const float* __restrict__ bh,
                            float* __restrict__ bzp, float* __restrict__ brp,
                            float* __restrict__ bhp) {
  int c = threadIdx.x;
  if (c >= 128) return;
  float sz = bz[c], sr = br[c], sh = bh[c];
  for (int k = 0; k < 128; ++k) {
    float g = bg[k];
    sz += g * (Wz0[k * 128 + c] + Wz1[k * 128 + c]);
    sr += g * (Wr0[k * 128 + c] + Wr1[k * 128 + c]);
    sh += g * (Wh0[k * 128 + c] + Wh1[k * 128 + c]);
  }
  bzp[c] = sz; brp[c] = sr; bhp[c] = sh;
}

// ---------------- CSR build: privatized packed histogram ----------------
// parts[c][i] u64: bits 40+ = edge count, bits 0..39 = sum(ew * 2^32)

__global__ void k_zero_parts(unsigned long long* __restrict__ parts) {
  int i = blockIdx.x * blockDim.x + threadIdx.x;
  int stride = gridDim.x * blockDim.x;
  for (; i < NCOPY * NN; i += stride) parts[i] = 0ULL;
}

__global__ void k_hist(const int* __restrict__ dst, const float* __restrict__ ew,
                       unsigned long long* __restrict__ parts) {
  const int c = blockIdx.x & (NCOPY - 1);
  unsigned long long* __restrict__ p = parts + (size_t)c * NN;
  int i = blockIdx.x * blockDim.x + threadIdx.x;
  int stride = gridDim.x * blockDim.x;
  for (int e = i; e < NE; e += stride) {
    int d = dst[e];
    unsigned long long pk = (1ULL << 40) +
        (unsigned long long)(ew[e] * 4294967296.0f + 0.5f);
    atomicAdd(&p[d], pk);
  }
}

// fold copies -> cnt + dinv = rsqrt(1 + wsum)
__global__ void k_reduce(const unsigned long long* __restrict__ parts,
                         float* __restrict__ dinv, int* __restrict__ cnt) {
  int i = blockIdx.x * blockDim.x + threadIdx.x;
  if (i >= NN) return;
  int ct = 0;
  double frac = 0.0;
#pragma unroll
  for (int c = 0; c < NCOPY; ++c) {
    unsigned long long v = parts[(size_t)c * NN + i];
    ct += (int)(v >> 40);
    frac += (double)(v & 0xFFFFFFFFFFULL);
  }
  cnt[i] = ct;
  double deg = 1.0 + frac * (1.0 / 4294967296.0);
  dinv[i] = rsqrtf((float)deg);
}

// hierarchical exclusive scan of cnt[NN] -> base[NN+1]
__global__ __launch_bounds__(256) void k_scan1(const int* __restrict__ cnt,
                                               int* __restrict__ base,
                                               int* __restrict__ bsum) {
  __shared__ int ts[256];
  const int t = threadIdx.x, b = blockIdx.x;
  const int i = b * 256 + t;
  int v = (i < NN) ? cnt[i] : 0;
  ts[t] = v;
  __syncthreads();
#pragma unroll
  for (int off = 1; off < 256; off <<= 1) {
    int u = (t >= off) ? ts[t - off] : 0;
    __syncthreads();
    ts[t] += u;
    __syncthreads();
  }
  if (i < NN) base[i] = ts[t] - v;
  if (t == 255) bsum[b] = ts[255];
}

__global__ __launch_bounds__(256) void k_scan2(const int* __restrict__ bsum,
                                               int* __restrict__ boff,
                                               int* __restrict__ base) {
  __shared__ int ts[256];
  const int t = threadIdx.x;
  int v = (t < SCAN_B) ? bsum[t] : 0;
  ts[t] = v;
  __syncthreads();
#pragma unroll
  for (int off = 1; off < 256; off <<= 1) {
    int u = (t >= off) ? ts[t - off] : 0;
    __syncthreads();
    ts[t] += u;
    __syncthreads();
  }
  if (t < SCAN_B) boff[t] = ts[t] - v;
  if (t == 255) base[NN] = ts[255];
}

// level 3: finalize base, carve per-copy cursor ranges off16[c][i]
__global__ __launch_bounds__(256) void k_scan3(int* __restrict__ base,
                                               const int* __restrict__ boff,
                                               const unsigned long long* __restrict__ parts,
                                               int* __restrict__ off16) {
  const int i = blockIdx.x * 256 + threadIdx.x;
  if (i >= NN) return;
  int b = base[i] + boff[blockIdx.x];
  base[i] = b;
  int run = b;
#pragma unroll
  for (int c = 0; c < NCOPY; ++c) {
    off16[(size_t)c * NN + i] = run;
    run += (int)(parts[(size_t)c * NN + i] >> 40);
  }
}

// scatter edges into dst-sorted order via per-copy cursors
// NOTE: grid/stride and c = blockIdx&15 MUST match k_hist exactly
__global__ void k_reorder(const int* __restrict__ ei, const float* __restrict__ ew,
                          const float* __restrict__ dinv,
                          int* __restrict__ off16, int* __restrict__ src_s,
                          float* __restrict__ nrm_s) {
  const int c = blockIdx.x & (NCOPY - 1);
  int* __restrict__ cur = off16 + (size_t)c * NN;
  int i = blockIdx.x * blockDim.x + threadIdx.x;
  int stride = gridDim.x * blockDim.x;
  const int* __restrict__ src = ei;
  const int* __restrict__ dst = ei + NE;
  for (int e = i; e < NE; e += stride) {
    int s = src[e], d = dst[e];
    int pos = atomicAdd(&cur[d], 1);
    src_s[pos] = s;
    nrm_s[pos] = dinv[s] * ew[e] * dinv[d];
  }
}

// ---------------- MFMA GEMM: xw = x @ Wg ; agg = xw * dinv^2 --------------

__global__ __launch_bounds__(256) void k_xw_mfma(
    const float* __restrict__ x, const short* __restrict__ wtg,
    const float* __restrict__ dinv, float* __restrict__ xw, float* __restrict__ agg) {
  __shared__ __align__(16) short As[64][40];
  const int tid = threadIdx.x;
  const int w = tid >> 6, l = tid & 63, g = l >> 4, ln = l & 15;
  const int n0 = blockIdx.x * 64;
  const int srow = tid >> 2, sk0 = (tid & 3) << 3;
  const s16x8* wt8 = (const s16x8*)wtg;

  f32x4 acc[4][2];
#pragma unroll
  for (int mi = 0; mi < 4; ++mi)
#pragma unroll
    for (int ni = 0; ni < 2; ++ni) acc[mi][ni] = (f32x4){0.f, 0.f, 0.f, 0.f};

  for (int kci = 0; kci < 4; ++kci) {
    int kg = kci * 32 + sk0;
    int n = n0 + srow;
    s16x8 av = {0, 0, 0, 0, 0, 0, 0, 0};
    if (n < NN) {
      const float* src = x + (size_t)n * FD + kg;
      float4 f0 = *(const float4*)src;
      float4 f1 = *(const float4*)(src + 4);
      av[0] = (short)f2bf(f0.x); av[1] = (short)f2bf(f0.y);
      av[2] = (short)f2bf(f0.z); av[3] = (short)f2bf(f0.w);
      av[4] = (short)f2bf(f1.x); av[5] = (short)f2bf(f1.y);
      av[6] = (short)f2bf(f1.z); av[7] = (short)f2bf(f1.w);
    }
    __syncthreads();
    *(s16x8*)&As[srow][sk0] = av;
    __syncthreads();
    s16x8 b[2], a[4];
#pragma unroll
    for (int ni = 0; ni < 2; ++ni) {
      int col = w * 32 + ni * 16 + ln;
      b[ni] = wt8[(size_t)col * 16 + kci * 4 + g];
    }
#pragma unroll
    for (int mi = 0; mi < 4; ++mi) a[mi] = *(const s16x8*)&As[mi * 16 + ln][g * 8];
#pragma unroll
    for (int mi = 0; mi < 4; ++mi)
#pragma unroll
      for (int ni = 0; ni < 2; ++ni)
        acc[mi][ni] = __builtin_amdgcn_mfma_f32_16x16x32_bf16(a[mi], b[ni], acc[mi][ni], 0, 0, 0);
  }
#pragma unroll
  for (int mi = 0; mi < 4; ++mi) {
#pragma unroll
    for (int r = 0; r < 4; ++r) {
      int n = n0 + mi * 16 + g * 4 + r;
      if (n >= NN) continue;
      float di = dinv[n];
      float d2 = di * di;
#pragma unroll
      for (int ni = 0; ni < 2; ++ni) {
        int c = w * 32 + ni * 16 + ln;
        float v = acc[mi][ni][r];
        xw[(size_t)n * FD + c] = v;
        agg[(size_t)n * FD + c] = v * d2;
      }
    }
  }
}

// ---------------- CSR gather (verified) ----------------

__global__ __launch_bounds__(256) void k_gather(
    const int* __restrict__ base, const int* __restrict__ src_s,
    const float* __restrict__ nrm_s, const float* __restrict__ xw,
    float* __restrict__ agg) {
  const int lane = threadIdx.x & 63;
  const int n = blockIdx.x * 4 + (threadIdx.x >> 6);
  if (n >= NN) return;
  const int e0 = base[n], e1 = base[n + 1];
  const int c = lane * 2;
  float* ap = agg + (size_t)n * FD + c;
  float2 acc = *(const float2*)ap;
  int e = e0;
  for (; e + 4 <= e1; e += 4) {
    int s0 = src_s[e], s1 = src_s[e + 1], s2 = src_s[e + 2], s3 = src_s[e + 3];
    float w0 = nrm_s[e], w1 = nrm_s[e + 1], w2 = nrm_s[e + 2], w3 = nrm_s[e + 3];
    float2 v0 = *(const float2*)(xw + (size_t)s0 * FD + c);
    float2 v1 = *(const float2*)(xw + (size_t)s1 * FD + c);
    float2 v2 = *(const float2*)(xw + (size_t)s2 * FD + c);
    float2 v3 = *(const float2*)(xw + (size_t)s3 * FD + c);
    acc.x = fmaf(w0, v0.x, acc.x); acc.y = fmaf(w0, v0.y, acc.y);
    acc.x = fmaf(w1, v1.x, acc.x); acc.y = fmaf(w1, v1.y, acc.y);
    acc.x = fmaf(w2, v2.x, acc.x); acc.y = fmaf(w2, v2.y, acc.y);
    acc.x = fmaf(w3, v3.x, acc.x); acc.y = fmaf(w3, v3.y, acc.y);
  }
  for (; e < e1; ++e) {
    int s = src_s[e];
    float wv = nrm_s[e];
    float2 v = *(const float2*)(xw + (size_t)s * FD + c);
    acc.x = fmaf(wv, v.x, acc.x); acc.y = fmaf(wv, v.y, acc.y);
  }
  *(float2*)ap = acc;
}

// ---------------- MFMA ZR: [agg|hs] @ wtzr^T -> Z (fp32), hsr (bf16) ------

__global__ __launch_bounds__(256) void k_zr_mfma(
    const float* __restrict__ agg, const float* __restrict__ hs,
    const short* __restrict__ wtzr, const float* __restrict__ bzp,
    const float* __restrict__ brp, float* __restrict__ Zb,
    short* __restrict__ hsr16) {
  __shared__ __align__(16) short As[64][40];
  const int tid = threadIdx.x;
  const int w = tid >> 6, l = tid & 63, g = l >> 4, ln = l & 15;
  const int n0 = blockIdx.x * 64;
  const int srow = tid >> 2, sk0 = (tid & 3) << 3;
  const s16x8* wt8 = (const s16x8*)wtzr;

  f32x4 acc[4][4];
#pragma unroll
  for (int mi = 0; mi < 4; ++mi)
#pragma unroll
    for (int ni = 0; ni < 4; ++ni) acc[mi][ni] = (f32x4){0.f, 0.f, 0.f, 0.f};

  for (int kci = 0; kci < 8; ++kci) {
    int kg = kci * 32 + sk0;
    int n = n0 + srow;
    s16x8 av = {0, 0, 0, 0, 0, 0, 0, 0};
    if (n < NN) {
      const float* src = (kg < FD) ? (agg + (size_t)n * FD + kg)
                                   : (hs + (size_t)n * FD + (kg - FD));
      float4 f0 = *(const float4*)src;
      float4 f1 = *(const float4*)(src + 4);
      av[0] = (short)f2bf(f0.x); av[1] = (short)f2bf(f0.y);
      av[2] = (short)f2bf(f0.z); av[3] = (short)f2bf(f0.w);
      av[4] = (short)f2bf(f1.x); av[5] = (short)f2bf(f1.y);
      av[6] = (short)f2bf(f1.z); av[7] = (short)f2bf(f1.w);
    }
    __syncthreads();
    *(s16x8*)&As[srow][sk0] = av;
    __syncthreads();
    s16x8 b[4], a[4];
#pragma unroll
    for (int ni = 0; ni < 4; ++ni) {
      int col = w * 64 + ni * 16 + ln;
      b[ni] = wt8[(size_t)col * 32 + kci * 4 + g];
    }
#pragma unroll
    for (int mi = 0; mi < 4; ++mi) a[mi] = *(const s16x8*)&As[mi * 16 + ln][g * 8];
#pragma unroll
    for (int mi = 0; mi < 4; ++mi)
#pragma unroll
      for (int ni = 0; ni < 4; ++ni)
        acc[mi][ni] = __builtin_amdgcn_mfma_f32_16x16x32_bf16(a[mi], b[ni], acc[mi][ni], 0, 0, 0);
  }
  float bias[4];
  int colv[4];
#pragma unroll
  for (int ni = 0; ni < 4; ++ni) {
    colv[ni] = w * 64 + ni * 16 + ln;
    bias[ni] = (colv[ni] < FD) ? bzp[colv[ni]] : brp[colv[ni] - FD];
  }
#pragma unroll
  for (int mi = 0; mi < 4; ++mi) {
#pragma unroll
    for (int r = 0; r < 4; ++r) {
      int n = n0 + mi * 16 + g * 4 + r;
      if (n >= NN) continue;
#pragma unroll
      for (int ni = 0; ni < 4; ++ni) {
        float sv = sigmoidf_(acc[mi][ni][r] + bias[ni]);
        if (colv[ni] < FD) {
          Zb[(size_t)n * FD + colv[ni]] = sv;
        } else {
          int cc = colv[ni] - FD;
          hsr16[(size_t)n * FD + cc] = (short)f2bf(sv * hs[(size_t)n * FD + cc]);
        }
      }
    }
  }
}

// ---------------- MFMA Ht + Hn + classifier + softmax --------------------

__global__ __launch_bounds__(256) void k_ht_mfma(
    const float* __restrict__ agg, const short* __restrict__ hsr16,
    const short* __restrict__ wth, const float* __restrict__ bhp,
    const float* __restrict__ Zb, const float* __restrict__ hs,
    const short* __restrict__ wtl, const float* __restrict__ bl,
    float* __restrict__ probs, float* __restrict__ Hn) {
  __shared__ __align__(16) short As[64][40];
  __shared__ __align__(16) short HnL[64][136];
  const int tid = threadIdx.x;
  const int w = tid >> 6, l = tid & 63, g = l >> 4, ln = l & 15;
  const int n0 = blockIdx.x * 64;
  const int srow = tid >> 2, sk0 = (tid & 3) << 3;
  const s16x8* wt8 = (const s16x8*)wth;

  f32x4 acc[4][2];
#pragma unroll
  for (int mi = 0; mi < 4; ++mi)
#pragma unroll
    for (int ni = 0; ni < 2; ++ni) acc[mi][ni] = (f32x4){0.f, 0.f, 0.f, 0.f};

  for (int kci = 0; kci < 8; ++kci) {
    int kg = kci * 32 + sk0;
    int n = n0 + srow;
    s16x8 av = {0, 0, 0, 0, 0, 0, 0, 0};
    if (n < NN) {
      if (kg < FD) {
        const float* src = agg + (size_t)n * FD + kg;
        float4 f0 = *(const float4*)src;
        float4 f1 = *(const float4*)(src + 4);
        av[0] = (short)f2bf(f0.x); av[1] = (short)f2bf(f0.y);
        av[2] = (short)f2bf(f0.z); av[3] = (short)f2bf(f0.w);
        av[4] = (short)f2bf(f1.x); av[5] = (short)f2bf(f1.y);
        av[6] = (short)f2bf(f1.z); av[7] = (short)f2bf(f1.w);
      } else {
        av = *(const s16x8*)(hsr16 + (size_t)n * FD + (kg - FD));
      }
    }
    __syncthreads();
    *(s16x8*)&As[srow][sk0] = av;
    __syncthreads();
    s16x8 b[2], a[4];
#pragma unroll
    for (int ni = 0; ni < 2; ++ni) {
      int col = w * 32 + ni * 16 + ln;
      b[ni] = wt8[(size_t)col * 32 + kci * 4 + g];
    }
#pragma unroll
    for (int mi = 0; mi < 4; ++mi) a[mi] = *(const s16x8*)&As[mi * 16 + ln][g * 8];
#pragma unroll
    for (int mi = 0; mi < 4; ++mi)
#pragma unroll
      for (int ni = 0; ni < 2; ++ni)
        acc[mi][ni] = __builtin_amdgcn_mfma_f32_16x16x32_bf16(a[mi], b[ni], acc[mi][ni], 0, 0, 0);
  }

  float bh_c[2];
#pragma unroll
  for (int ni = 0; ni < 2; ++ni) bh_c[ni] = bhp[w * 32 + ni * 16 + ln];

#pragma unroll
  for (int mi = 0; mi < 4; ++mi) {
#pragma unroll
    for (int r = 0; r < 4; ++r) {
      int lr = mi * 16 + g * 4 + r;
      int n = n0 + lr;
#pragma unroll
      for (int ni = 0; ni < 2; ++ni) {
        int c = w * 32 + ni * 16 + ln;
        if (n < NN) {
          float z = Zb[(size_t)n * FD + c];
          float hv = hs[(size_t)n * FD + c];
          float ht = tanhf(acc[mi][ni][r] + bh_c[ni]);
          float hn = z * hv + (1.f - z) * ht;
          Hn[(size_t)n * FD + c] = hn;
          HnL[lr][c] = (short)f2bf(fmaxf(hn, 0.f));
        } else {
          HnL[lr][c] = 0;
        }
      }
    }
  }
  __syncthreads();

  f32x4 ac = (f32x4){0.f, 0.f, 0.f, 0.f};
  const s16x8* wtl8 = (const s16x8*)wtl;
#pragma unroll
  for (int kci = 0; kci < 4; ++kci) {
    s16x8 a = *(const s16x8*)&HnL[w * 16 + ln][kci * 32 + g * 8];
    s16x8 bfr = wtl8[ln * 16 + kci * 4 + g];
    ac = __builtin_amdgcn_mfma_f32_16x16x32_bf16(a, bfr, ac, 0, 0, 0);
  }
  float blv = bl[ln];
#pragma unroll
  for (int r = 0; r < 4; ++r) {
    int n = n0 + w * 16 + g * 4 + r;
    float v = ac[r] + blv;
    float m = v;
#pragma unroll
    for (int msk = 1; msk < 16; msk <<= 1) m = fmaxf(m, __shfl_xor(m, msk, 64));
    float e = expf(v - m);
    float s = e;
#pragma unroll
    for (int msk = 1; msk < 16; msk <<= 1) s += __shfl_xor(s, msk, 64);
    if (n < NN) probs[(size_t)n * NCLS + ln] = e / s;
  }
}

// ---------------- launch ----------------

extern "C" void kernel_launch(void* const* d_in, const int* in_sizes, int n_in,
                              void* d_out, int out_size, void* d_ws, size_t ws_size,
                              hipStream_t stream) {
  (void)in_sizes; (void)n_in; (void)out_size; (void)ws_size;
  const float* x   = (const float*)d_in[0];
  const int*   ei  = (const int*)d_in[1];
  const float* ew  = (const float*)d_in[2];
  const float* hs  = (const float*)d_in[3];
  const float* Wg  = (const float*)d_in[4];
  const float* bg  = (const float*)d_in[5];
  const float* Wz0 = (const float*)d_in[6];
  const float* Wz1 = (const float*)d_in[7];
  const float* bz  = (const float*)d_in[8];
  const float* Wr0 = (const float*)d_in[9];
  const float* Wr1 = (const float*)d_in[10];
  const float* br  = (const float*)d_in[11];
  const float* Wh0 = (const float*)d_in[12];
  const float* Wh1 = (const float*)d_in[13];
  const float* bh  = (const float*)d_in[14];
  const float* Wl  = (const float*)d_in[15];
  const float* bl  = (const float*)d_in[16];

  float* out   = (float*)d_out;
  float* probs = out;                      // [NN,16]
  float* Hn    = out + (size_t)NN * NCLS;  // [NN,128]

  float* w    = (float*)d_ws;
  float* dinv = w;                             // [NN]
  float* xw   = w + 50048;                     // [NN*FD]; reused as Zb
  float* agg  = xw + (size_t)NN * FD;          // [NN*FD]
  float* hsrf = agg + (size_t)NN * FD;         // [NN*FD]: CSR scratch, then hsr16
  float* wsp  = hsrf + (size_t)NN * FD;        // tail: bf16 weights + biases
  float* Zb   = xw;
  short* hsr16 = (short*)hsrf;

  short* wtzr = (short*)wsp;                       // 65536 shorts
  short* wth  = (short*)(wsp + 32768);             // 32768 shorts
  short* wtg  = (short*)(wsp + 32768 + 16384);     // 16384 shorts
  short* wtl  = (short*)(wsp + 32768 + 16384 + 8192);  // 2048 shorts
  float* bzp  = wsp + 32768 + 16384 + 8192 + 1024;
  float* brp  = bzp + 128;
  float* bhp  = brp + 128;

  // CSR scratch laid out in hsrf region (6.4M floats available):
  //   [0, 800000)           src_s  (int)     -- overwritten by hsr16 later (dead then)
  //   [800000, 1600000)     nrm_s  (float)
  //   [1600000, 1650001)    basep  (int, NN+1)
  //   [1650048, 1650304)    bsum
  //   [1650304, 1650560)    boff
  //   [1651024, 3251024)    parts  (u64[NCOPY][NN], 8B-aligned offset)
  //   [3251040, 3301040)    cnt    (int NN)
  //   [3301040, 4101040)    off16  (int[NCOPY][NN])
  int*   src_s = (int*)hsrf;
  float* nrm_s = hsrf + NE;
  int*   basep = (int*)(hsrf + 2 * NE);
  int*   bsum  = (int*)(hsrf + 1650048);
  int*   boff  = (int*)(hsrf + 1650304);
  unsigned long long* parts = (unsigned long long*)(hsrf + 1651024);
  int*   cnt   = (int*)(hsrf + 3251040);
  int*   off16 = (int*)(hsrf + 3301040);

  k_prep_w<<<456, 256, 0, stream>>>(Wz0, Wz1, Wr0, Wr1, Wh0, Wh1, Wg, Wl,
                                    wtzr, wth, wtg, wtl);
  k_prep_bias<<<1, 128, 0, stream>>>(bg, Wz0, Wz1, Wr0, Wr1, Wh0, Wh1,
                                     bz, br, bh, bzp, brp, bhp);
  k_zero_parts<<<1024, 256, 0, stream>>>(parts);
  k_hist<<<1024, 256, 0, stream>>>(ei + NE, ew, parts);
  k_reduce<<<SCAN_B, 256, 0, stream>>>(parts, dinv, cnt);
  k_scan1<<<SCAN_B, 256, 0, stream>>>(cnt, basep, bsum);
  k_scan2<<<1, 256, 0, stream>>>(bsum, boff, basep);
  k_scan3<<<SCAN_B, 256, 0, stream>>>(basep, boff, parts, off16);
  k_reorder<<<1024, 256, 0, stream>>>(ei, ew, dinv, off16, src_s, nrm_s);
  k_xw_mfma<<<782, 256, 0, stream>>>(x, wtg, dinv, xw, agg);
  k_gather<<<12500, 256, 0, stream>>>(basep, src_s, nrm_s, xw, agg);
  k_zr_mfma<<<782, 256, 0, stream>>>(agg, hs, wtzr, bzp, brp, Zb, hsr16);
  k_ht_mfma<<<782, 256, 0, stream>>>(agg, hsr16, wth, bhp, Zb, hs, wtl, bl, probs, Hn);
}

// Round 11
// 256.581 us; speedup vs baseline: 3.7713x; 1.0538x over previous
//
#include <hip/hip_runtime.h>
#include <math.h>

#define NN 50000
#define NE 800000
#define FD 128
#define CIN 256
#define NCLS 16
#define SCAN_B 196   // ceil(NN/256)
#define NCOPY 16

typedef short s16x8 __attribute__((ext_vector_type(8)));
typedef float f32x4 __attribute__((ext_vector_type(4)));

__device__ __forceinline__ unsigned short f2bf(float f) {
  union { float f; unsigned u; } v; v.f = f;
  unsigned r = v.u + 0x7fffu + ((v.u >> 16) & 1u);
  return (unsigned short)(r >> 16);
}

__device__ __forceinline__ float bf2f(unsigned short h) {
  union { unsigned u; float f; } v; v.u = ((unsigned)h) << 16;
  return v.f;
}

__device__ __forceinline__ float sigmoidf_(float x) {
  return 1.0f / (1.0f + expf(-x));
}

// ---------------- weight prep: bf16 transposed WT[col][k] ----------------

__global__ void k_prep_w(const float* __restrict__ Wz0, const float* __restrict__ Wz1,
                         const float* __restrict__ Wr0, const float* __restrict__ Wr1,
                         const float* __restrict__ Wh0, const float* __restrict__ Wh1,
                         const float* __restrict__ Wg, const float* __restrict__ Wl,
                         short* __restrict__ wtzr, short* __restrict__ wth,
                         short* __restrict__ wtg, short* __restrict__ wtl) {
  int i = blockIdx.x * blockDim.x + threadIdx.x;
  if (i < 65536) {
    int n = i >> 8, k = i & 255;
    float v = (n < 128) ? (Wz0[k * 128 + n] + Wz1[k * 128 + n])
                        : (Wr0[k * 128 + (n - 128)] + Wr1[k * 128 + (n - 128)]);
    wtzr[i] = (short)f2bf(v);
  } else if (i < 98304) {
    int j = i - 65536; int n = j >> 8, k = j & 255;
    wth[j] = (short)f2bf(Wh0[k * 128 + n] + Wh1[k * 128 + n]);
  } else if (i < 114688) {
    int j = i - 98304; int n = j >> 7, k = j & 127;
    wtg[j] = (short)f2bf(Wg[k * 128 + n]);
  } else if (i < 116736) {
    int j = i - 114688; int n = j >> 7, k = j & 127;
    wtl[j] = (short)f2bf(Wl[k * 16 + n]);
  }
}

// fold bg into gate biases: b'[c] = b[c] + sum_k bg[k] * (W0+W1)[k][c]
__global__ void k_prep_bias(const float* __restrict__ bg,
                            const float* __restrict__ Wz0, const float* __restrict__ Wz1,
                            const float* __restrict__ Wr0, const float* __restrict__ Wr1,
                            const float* __restrict__ Wh0, const float* __restrict__ Wh1,
                            const float* __restrict__ bz, const float* __restrict__ br,
                            const float* __restrict__ bh,
                            float* __restrict__ bzp, float* __restrict__ brp,
                            float* __restrict__ bhp) {
  int c = threadIdx.x;
  if (c >= 128) return;
  float sz = bz[c], sr = br[c], sh = bh[c];
  for (int k = 0; k < 128; ++k) {
    float g = bg[k];
    sz += g * (Wz0[k * 128 + c] + Wz1[k * 128 + c]);
    sr += g * (Wr0[k * 128 + c] + Wr1[k * 128 + c]);
    sh += g * (Wh0[k * 128 + c] + Wh1[k * 128 + c]);
  }
  bzp[c] = sz; brp[c] = sr; bhp[c] = sh;
}

// ---------------- CSR build: privatized packed histogram ----------------

__global__ void k_zero_parts(unsigned long long* __restrict__ parts) {
  int i = blockIdx.x * blockDim.x + threadIdx.x;
  int stride = gridDim.x * blockDim.x;
  for (; i < NCOPY * NN; i += stride) parts[i] = 0ULL;
}

__global__ void k_hist(const int* __restrict__ dst, const float* __restrict__ ew,
                       unsigned long long* __restrict__ parts) {
  const int c = blockIdx.x & (NCOPY - 1);
  unsigned long long* __restrict__ p = parts + (size_t)c * NN;
  int i = blockIdx.x * blockDim.x + threadIdx.x;
  int stride = gridDim.x * blockDim.x;
  for (int e = i; e < NE; e += stride) {
    int d = dst[e];
    unsigned long long pk = (1ULL << 40) +
        (unsigned long long)(ew[e] * 4294967296.0f + 0.5f);
    atomicAdd(&p[d], pk);
  }
}

__global__ void k_reduce(const unsigned long long* __restrict__ parts,
                         float* __restrict__ dinv, int* __restrict__ cnt) {
  int i = blockIdx.x * blockDim.x + threadIdx.x;
  if (i >= NN) return;
  int ct = 0;
  double frac = 0.0;
#pragma unroll
  for (int c = 0; c < NCOPY; ++c) {
    unsigned long long v = parts[(size_t)c * NN + i];
    ct += (int)(v >> 40);
    frac += (double)(v & 0xFFFFFFFFFFULL);
  }
  cnt[i] = ct;
  double deg = 1.0 + frac * (1.0 / 4294967296.0);
  dinv[i] = rsqrtf((float)deg);
}

__global__ __launch_bounds__(256) void k_scan1(const int* __restrict__ cnt,
                                               int* __restrict__ base,
                                               int* __restrict__ bsum) {
  __shared__ int ts[256];
  const int t = threadIdx.x, b = blockIdx.x;
  const int i = b * 256 + t;
  int v = (i < NN) ? cnt[i] : 0;
  ts[t] = v;
  __syncthreads();
#pragma unroll
  for (int off = 1; off < 256; off <<= 1) {
    int u = (t >= off) ? ts[t - off] : 0;
    __syncthreads();
    ts[t] += u;
    __syncthreads();
  }
  if (i < NN) base[i] = ts[t] - v;
  if (t == 255) bsum[b] = ts[255];
}

__global__ __launch_bounds__(256) void k_scan2(const int* __restrict__ bsum,
                                               int* __restrict__ boff,
                                               int* __restrict__ base) {
  __shared__ int ts[256];
  const int t = threadIdx.x;
  int v = (t < SCAN_B) ? bsum[t] : 0;
  ts[t] = v;
  __syncthreads();
#pragma unroll
  for (int off = 1; off < 256; off <<= 1) {
    int u = (t >= off) ? ts[t - off] : 0;
    __syncthreads();
    ts[t] += u;
    __syncthreads();
  }
  if (t < SCAN_B) boff[t] = ts[t] - v;
  if (t == 255) base[NN] = ts[255];
}

__global__ __launch_bounds__(256) void k_scan3(int* __restrict__ base,
                                               const int* __restrict__ boff,
                                               const unsigned long long* __restrict__ parts,
                                               int* __restrict__ off16) {
  const int i = blockIdx.x * 256 + threadIdx.x;
  if (i >= NN) return;
  int b = base[i] + boff[blockIdx.x];
  base[i] = b;
  int run = b;
#pragma unroll
  for (int c = 0; c < NCOPY; ++c) {
    off16[(size_t)c * NN + i] = run;
    run += (int)(parts[(size_t)c * NN + i] >> 40);
  }
}

// NOTE: grid/stride and c = blockIdx&15 MUST match k_hist exactly
__global__ void k_reorder(const int* __restrict__ ei, const float* __restrict__ ew,
                          const float* __restrict__ dinv,
                          int* __restrict__ off16, int* __restrict__ src_s,
                          float* __restrict__ nrm_s) {
  const int c = blockIdx.x & (NCOPY - 1);
  int* __restrict__ cur = off16 + (size_t)c * NN;
  int i = blockIdx.x * blockDim.x + threadIdx.x;
  int stride = gridDim.x * blockDim.x;
  const int* __restrict__ src = ei;
  const int* __restrict__ dst = ei + NE;
  for (int e = i; e < NE; e += stride) {
    int s = src[e], d = dst[e];
    int pos = atomicAdd(&cur[d], 1);
    src_s[pos] = s;
    nrm_s[pos] = dinv[s] * ew[e] * dinv[d];
  }
}

// ---------------- MFMA GEMM: xw = x @ Wg ; agg = xw * dinv^2 --------------

__global__ __launch_bounds__(256) void k_xw_mfma(
    const float* __restrict__ x, const short* __restrict__ wtg,
    const float* __restrict__ dinv, float* __restrict__ xw, float* __restrict__ agg) {
  __shared__ __align__(16) short As[64][40];
  const int tid = threadIdx.x;
  const int w = tid >> 6, l = tid & 63, g = l >> 4, ln = l & 15;
  const int n0 = blockIdx.x * 64;
  const int srow = tid >> 2, sk0 = (tid & 3) << 3;
  const s16x8* wt8 = (const s16x8*)wtg;

  f32x4 acc[4][2];
#pragma unroll
  for (int mi = 0; mi < 4; ++mi)
#pragma unroll
    for (int ni = 0; ni < 2; ++ni) acc[mi][ni] = (f32x4){0.f, 0.f, 0.f, 0.f};

  for (int kci = 0; kci < 4; ++kci) {
    int kg = kci * 32 + sk0;
    int n = n0 + srow;
    s16x8 av = {0, 0, 0, 0, 0, 0, 0, 0};
    if (n < NN) {
      const float* src = x + (size_t)n * FD + kg;
      float4 f0 = *(const float4*)src;
      float4 f1 = *(const float4*)(src + 4);
      av[0] = (short)f2bf(f0.x); av[1] = (short)f2bf(f0.y);
      av[2] = (short)f2bf(f0.z); av[3] = (short)f2bf(f0.w);
      av[4] = (short)f2bf(f1.x); av[5] = (short)f2bf(f1.y);
      av[6] = (short)f2bf(f1.z); av[7] = (short)f2bf(f1.w);
    }
    __syncthreads();
    *(s16x8*)&As[srow][sk0] = av;
    __syncthreads();
    s16x8 b[2], a[4];
#pragma unroll
    for (int ni = 0; ni < 2; ++ni) {
      int col = w * 32 + ni * 16 + ln;
      b[ni] = wt8[(size_t)col * 16 + kci * 4 + g];
    }
#pragma unroll
    for (int mi = 0; mi < 4; ++mi) a[mi] = *(const s16x8*)&As[mi * 16 + ln][g * 8];
#pragma unroll
    for (int mi = 0; mi < 4; ++mi)
#pragma unroll
      for (int ni = 0; ni < 2; ++ni)
        acc[mi][ni] = __builtin_amdgcn_mfma_f32_16x16x32_bf16(a[mi], b[ni], acc[mi][ni], 0, 0, 0);
  }
#pragma unroll
  for (int mi = 0; mi < 4; ++mi) {
#pragma unroll
    for (int r = 0; r < 4; ++r) {
      int n = n0 + mi * 16 + g * 4 + r;
      if (n >= NN) continue;
      float di = dinv[n];
      float d2 = di * di;
#pragma unroll
      for (int ni = 0; ni < 2; ++ni) {
        int c = w * 32 + ni * 16 + ln;
        float v = acc[mi][ni][r];
        xw[(size_t)n * FD + c] = v;
        agg[(size_t)n * FD + c] = v * d2;
      }
    }
  }
}

// ---------------- CSR gather (verified) ----------------

__global__ __launch_bounds__(256) void k_gather(
    const int* __restrict__ base, const int* __restrict__ src_s,
    const float* __restrict__ nrm_s, const float* __restrict__ xw,
    float* __restrict__ agg) {
  const int lane = threadIdx.x & 63;
  const int n = blockIdx.x * 4 + (threadIdx.x >> 6);
  if (n >= NN) return;
  const int e0 = base[n], e1 = base[n + 1];
  const int c = lane * 2;
  float* ap = agg + (size_t)n * FD + c;
  float2 acc = *(const float2*)ap;
  int e = e0;
  for (; e + 4 <= e1; e += 4) {
    int s0 = src_s[e], s1 = src_s[e + 1], s2 = src_s[e + 2], s3 = src_s[e + 3];
    float w0 = nrm_s[e], w1 = nrm_s[e + 1], w2 = nrm_s[e + 2], w3 = nrm_s[e + 3];
    float2 v0 = *(const float2*)(xw + (size_t)s0 * FD + c);
    float2 v1 = *(const float2*)(xw + (size_t)s1 * FD + c);
    float2 v2 = *(const float2*)(xw + (size_t)s2 * FD + c);
    float2 v3 = *(const float2*)(xw + (size_t)s3 * FD + c);
    acc.x = fmaf(w0, v0.x, acc.x); acc.y = fmaf(w0, v0.y, acc.y);
    acc.x = fmaf(w1, v1.x, acc.x); acc.y = fmaf(w1, v1.y, acc.y);
    acc.x = fmaf(w2, v2.x, acc.x); acc.y = fmaf(w2, v2.y, acc.y);
    acc.x = fmaf(w3, v3.x, acc.x); acc.y = fmaf(w3, v3.y, acc.y);
  }
  for (; e < e1; ++e) {
    int s = src_s[e];
    float wv = nrm_s[e];
    float2 v = *(const float2*)(xw + (size_t)s * FD + c);
    acc.x = fmaf(wv, v.x, acc.x); acc.y = fmaf(wv, v.y, acc.y);
  }
  *(float2*)ap = acc;
}

// ---------------- fused DCRNN cell: ZR + Ht + Hn + classifier + softmax ----
// block = 64 rows, 4 waves. As[64][264] = [bf16(agg)|bf16(hs)], staged once.
// ZR: wave w -> cols [w*64,w*64+64): waves 0,1 = Z -> ZH; waves 2,3 = R ->
//     hsr overwrites As hs-half in place.
// Ht: wave w -> cols [w*32,w*32+32); epilogue re-reads hs fp32 from global,
//     relu(Hn) bf16 overwrites ZH in place. Classifier reads ZH.

__global__ __launch_bounds__(256) void k_cell(
    const float* __restrict__ agg, const float* __restrict__ hs,
    const short* __restrict__ wtzr, const short* __restrict__ wth,
    const short* __restrict__ wtl, const float* __restrict__ bzp,
    const float* __restrict__ brp, const float* __restrict__ bhp,
    const float* __restrict__ bl, float* __restrict__ probs,
    float* __restrict__ Hn) {
  __shared__ __align__(16) short As[64][264];   // 33.8 KB
  __shared__ __align__(16) short ZH[64][136];   // 17.4 KB (Z, then relu(Hn))
  const int tid = threadIdx.x;
  const int w = tid >> 6, l = tid & 63, g = l >> 4, ln = l & 15;
  const int n0 = blockIdx.x * 64;
  const int srow = tid >> 2, sk0 = (tid & 3) << 3;

  // ---- stage As = [bf16(agg) | bf16(hs)], all K=256, single barrier ----
  {
    int n = n0 + srow;
#pragma unroll
    for (int kc = 0; kc < 8; ++kc) {
      int kg = kc * 32 + sk0;
      s16x8 av = {0, 0, 0, 0, 0, 0, 0, 0};
      if (n < NN) {
        const float* src = (kg < FD) ? (agg + (size_t)n * FD + kg)
                                     : (hs + (size_t)n * FD + (kg - FD));
        float4 f0 = *(const float4*)src;
        float4 f1 = *(const float4*)(src + 4);
        av[0] = (short)f2bf(f0.x); av[1] = (short)f2bf(f0.y);
        av[2] = (short)f2bf(f0.z); av[3] = (short)f2bf(f0.w);
        av[4] = (short)f2bf(f1.x); av[5] = (short)f2bf(f1.y);
        av[6] = (short)f2bf(f1.z); av[7] = (short)f2bf(f1.w);
      }
      *(s16x8*)&As[srow][kg] = av;
    }
  }
  __syncthreads();

  // ---- ZR GEMM: acc[4][4], wave w -> cols [w*64, w*64+64) ----
  {
    f32x4 acc[4][4];
#pragma unroll
    for (int mi = 0; mi < 4; ++mi)
#pragma unroll
      for (int ni = 0; ni < 4; ++ni) acc[mi][ni] = (f32x4){0.f, 0.f, 0.f, 0.f};
    const s16x8* wt8 = (const s16x8*)wtzr;  // row = 256 shorts = 32 units
#pragma unroll 2
    for (int kci = 0; kci < 8; ++kci) {
      s16x8 b[4], a[4];
#pragma unroll
      for (int ni = 0; ni < 4; ++ni) {
        int col = w * 64 + ni * 16 + ln;
        b[ni] = wt8[(size_t)col * 32 + kci * 4 + g];
      }
#pragma unroll
      for (int mi = 0; mi < 4; ++mi)
        a[mi] = *(const s16x8*)&As[mi * 16 + ln][kci * 32 + g * 8];
#pragma unroll
      for (int mi = 0; mi < 4; ++mi)
#pragma unroll
        for (int ni = 0; ni < 4; ++ni)
          acc[mi][ni] = __builtin_amdgcn_mfma_f32_16x16x32_bf16(a[mi], b[ni], acc[mi][ni], 0, 0, 0);
    }
    __syncthreads();  // all waves done reading As hs-half

    // epilogue: Z -> ZH (bf16); R -> hsr = R*hs overwrites As[.][128+cc]
    float bias[4];
    int colv[4];
#pragma unroll
    for (int ni = 0; ni < 4; ++ni) {
      colv[ni] = w * 64 + ni * 16 + ln;
      bias[ni] = (colv[ni] < FD) ? bzp[colv[ni]] : brp[colv[ni] - FD];
    }
#pragma unroll
    for (int mi = 0; mi < 4; ++mi) {
#pragma unroll
      for (int r = 0; r < 4; ++r) {
        int row = mi * 16 + g * 4 + r;
#pragma unroll
        for (int ni = 0; ni < 4; ++ni) {
          float sv = sigmoidf_(acc[mi][ni][r] + bias[ni]);
          if (colv[ni] < FD) {
            ZH[row][colv[ni]] = (short)f2bf(sv);
          } else {
            int cc = colv[ni] - FD;
            float hv = bf2f((unsigned short)As[row][FD + cc]);
            As[row][FD + cc] = (short)f2bf(sv * hv);
          }
        }
      }
    }
  }
  __syncthreads();

  // ---- Ht GEMM: acc2[4][2], wave w -> cols [w*32, w*32+32) ----
  f32x4 acc2[4][2];
#pragma unroll
  for (int mi = 0; mi < 4; ++mi)
#pragma unroll
    for (int ni = 0; ni < 2; ++ni) acc2[mi][ni] = (f32x4){0.f, 0.f, 0.f, 0.f};
  {
    const s16x8* wt8 = (const s16x8*)wth;  // row = 256 shorts = 32 units
#pragma unroll 2
    for (int kci = 0; kci < 8; ++kci) {
      s16x8 b[2], a[4];
#pragma unroll
      for (int ni = 0; ni < 2; ++ni) {
        int col = w * 32 + ni * 16 + ln;
        b[ni] = wt8[(size_t)col * 32 + kci * 4 + g];
      }
#pragma unroll
      for (int mi = 0; mi < 4; ++mi)
        a[mi] = *(const s16x8*)&As[mi * 16 + ln][kci * 32 + g * 8];
#pragma unroll
      for (int mi = 0; mi < 4; ++mi)
#pragma unroll
        for (int ni = 0; ni < 2; ++ni)
          acc2[mi][ni] = __builtin_amdgcn_mfma_f32_16x16x32_bf16(a[mi], b[ni], acc2[mi][ni], 0, 0, 0);
    }
  }

  // ---- Hn epilogue: each (row,c) owner reads ZH then overwrites in place ----
  {
    float bh_c[2];
#pragma unroll
    for (int ni = 0; ni < 2; ++ni) bh_c[ni] = bhp[w * 32 + ni * 16 + ln];
#pragma unroll
    for (int mi = 0; mi < 4; ++mi) {
#pragma unroll
      for (int r = 0; r < 4; ++r) {
        int row = mi * 16 + g * 4 + r;
        int n = n0 + row;
#pragma unroll
        for (int ni = 0; ni < 2; ++ni) {
          int c = w * 32 + ni * 16 + ln;
          float z = bf2f((unsigned short)ZH[row][c]);
          float ht = tanhf(acc2[mi][ni][r] + bh_c[ni]);
          if (n < NN) {
            float hv = hs[(size_t)n * FD + c];
            float hn = z * hv + (1.f - z) * ht;
            Hn[(size_t)n * FD + c] = hn;
            ZH[row][c] = (short)f2bf(fmaxf(hn, 0.f));
          } else {
            ZH[row][c] = 0;
          }
        }
      }
    }
  }
  __syncthreads();

  // ---- classifier: wave w -> rows [w*16, w*16+16); 16 classes ----
  f32x4 ac = (f32x4){0.f, 0.f, 0.f, 0.f};
  const s16x8* wtl8 = (const s16x8*)wtl;  // row = 128 shorts = 16 units
#pragma unroll
  for (int kci = 0; kci < 4; ++kci) {
    s16x8 a = *(const s16x8*)&ZH[w * 16 + ln][kci * 32 + g * 8];
    s16x8 bfr = wtl8[ln * 16 + kci * 4 + g];
    ac = __builtin_amdgcn_mfma_f32_16x16x32_bf16(a, bfr, ac, 0, 0, 0);
  }
  float blv = bl[ln];
#pragma unroll
  for (int r = 0; r < 4; ++r) {
    int n = n0 + w * 16 + g * 4 + r;
    float v = ac[r] + blv;
    float m = v;
#pragma unroll
    for (int msk = 1; msk < 16; msk <<= 1) m = fmaxf(m, __shfl_xor(m, msk, 64));
    float e = expf(v - m);
    float s = e;
#pragma unroll
    for (int msk = 1; msk < 16; msk <<= 1) s += __shfl_xor(s, msk, 64);
    if (n < NN) probs[(size_t)n * NCLS + ln] = e / s;
  }
}

// ---------------- launch ----------------

extern "C" void kernel_launch(void* const* d_in, const int* in_sizes, int n_in,
                              void* d_out, int out_size, void* d_ws, size_t ws_size,
                              hipStream_t stream) {
  (void)in_sizes; (void)n_in; (void)out_size; (void)ws_size;
  const float* x   = (const float*)d_in[0];
  const int*   ei  = (const int*)d_in[1];
  const float* ew  = (const float*)d_in[2];
  const float* hs  = (const float*)d_in[3];
  const float* Wg  = (const float*)d_in[4];
  const float* bg  = (const float*)d_in[5];
  const float* Wz0 = (const float*)d_in[6];
  const float* Wz1 = (const float*)d_in[7];
  const float* bz  = (const float*)d_in[8];
  const float* Wr0 = (const float*)d_in[9];
  const float* Wr1 = (const float*)d_in[10];
  const float* br  = (const float*)d_in[11];
  const float* Wh0 = (const float*)d_in[12];
  const float* Wh1 = (const float*)d_in[13];
  const float* bh  = (const float*)d_in[14];
  const float* Wl  = (const float*)d_in[15];
  const float* bl  = (const float*)d_in[16];

  float* out   = (float*)d_out;
  float* probs = out;                      // [NN,16]
  float* Hn    = out + (size_t)NN * NCLS;  // [NN,128]

  float* w    = (float*)d_ws;
  float* dinv = w;                             // [NN]
  float* xw   = w + 50048;                     // [NN*FD]
  float* agg  = xw + (size_t)NN * FD;          // [NN*FD]
  float* hsrf = agg + (size_t)NN * FD;         // [NN*FD]: CSR scratch region
  float* wsp  = hsrf + (size_t)NN * FD;        // tail: bf16 weights + biases

  short* wtzr = (short*)wsp;                       // 65536 shorts
  short* wth  = (short*)(wsp + 32768);             // 32768 shorts
  short* wtg  = (short*)(wsp + 32768 + 16384);     // 16384 shorts
  short* wtl  = (short*)(wsp + 32768 + 16384 + 8192);  // 2048 shorts
  float* bzp  = wsp + 32768 + 16384 + 8192 + 1024;
  float* brp  = bzp + 128;
  float* bhp  = brp + 128;

  // CSR scratch laid out in hsrf region (6.4M floats available):
  int*   src_s = (int*)hsrf;                        // [NE]
  float* nrm_s = hsrf + NE;                         // [NE]
  int*   basep = (int*)(hsrf + 2 * NE);             // [NN+1]
  int*   bsum  = (int*)(hsrf + 1650048);            // [SCAN_B]
  int*   boff  = (int*)(hsrf + 1650304);            // [SCAN_B]
  unsigned long long* parts = (unsigned long long*)(hsrf + 1651024);  // [NCOPY*NN]
  int*   cnt   = (int*)(hsrf + 3251040);            // [NN]
  int*   off16 = (int*)(hsrf + 3301040);            // [NCOPY*NN]

  k_prep_w<<<456, 256, 0, stream>>>(Wz0, Wz1, Wr0, Wr1, Wh0, Wh1, Wg, Wl,
                                    wtzr, wth, wtg, wtl);
  k_prep_bias<<<1, 128, 0, stream>>>(bg, Wz0, Wz1, Wr0, Wr1, Wh0, Wh1,
                                     bz, br, bh, bzp, brp, bhp);
  k_zero_parts<<<1024, 256, 0, stream>>>(parts);
  k_hist<<<1024, 256, 0, stream>>>(ei + NE, ew, parts);
  k_reduce<<<SCAN_B, 256, 0, stream>>>(parts, dinv, cnt);
  k_scan1<<<SCAN_B, 256, 0, stream>>>(cnt, basep, bsum);
  k_scan2<<<1, 256, 0, stream>>>(bsum, boff, basep);
  k_scan3<<<SCAN_B, 256, 0, stream>>>(basep, boff, parts, off16);
  k_reorder<<<1024, 256, 0, stream>>>(ei, ew, dinv, off16, src_s, nrm_s);
  k_xw_mfma<<<782, 256, 0, stream>>>(x, wtg, dinv, xw, agg);
  k_gather<<<12500, 256, 0, stream>>>(basep, src_s, nrm_s, xw, agg);
  k_cell<<<782, 256, 0, stream>>>(agg, hs, wtzr, wth, wtl, bzp, brp, bhp,
                                  bl, probs, Hn);
}

// Round 12
// 221.532 us; speedup vs baseline: 4.3680x; 1.1582x over previous
//
#include <hip/hip_runtime.h>
#include <math.h>

#define NN 50000
#define NE 800000
#define FD 128
#define CIN 256
#define NCLS 16
#define SCAN_B 196   // ceil(NN/256)
#define NCOPY 16

typedef short s16x8 __attribute__((ext_vector_type(8)));
typedef float f32x4 __attribute__((ext_vector_type(4)));

__device__ __forceinline__ unsigned short f2bf(float f) {
  union { float f; unsigned u; } v; v.f = f;
  unsigned r = v.u + 0x7fffu + ((v.u >> 16) & 1u);
  return (unsigned short)(r >> 16);
}

__device__ __forceinline__ float bf2f(unsigned short h) {
  union { unsigned u; float f; } v; v.u = ((unsigned)h) << 16;
  return v.f;
}

__device__ __forceinline__ float sigmoidf_(float x) {
  return 1.0f / (1.0f + expf(-x));
}

// ---------------- weight prep: bf16 transposed WT[col][k] ----------------

__global__ void k_prep_w(const float* __restrict__ Wz0, const float* __restrict__ Wz1,
                         const float* __restrict__ Wr0, const float* __restrict__ Wr1,
                         const float* __restrict__ Wh0, const float* __restrict__ Wh1,
                         const float* __restrict__ Wg, const float* __restrict__ Wl,
                         short* __restrict__ wtzr, short* __restrict__ wth,
                         short* __restrict__ wtg, short* __restrict__ wtl) {
  int i = blockIdx.x * blockDim.x + threadIdx.x;
  if (i < 65536) {
    int n = i >> 8, k = i & 255;
    float v = (n < 128) ? (Wz0[k * 128 + n] + Wz1[k * 128 + n])
                        : (Wr0[k * 128 + (n - 128)] + Wr1[k * 128 + (n - 128)]);
    wtzr[i] = (short)f2bf(v);
  } else if (i < 98304) {
    int j = i - 65536; int n = j >> 8, k = j & 255;
    wth[j] = (short)f2bf(Wh0[k * 128 + n] + Wh1[k * 128 + n]);
  } else if (i < 114688) {
    int j = i - 98304; int n = j >> 7, k = j & 127;
    wtg[j] = (short)f2bf(Wg[k * 128 + n]);
  } else if (i < 116736) {
    int j = i - 114688; int n = j >> 7, k = j & 127;
    wtl[j] = (short)f2bf(Wl[k * 16 + n]);
  }
}

// fold bg into gate biases: b'[c] = b[c] + sum_k bg[k] * (W0+W1)[k][c]
__global__ void k_prep_bias(const float* __restrict__ bg,
                            const float* __restrict__ Wz0, const float* __restrict__ Wz1,
                            const float* __restrict__ Wr0, const float* __restrict__ Wr1,
                            const float* __restrict__ Wh0, const float* __restrict__ Wh1,
                            const float* __restrict__ bz, const float* __restrict__ br,
                            const float* __restrict__ bh,
                            float* __restrict__ bzp, float* __restrict__ brp,
                            float* __restrict__ bhp) {
  int c = threadIdx.x;
  if (c >= 128) return;
  float sz = bz[c], sr = br[c], sh = bh[c];
  for (int k = 0; k < 128; ++k) {
    float g = bg[k];
    sz += g * (Wz0[k * 128 + c] + Wz1[k * 128 + c]);
    sr += g * (Wr0[k * 128 + c] + Wr1[k * 128 + c]);
    sh += g * (Wh0[k * 128 + c] + Wh1[k * 128 + c]);
  }
  bzp[c] = sz; brp[c] = sr; bhp[c] = sh;
}

// ---------------- CSR build: privatized packed histogram ----------------

__global__ void k_zero_parts(unsigned long long* __restrict__ parts) {
  int i = blockIdx.x * blockDim.x + threadIdx.x;
  int stride = gridDim.x * blockDim.x;
  for (; i < NCOPY * NN; i += stride) parts[i] = 0ULL;
}

__global__ void k_hist(const int* __restrict__ dst, const float* __restrict__ ew,
                       unsigned long long* __restrict__ parts) {
  const int c = blockIdx.x & (NCOPY - 1);
  unsigned long long* __restrict__ p = parts + (size_t)c * NN;
  int i = blockIdx.x * blockDim.x + threadIdx.x;
  int stride = gridDim.x * blockDim.x;
  for (int e = i; e < NE; e += stride) {
    int d = dst[e];
    unsigned long long pk = (1ULL << 40) +
        (unsigned long long)(ew[e] * 4294967296.0f + 0.5f);
    atomicAdd(&p[d], pk);
  }
}

__global__ void k_reduce(const unsigned long long* __restrict__ parts,
                         float* __restrict__ dinv, int* __restrict__ cnt) {
  int i = blockIdx.x * blockDim.x + threadIdx.x;
  if (i >= NN) return;
  int ct = 0;
  double frac = 0.0;
#pragma unroll
  for (int c = 0; c < NCOPY; ++c) {
    unsigned long long v = parts[(size_t)c * NN + i];
    ct += (int)(v >> 40);
    frac += (double)(v & 0xFFFFFFFFFFULL);
  }
  cnt[i] = ct;
  double deg = 1.0 + frac * (1.0 / 4294967296.0);
  dinv[i] = rsqrtf((float)deg);
}

__global__ __launch_bounds__(256) void k_scan1(const int* __restrict__ cnt,
                                               int* __restrict__ base,
                                               int* __restrict__ bsum) {
  __shared__ int ts[256];
  const int t = threadIdx.x, b = blockIdx.x;
  const int i = b * 256 + t;
  int v = (i < NN) ? cnt[i] : 0;
  ts[t] = v;
  __syncthreads();
#pragma unroll
  for (int off = 1; off < 256; off <<= 1) {
    int u = (t >= off) ? ts[t - off] : 0;
    __syncthreads();
    ts[t] += u;
    __syncthreads();
  }
  if (i < NN) base[i] = ts[t] - v;
  if (t == 255) bsum[b] = ts[255];
}

__global__ __launch_bounds__(256) void k_scan2(const int* __restrict__ bsum,
                                               int* __restrict__ boff,
                                               int* __restrict__ base) {
  __shared__ int ts[256];
  const int t = threadIdx.x;
  int v = (t < SCAN_B) ? bsum[t] : 0;
  ts[t] = v;
  __syncthreads();
#pragma unroll
  for (int off = 1; off < 256; off <<= 1) {
    int u = (t >= off) ? ts[t - off] : 0;
    __syncthreads();
    ts[t] += u;
    __syncthreads();
  }
  if (t < SCAN_B) boff[t] = ts[t] - v;
  if (t == 255) base[NN] = ts[255];
}

__global__ __launch_bounds__(256) void k_scan3(int* __restrict__ base,
                                               const int* __restrict__ boff,
                                               const unsigned long long* __restrict__ parts,
                                               int* __restrict__ off16) {
  const int i = blockIdx.x * 256 + threadIdx.x;
  if (i >= NN) return;
  int b = base[i] + boff[blockIdx.x];
  base[i] = b;
  int run = b;
#pragma unroll
  for (int c = 0; c < NCOPY; ++c) {
    off16[(size_t)c * NN + i] = run;
    run += (int)(parts[(size_t)c * NN + i] >> 40);
  }
}

// NOTE: grid/stride and c = blockIdx&15 MUST match k_hist exactly
__global__ void k_reorder(const int* __restrict__ ei, const float* __restrict__ ew,
                          const float* __restrict__ dinv,
                          int* __restrict__ off16, int* __restrict__ src_s,
                          float* __restrict__ nrm_s) {
  const int c = blockIdx.x & (NCOPY - 1);
  int* __restrict__ cur = off16 + (size_t)c * NN;
  int i = blockIdx.x * blockDim.x + threadIdx.x;
  int stride = gridDim.x * blockDim.x;
  const int* __restrict__ src = ei;
  const int* __restrict__ dst = ei + NE;
  for (int e = i; e < NE; e += stride) {
    int s = src[e], d = dst[e];
    int pos = atomicAdd(&cur[d], 1);
    src_s[pos] = s;
    nrm_s[pos] = dinv[s] * ew[e] * dinv[d];
  }
}

// ---------------- MFMA GEMM: xw(bf16) = x @ Wg ; agg = xw * dinv^2 --------

__global__ __launch_bounds__(256) void k_xw_mfma(
    const float* __restrict__ x, const short* __restrict__ wtg,
    const float* __restrict__ dinv, short* __restrict__ xw16,
    float* __restrict__ agg) {
  __shared__ __align__(16) short As[64][40];
  const int tid = threadIdx.x;
  const int w = tid >> 6, l = tid & 63, g = l >> 4, ln = l & 15;
  const int n0 = blockIdx.x * 64;
  const int srow = tid >> 2, sk0 = (tid & 3) << 3;
  const s16x8* wt8 = (const s16x8*)wtg;

  f32x4 acc[4][2];
#pragma unroll
  for (int mi = 0; mi < 4; ++mi)
#pragma unroll
    for (int ni = 0; ni < 2; ++ni) acc[mi][ni] = (f32x4){0.f, 0.f, 0.f, 0.f};

  for (int kci = 0; kci < 4; ++kci) {
    int kg = kci * 32 + sk0;
    int n = n0 + srow;
    s16x8 av = {0, 0, 0, 0, 0, 0, 0, 0};
    if (n < NN) {
      const float* src = x + (size_t)n * FD + kg;
      float4 f0 = *(const float4*)src;
      float4 f1 = *(const float4*)(src + 4);
      av[0] = (short)f2bf(f0.x); av[1] = (short)f2bf(f0.y);
      av[2] = (short)f2bf(f0.z); av[3] = (short)f2bf(f0.w);
      av[4] = (short)f2bf(f1.x); av[5] = (short)f2bf(f1.y);
      av[6] = (short)f2bf(f1.z); av[7] = (short)f2bf(f1.w);
    }
    __syncthreads();
    *(s16x8*)&As[srow][sk0] = av;
    __syncthreads();
    s16x8 b[2], a[4];
#pragma unroll
    for (int ni = 0; ni < 2; ++ni) {
      int col = w * 32 + ni * 16 + ln;
      b[ni] = wt8[(size_t)col * 16 + kci * 4 + g];
    }
#pragma unroll
    for (int mi = 0; mi < 4; ++mi) a[mi] = *(const s16x8*)&As[mi * 16 + ln][g * 8];
#pragma unroll
    for (int mi = 0; mi < 4; ++mi)
#pragma unroll
      for (int ni = 0; ni < 2; ++ni)
        acc[mi][ni] = __builtin_amdgcn_mfma_f32_16x16x32_bf16(a[mi], b[ni], acc[mi][ni], 0, 0, 0);
  }
#pragma unroll
  for (int mi = 0; mi < 4; ++mi) {
#pragma unroll
    for (int r = 0; r < 4; ++r) {
      int n = n0 + mi * 16 + g * 4 + r;
      if (n >= NN) continue;
      float di = dinv[n];
      float d2 = di * di;
#pragma unroll
      for (int ni = 0; ni < 2; ++ni) {
        int c = w * 32 + ni * 16 + ln;
        float v = acc[mi][ni][r];
        xw16[(size_t)n * FD + c] = (short)f2bf(v);
        agg[(size_t)n * FD + c] = v * d2;
      }
    }
  }
}

// ---------------- CSR gather: bf16 xw, fp32 accumulate ----------------

__global__ __launch_bounds__(256) void k_gather(
    const int* __restrict__ base, const int* __restrict__ src_s,
    const float* __restrict__ nrm_s, const unsigned short* __restrict__ xw16,
    float* __restrict__ agg) {
  const int lane = threadIdx.x & 63;
  const int n = blockIdx.x * 4 + (threadIdx.x >> 6);
  if (n >= NN) return;
  const int e0 = base[n], e1 = base[n + 1];
  const int c = lane * 2;
  float* ap = agg + (size_t)n * FD + c;
  float2 acc = *(const float2*)ap;
  int e = e0;
  for (; e + 4 <= e1; e += 4) {
    int s0 = src_s[e], s1 = src_s[e + 1], s2 = src_s[e + 2], s3 = src_s[e + 3];
    float w0 = nrm_s[e], w1 = nrm_s[e + 1], w2 = nrm_s[e + 2], w3 = nrm_s[e + 3];
    unsigned v0 = *(const unsigned*)(xw16 + (size_t)s0 * FD + c);
    unsigned v1 = *(const unsigned*)(xw16 + (size_t)s1 * FD + c);
    unsigned v2 = *(const unsigned*)(xw16 + (size_t)s2 * FD + c);
    unsigned v3 = *(const unsigned*)(xw16 + (size_t)s3 * FD + c);
    acc.x = fmaf(w0, bf2f((unsigned short)(v0 & 0xffff)), acc.x);
    acc.y = fmaf(w0, bf2f((unsigned short)(v0 >> 16)), acc.y);
    acc.x = fmaf(w1, bf2f((unsigned short)(v1 & 0xffff)), acc.x);
    acc.y = fmaf(w1, bf2f((unsigned short)(v1 >> 16)), acc.y);
    acc.x = fmaf(w2, bf2f((unsigned short)(v2 & 0xffff)), acc.x);
    acc.y = fmaf(w2, bf2f((unsigned short)(v2 >> 16)), acc.y);
    acc.x = fmaf(w3, bf2f((unsigned short)(v3 & 0xffff)), acc.x);
    acc.y = fmaf(w3, bf2f((unsigned short)(v3 >> 16)), acc.y);
  }
  for (; e < e1; ++e) {
    int s = src_s[e];
    float wv = nrm_s[e];
    unsigned v = *(const unsigned*)(xw16 + (size_t)s * FD + c);
    acc.x = fmaf(wv, bf2f((unsigned short)(v & 0xffff)), acc.x);
    acc.y = fmaf(wv, bf2f((unsigned short)(v >> 16)), acc.y);
  }
  *(float2*)ap = acc;
}

// ---------------- fused DCRNN cell: ZR + Ht + Hn + classifier + softmax ----
// block = 64 rows, 4 waves. As[64][264] = [bf16(agg)|bf16(hs)], staged once.
// ZR wave mapping: wave w computes Z cols [w*32,w*32+32) (ni 0,1) and
//   R cols 128+[w*32,w*32+32) (ni 2,3). Z stays in REGISTERS (zacc) — the
//   same (row,col) owner consumes it in the Hn epilogue. R -> hsr = R*hs
//   overwrites As hs-half in place.
// Ht: wave w -> cols [w*32,w*32+32). Hn epilogue re-reads hs fp32 (L3-hot),
//   writes Hn, and stores relu(Hn) bf16 into As cols 0..127 (free after a
//   barrier). Classifier reads As.

__global__ __launch_bounds__(256) void k_cell(
    const float* __restrict__ agg, const float* __restrict__ hs,
    const short* __restrict__ wtzr, const short* __restrict__ wth,
    const short* __restrict__ wtl, const float* __restrict__ bzp,
    const float* __restrict__ brp, const float* __restrict__ bhp,
    const float* __restrict__ bl, float* __restrict__ probs,
    float* __restrict__ Hn) {
  __shared__ __align__(16) short As[64][264];   // 33.8 KB total LDS
  const int tid = threadIdx.x;
  const int w = tid >> 6, l = tid & 63, g = l >> 4, ln = l & 15;
  const int n0 = blockIdx.x * 64;
  const int srow = tid >> 2, sk0 = (tid & 3) << 3;

  // ---- stage As = [bf16(agg) | bf16(hs)], all K=256, single barrier ----
  {
    int n = n0 + srow;
#pragma unroll
    for (int kc = 0; kc < 8; ++kc) {
      int kg = kc * 32 + sk0;
      s16x8 av = {0, 0, 0, 0, 0, 0, 0, 0};
      if (n < NN) {
        const float* src = (kg < FD) ? (agg + (size_t)n * FD + kg)
                                     : (hs + (size_t)n * FD + (kg - FD));
        float4 f0 = *(const float4*)src;
        float4 f1 = *(const float4*)(src + 4);
        av[0] = (short)f2bf(f0.x); av[1] = (short)f2bf(f0.y);
        av[2] = (short)f2bf(f0.z); av[3] = (short)f2bf(f0.w);
        av[4] = (short)f2bf(f1.x); av[5] = (short)f2bf(f1.y);
        av[6] = (short)f2bf(f1.z); av[7] = (short)f2bf(f1.w);
      }
      *(s16x8*)&As[srow][kg] = av;
    }
  }
  __syncthreads();

  // ---- ZR GEMM ----
  f32x4 zacc[4][2];  // z gate values, live into Hn epilogue
  {
    f32x4 acc[4][4];
#pragma unroll
    for (int mi = 0; mi < 4; ++mi)
#pragma unroll
      for (int ni = 0; ni < 4; ++ni) acc[mi][ni] = (f32x4){0.f, 0.f, 0.f, 0.f};
    const s16x8* wt8 = (const s16x8*)wtzr;  // row = 256 shorts = 32 units
#pragma unroll 2
    for (int kci = 0; kci < 8; ++kci) {
      s16x8 b[4], a[4];
#pragma unroll
      for (int ni = 0; ni < 4; ++ni) {
        int col = (ni < 2) ? (w * 32 + ni * 16 + ln)
                           : (FD + w * 32 + (ni - 2) * 16 + ln);
        b[ni] = wt8[(size_t)col * 32 + kci * 4 + g];
      }
#pragma unroll
      for (int mi = 0; mi < 4; ++mi)
        a[mi] = *(const s16x8*)&As[mi * 16 + ln][kci * 32 + g * 8];
#pragma unroll
      for (int mi = 0; mi < 4; ++mi)
#pragma unroll
        for (int ni = 0; ni < 4; ++ni)
          acc[mi][ni] = __builtin_amdgcn_mfma_f32_16x16x32_bf16(a[mi], b[ni], acc[mi][ni], 0, 0, 0);
    }
    __syncthreads();  // all waves done reading As hs-half

    // epilogue: z -> registers; r -> hsr = r*hs overwrites As[.][128+cc]
    float bz_c[2], br_c[2];
#pragma unroll
    for (int ni = 0; ni < 2; ++ni) {
      bz_c[ni] = bzp[w * 32 + ni * 16 + ln];
      br_c[ni] = brp[w * 32 + ni * 16 + ln];
    }
#pragma unroll
    for (int mi = 0; mi < 4; ++mi) {
#pragma unroll
      for (int r = 0; r < 4; ++r) {
        int row = mi * 16 + g * 4 + r;
#pragma unroll
        for (int ni = 0; ni < 2; ++ni) {
          zacc[mi][ni][r] = sigmoidf_(acc[mi][ni][r] + bz_c[ni]);
          int cc = w * 32 + ni * 16 + ln;
          float rv = sigmoidf_(acc[mi][ni + 2][r] + br_c[ni]);
          float hv = bf2f((unsigned short)As[row][FD + cc]);
          As[row][FD + cc] = (short)f2bf(rv * hv);
        }
      }
    }
  }
  __syncthreads();

  // ---- Ht GEMM: acc2[4][2], wave w -> cols [w*32, w*32+32) ----
  f32x4 acc2[4][2];
#pragma unroll
  for (int mi = 0; mi < 4; ++mi)
#pragma unroll
    for (int ni = 0; ni < 2; ++ni) acc2[mi][ni] = (f32x4){0.f, 0.f, 0.f, 0.f};
  {
    const s16x8* wt8 = (const s16x8*)wth;  // row = 256 shorts = 32 units
#pragma unroll 2
    for (int kci = 0; kci < 8; ++kci) {
      s16x8 b[2], a[4];
#pragma unroll
      for (int ni = 0; ni < 2; ++ni) {
        int col = w * 32 + ni * 16 + ln;
        b[ni] = wt8[(size_t)col * 32 + kci * 4 + g];
      }
#pragma unroll
      for (int mi = 0; mi < 4; ++mi)
        a[mi] = *(const s16x8*)&As[mi * 16 + ln][kci * 32 + g * 8];
#pragma unroll
      for (int mi = 0; mi < 4; ++mi)
#pragma unroll
        for (int ni = 0; ni < 2; ++ni)
          acc2[mi][ni] = __builtin_amdgcn_mfma_f32_16x16x32_bf16(a[mi], b[ni], acc2[mi][ni], 0, 0, 0);
    }
  }
  __syncthreads();  // all waves done reading As before relu(Hn) overwrite

  // ---- Hn epilogue: Hn = z*hs + (1-z)*tanh(ht); relu(Hn) -> As[:,0:128] ----
  {
    float bh_c[2];
#pragma unroll
    for (int ni = 0; ni < 2; ++ni) bh_c[ni] = bhp[w * 32 + ni * 16 + ln];
#pragma unroll
    for (int mi = 0; mi < 4; ++mi) {
#pragma unroll
      for (int r = 0; r < 4; ++r) {
        int row = mi * 16 + g * 4 + r;
        int n = n0 + row;
#pragma unroll
        for (int ni = 0; ni < 2; ++ni) {
          int c = w * 32 + ni * 16 + ln;
          float z = zacc[mi][ni][r];
          float ht = tanhf(acc2[mi][ni][r] + bh_c[ni]);
          if (n < NN) {
            float hv = hs[(size_t)n * FD + c];
            float hn = z * hv + (1.f - z) * ht;
            Hn[(size_t)n * FD + c] = hn;
            As[row][c] = (short)f2bf(fmaxf(hn, 0.f));
          } else {
            As[row][c] = 0;
          }
        }
      }
    }
  }
  __syncthreads();

  // ---- classifier: wave w -> rows [w*16, w*16+16); 16 classes ----
  f32x4 ac = (f32x4){0.f, 0.f, 0.f, 0.f};
  const s16x8* wtl8 = (const s16x8*)wtl;  // row = 128 shorts = 16 units
#pragma unroll
  for (int kci = 0; kci < 4; ++kci) {
    s16x8 a = *(const s16x8*)&As[w * 16 + ln][kci * 32 + g * 8];
    s16x8 bfr = wtl8[ln * 16 + kci * 4 + g];
    ac = __builtin_amdgcn_mfma_f32_16x16x32_bf16(a, bfr, ac, 0, 0, 0);
  }
  float blv = bl[ln];
#pragma unroll
  for (int r = 0; r < 4; ++r) {
    int n = n0 + w * 16 + g * 4 + r;
    float v = ac[r] + blv;
    float m = v;
#pragma unroll
    for (int msk = 1; msk < 16; msk <<= 1) m = fmaxf(m, __shfl_xor(m, msk, 64));
    float e = expf(v - m);
    float s = e;
#pragma unroll
    for (int msk = 1; msk < 16; msk <<= 1) s += __shfl_xor(s, msk, 64);
    if (n < NN) probs[(size_t)n * NCLS + ln] = e / s;
  }
}

// ---------------- launch ----------------

extern "C" void kernel_launch(void* const* d_in, const int* in_sizes, int n_in,
                              void* d_out, int out_size, void* d_ws, size_t ws_size,
                              hipStream_t stream) {
  (void)in_sizes; (void)n_in; (void)out_size; (void)ws_size;
  const float* x   = (const float*)d_in[0];
  const int*   ei  = (const int*)d_in[1];
  const float* ew  = (const float*)d_in[2];
  const float* hs  = (const float*)d_in[3];
  const float* Wg  = (const float*)d_in[4];
  const float* bg  = (const float*)d_in[5];
  const float* Wz0 = (const float*)d_in[6];
  const float* Wz1 = (const float*)d_in[7];
  const float* bz  = (const float*)d_in[8];
  const float* Wr0 = (const float*)d_in[9];
  const float* Wr1 = (const float*)d_in[10];
  const float* br  = (const float*)d_in[11];
  const float* Wh0 = (const float*)d_in[12];
  const float* Wh1 = (const float*)d_in[13];
  const float* bh  = (const float*)d_in[14];
  const float* Wl  = (const float*)d_in[15];
  const float* bl  = (const float*)d_in[16];

  float* out   = (float*)d_out;
  float* probs = out;                      // [NN,16]
  float* Hn    = out + (size_t)NN * NCLS;  // [NN,128]

  float* w    = (float*)d_ws;
  float* dinv = w;                             // [NN]
  short* xw16 = (short*)(w + 50048);           // [NN*FD] bf16 (in old xw slot)
  float* agg  = w + 50048 + (size_t)NN * FD;   // [NN*FD]
  float* hsrf = agg + (size_t)NN * FD;         // [NN*FD]: CSR scratch region
  float* wsp  = hsrf + (size_t)NN * FD;        // tail: bf16 weights + biases

  short* wtzr = (short*)wsp;                       // 65536 shorts
  short* wth  = (short*)(wsp + 32768);             // 32768 shorts
  short* wtg  = (short*)(wsp + 32768 + 16384);     // 16384 shorts
  short* wtl  = (short*)(wsp + 32768 + 16384 + 8192);  // 2048 shorts
  float* bzp  = wsp + 32768 + 16384 + 8192 + 1024;
  float* brp  = bzp + 128;
  float* bhp  = brp + 128;

  // CSR scratch laid out in hsrf region (6.4M floats available):
  int*   src_s = (int*)hsrf;                        // [NE]
  float* nrm_s = hsrf + NE;                         // [NE]
  int*   basep = (int*)(hsrf + 2 * NE);             // [NN+1]
  int*   bsum  = (int*)(hsrf + 1650048);            // [SCAN_B]
  int*   boff  = (int*)(hsrf + 1650304);            // [SCAN_B]
  unsigned long long* parts = (unsigned long long*)(hsrf + 1651024);  // [NCOPY*NN]
  int*   cnt   = (int*)(hsrf + 3251040);            // [NN]
  int*   off16 = (int*)(hsrf + 3301040);            // [NCOPY*NN]

  k_prep_w<<<456, 256, 0, stream>>>(Wz0, Wz1, Wr0, Wr1, Wh0, Wh1, Wg, Wl,
                                    wtzr, wth, wtg, wtl);
  k_prep_bias<<<1, 128, 0, stream>>>(bg, Wz0, Wz1, Wr0, Wr1, Wh0, Wh1,
                                     bz, br, bh, bzp, brp, bhp);
  k_zero_parts<<<1024, 256, 0, stream>>>(parts);
  k_hist<<<1024, 256, 0, stream>>>(ei + NE, ew, parts);
  k_reduce<<<SCAN_B, 256, 0, stream>>>(parts, dinv, cnt);
  k_scan1<<<SCAN_B, 256, 0, stream>>>(cnt, basep, bsum);
  k_scan2<<<1, 256, 0, stream>>>(bsum, boff, basep);
  k_scan3<<<SCAN_B, 256, 0, stream>>>(basep, boff, parts, off16);
  k_reorder<<<1024, 256, 0, stream>>>(ei, ew, dinv, off16, src_s, nrm_s);
  k_xw_mfma<<<782, 256, 0, stream>>>(x, wtg, dinv, xw16, agg);
  k_gather<<<12500, 256, 0, stream>>>(basep, src_s, nrm_s,
                                      (const unsigned short*)xw16, agg);
  k_cell<<<782, 256, 0, stream>>>(agg, hs, wtzr, wth, wtl, bzp, brp, bhp,
                                  bl, probs, Hn);
}

// Round 13
// 219.162 us; speedup vs baseline: 4.4152x; 1.0108x over previous
//
#include <hip/hip_runtime.h>
#include <math.h>

#define NN 50000
#define NE 800000
#define FD 128
#define CIN 256
#define NCLS 16
#define SCAN_B 196   // ceil(NN/256)
#define NCOPY 16

typedef short s16x8 __attribute__((ext_vector_type(8)));
typedef short s16x4 __attribute__((ext_vector_type(4)));
typedef float f32x4 __attribute__((ext_vector_type(4)));

__device__ __forceinline__ unsigned short f2bf(float f) {
  union { float f; unsigned u; } v; v.f = f;
  unsigned r = v.u + 0x7fffu + ((v.u >> 16) & 1u);
  return (unsigned short)(r >> 16);
}

__device__ __forceinline__ float bf2f(unsigned short h) {
  union { unsigned u; float f; } v; v.u = ((unsigned)h) << 16;
  return v.f;
}

// fast transcendentals: v_exp_f32 computes 2^x; rcp is 1-instr approx
__device__ __forceinline__ float fast_sigmoid(float x) {
  return __builtin_amdgcn_rcpf(1.0f + exp2f(-1.44269504f * x));
}
__device__ __forceinline__ float fast_tanh(float x) {
  return 1.0f - 2.0f * __builtin_amdgcn_rcpf(1.0f + exp2f(2.88539008f * x));
}

// ---------------- weight prep: bf16 transposed WT[col][k] ----------------

__global__ void k_prep_w(const float* __restrict__ Wz0, const float* __restrict__ Wz1,
                         const float* __restrict__ Wr0, const float* __restrict__ Wr1,
                         const float* __restrict__ Wh0, const float* __restrict__ Wh1,
                         const float* __restrict__ Wg, const float* __restrict__ Wl,
                         short* __restrict__ wtzr, short* __restrict__ wth,
                         short* __restrict__ wtg, short* __restrict__ wtl) {
  int i = blockIdx.x * blockDim.x + threadIdx.x;
  if (i < 65536) {
    int n = i >> 8, k = i & 255;
    float v = (n < 128) ? (Wz0[k * 128 + n] + Wz1[k * 128 + n])
                        : (Wr0[k * 128 + (n - 128)] + Wr1[k * 128 + (n - 128)]);
    wtzr[i] = (short)f2bf(v);
  } else if (i < 98304) {
    int j = i - 65536; int n = j >> 8, k = j & 255;
    wth[j] = (short)f2bf(Wh0[k * 128 + n] + Wh1[k * 128 + n]);
  } else if (i < 114688) {
    int j = i - 98304; int n = j >> 7, k = j & 127;
    wtg[j] = (short)f2bf(Wg[k * 128 + n]);
  } else if (i < 116736) {
    int j = i - 114688; int n = j >> 7, k = j & 127;
    wtl[j] = (short)f2bf(Wl[k * 16 + n]);
  }
}

__global__ void k_prep_bias(const float* __restrict__ bg,
                            const float* __restrict__ Wz0, const float* __restrict__ Wz1,
                            const float* __restrict__ Wr0, const float* __restrict__ Wr1,
                            const float* __restrict__ Wh0, const float* __restrict__ Wh1,
                            const float* __restrict__ bz, const float* __restrict__ br,
                            const float* __restrict__ bh,
                            float* __restrict__ bzp, float* __restrict__ brp,
                            float* __restrict__ bhp) {
  int c = threadIdx.x;
  if (c >= 128) return;
  float sz = bz[c], sr = br[c], sh = bh[c];
  for (int k = 0; k < 128; ++k) {
    float g = bg[k];
    sz += g * (Wz0[k * 128 + c] + Wz1[k * 128 + c]);
    sr += g * (Wr0[k * 128 + c] + Wr1[k * 128 + c]);
    sh += g * (Wh0[k * 128 + c] + Wh1[k * 128 + c]);
  }
  bzp[c] = sz; brp[c] = sr; bhp[c] = sh;
}

// ---------------- CSR build: privatized packed histogram ----------------

__global__ void k_zero_parts(unsigned long long* __restrict__ parts) {
  int i = blockIdx.x * blockDim.x + threadIdx.x;
  int stride = gridDim.x * blockDim.x;
  for (; i < NCOPY * NN; i += stride) parts[i] = 0ULL;
}

__global__ void k_hist(const int* __restrict__ dst, const float* __restrict__ ew,
                       unsigned long long* __restrict__ parts) {
  const int c = blockIdx.x & (NCOPY - 1);
  unsigned long long* __restrict__ p = parts + (size_t)c * NN;
  int i = blockIdx.x * blockDim.x + threadIdx.x;
  int stride = gridDim.x * blockDim.x;
  for (int e = i; e < NE; e += stride) {
    int d = dst[e];
    unsigned long long pk = (1ULL << 40) +
        (unsigned long long)(ew[e] * 4294967296.0f + 0.5f);
    atomicAdd(&p[d], pk);
  }
}

__global__ void k_reduce(const unsigned long long* __restrict__ parts,
                         float* __restrict__ dinv, int* __restrict__ cnt) {
  int i = blockIdx.x * blockDim.x + threadIdx.x;
  if (i >= NN) return;
  int ct = 0;
  double frac = 0.0;
#pragma unroll
  for (int c = 0; c < NCOPY; ++c) {
    unsigned long long v = parts[(size_t)c * NN + i];
    ct += (int)(v >> 40);
    frac += (double)(v & 0xFFFFFFFFFFULL);
  }
  cnt[i] = ct;
  double deg = 1.0 + frac * (1.0 / 4294967296.0);
  dinv[i] = rsqrtf((float)deg);
}

__global__ __launch_bounds__(256) void k_scan1(const int* __restrict__ cnt,
                                               int* __restrict__ base,
                                               int* __restrict__ bsum) {
  __shared__ int ts[256];
  const int t = threadIdx.x, b = blockIdx.x;
  const int i = b * 256 + t;
  int v = (i < NN) ? cnt[i] : 0;
  ts[t] = v;
  __syncthreads();
#pragma unroll
  for (int off = 1; off < 256; off <<= 1) {
    int u = (t >= off) ? ts[t - off] : 0;
    __syncthreads();
    ts[t] += u;
    __syncthreads();
  }
  if (i < NN) base[i] = ts[t] - v;
  if (t == 255) bsum[b] = ts[255];
}

__global__ __launch_bounds__(256) void k_scan2(const int* __restrict__ bsum,
                                               int* __restrict__ boff,
                                               int* __restrict__ base) {
  __shared__ int ts[256];
  const int t = threadIdx.x;
  int v = (t < SCAN_B) ? bsum[t] : 0;
  ts[t] = v;
  __syncthreads();
#pragma unroll
  for (int off = 1; off < 256; off <<= 1) {
    int u = (t >= off) ? ts[t - off] : 0;
    __syncthreads();
    ts[t] += u;
    __syncthreads();
  }
  if (t < SCAN_B) boff[t] = ts[t] - v;
  if (t == 255) base[NN] = ts[255];
}

__global__ __launch_bounds__(256) void k_scan3(int* __restrict__ base,
                                               const int* __restrict__ boff,
                                               const unsigned long long* __restrict__ parts,
                                               int* __restrict__ off16) {
  const int i = blockIdx.x * 256 + threadIdx.x;
  if (i >= NN) return;
  int b = base[i] + boff[blockIdx.x];
  base[i] = b;
  int run = b;
#pragma unroll
  for (int c = 0; c < NCOPY; ++c) {
    off16[(size_t)c * NN + i] = run;
    run += (int)(parts[(size_t)c * NN + i] >> 40);
  }
}

// NOTE: grid/stride and c = blockIdx&15 MUST match k_hist exactly
__global__ void k_reorder(const int* __restrict__ ei, const float* __restrict__ ew,
                          const float* __restrict__ dinv,
                          int* __restrict__ off16, int* __restrict__ src_s,
                          float* __restrict__ nrm_s) {
  const int c = blockIdx.x & (NCOPY - 1);
  int* __restrict__ cur = off16 + (size_t)c * NN;
  int i = blockIdx.x * blockDim.x + threadIdx.x;
  int stride = gridDim.x * blockDim.x;
  const int* __restrict__ src = ei;
  const int* __restrict__ dst = ei + NE;
  for (int e = i; e < NE; e += stride) {
    int s = src[e], d = dst[e];
    int pos = atomicAdd(&cur[d], 1);
    src_s[pos] = s;
    nrm_s[pos] = dinv[s] * ew[e] * dinv[d];
  }
}

// ------- MFMA GEMM: xw16(bf16) = x @ Wg ; agg16(bf16) = xw * dinv^2 -------

__global__ __launch_bounds__(256) void k_xw_mfma(
    const float* __restrict__ x, const short* __restrict__ wtg,
    const float* __restrict__ dinv, short* __restrict__ xw16,
    short* __restrict__ agg16) {
  __shared__ __align__(16) short As[64][40];
  const int tid = threadIdx.x;
  const int w = tid >> 6, l = tid & 63, g = l >> 4, ln = l & 15;
  const int n0 = blockIdx.x * 64;
  const int srow = tid >> 2, sk0 = (tid & 3) << 3;
  const s16x8* wt8 = (const s16x8*)wtg;

  f32x4 acc[4][2];
#pragma unroll
  for (int mi = 0; mi < 4; ++mi)
#pragma unroll
    for (int ni = 0; ni < 2; ++ni) acc[mi][ni] = (f32x4){0.f, 0.f, 0.f, 0.f};

  for (int kci = 0; kci < 4; ++kci) {
    int kg = kci * 32 + sk0;
    int n = n0 + srow;
    s16x8 av = {0, 0, 0, 0, 0, 0, 0, 0};
    if (n < NN) {
      const float* src = x + (size_t)n * FD + kg;
      float4 f0 = *(const float4*)src;
      float4 f1 = *(const float4*)(src + 4);
      av[0] = (short)f2bf(f0.x); av[1] = (short)f2bf(f0.y);
      av[2] = (short)f2bf(f0.z); av[3] = (short)f2bf(f0.w);
      av[4] = (short)f2bf(f1.x); av[5] = (short)f2bf(f1.y);
      av[6] = (short)f2bf(f1.z); av[7] = (short)f2bf(f1.w);
    }
    __syncthreads();
    *(s16x8*)&As[srow][sk0] = av;
    __syncthreads();
    s16x8 b[2], a[4];
#pragma unroll
    for (int ni = 0; ni < 2; ++ni) {
      int col = w * 32 + ni * 16 + ln;
      b[ni] = wt8[(size_t)col * 16 + kci * 4 + g];
    }
#pragma unroll
    for (int mi = 0; mi < 4; ++mi) a[mi] = *(const s16x8*)&As[mi * 16 + ln][g * 8];
#pragma unroll
    for (int mi = 0; mi < 4; ++mi)
#pragma unroll
      for (int ni = 0; ni < 2; ++ni)
        acc[mi][ni] = __builtin_amdgcn_mfma_f32_16x16x32_bf16(a[mi], b[ni], acc[mi][ni], 0, 0, 0);
  }
#pragma unroll
  for (int mi = 0; mi < 4; ++mi) {
#pragma unroll
    for (int r = 0; r < 4; ++r) {
      int n = n0 + mi * 16 + g * 4 + r;
      if (n >= NN) continue;
      float di = dinv[n];
      float d2 = di * di;
#pragma unroll
      for (int ni = 0; ni < 2; ++ni) {
        int c = w * 32 + ni * 16 + ln;
        float v = acc[mi][ni][r];
        xw16[(size_t)n * FD + c] = (short)f2bf(v);
        agg16[(size_t)n * FD + c] = (short)f2bf(v * d2);
      }
    }
  }
}

// -------- CSR gather: bf16 xw, fp32 register accumulate, bf16 agg RMW ------

__global__ __launch_bounds__(256) void k_gather(
    const int* __restrict__ base, const int* __restrict__ src_s,
    const float* __restrict__ nrm_s, const unsigned short* __restrict__ xw16,
    unsigned short* __restrict__ agg16) {
  const int lane = threadIdx.x & 63;
  const int n = blockIdx.x * 4 + (threadIdx.x >> 6);
  if (n >= NN) return;
  const int e0 = base[n], e1 = base[n + 1];
  const int c = lane * 2;
  unsigned* ap = (unsigned*)(agg16 + (size_t)n * FD + c);
  unsigned iv = *ap;
  float2 acc = make_float2(bf2f((unsigned short)(iv & 0xffff)),
                           bf2f((unsigned short)(iv >> 16)));
  int e = e0;
  for (; e + 4 <= e1; e += 4) {
    int s0 = src_s[e], s1 = src_s[e + 1], s2 = src_s[e + 2], s3 = src_s[e + 3];
    float w0 = nrm_s[e], w1 = nrm_s[e + 1], w2 = nrm_s[e + 2], w3 = nrm_s[e + 3];
    unsigned v0 = *(const unsigned*)(xw16 + (size_t)s0 * FD + c);
    unsigned v1 = *(const unsigned*)(xw16 + (size_t)s1 * FD + c);
    unsigned v2 = *(const unsigned*)(xw16 + (size_t)s2 * FD + c);
    unsigned v3 = *(const unsigned*)(xw16 + (size_t)s3 * FD + c);
    acc.x = fmaf(w0, bf2f((unsigned short)(v0 & 0xffff)), acc.x);
    acc.y = fmaf(w0, bf2f((unsigned short)(v0 >> 16)), acc.y);
    acc.x = fmaf(w1, bf2f((unsigned short)(v1 & 0xffff)), acc.x);
    acc.y = fmaf(w1, bf2f((unsigned short)(v1 >> 16)), acc.y);
    acc.x = fmaf(w2, bf2f((unsigned short)(v2 & 0xffff)), acc.x);
    acc.y = fmaf(w2, bf2f((unsigned short)(v2 >> 16)), acc.y);
    acc.x = fmaf(w3, bf2f((unsigned short)(v3 & 0xffff)), acc.x);
    acc.y = fmaf(w3, bf2f((unsigned short)(v3 >> 16)), acc.y);
  }
  for (; e < e1; ++e) {
    int s = src_s[e];
    float wv = nrm_s[e];
    unsigned v = *(const unsigned*)(xw16 + (size_t)s * FD + c);
    acc.x = fmaf(wv, bf2f((unsigned short)(v & 0xffff)), acc.x);
    acc.y = fmaf(wv, bf2f((unsigned short)(v >> 16)), acc.y);
  }
  *ap = (unsigned)f2bf(acc.x) | ((unsigned)f2bf(acc.y) << 16);
}

// ---------------- fused DCRNN cell (32-row blocks) ----------------
// block = 32 rows, 4 waves, 256 thr. As[32][264] = [bf16(agg)|bf16(hs)].
// ZR: wave w -> Z cols [w*32,w*32+32) (ni 0,1; z stays in registers) and
//     R cols 128+[w*32,w*32+32) (ni 2,3; hsr overwrites As hs-half).
// Ht: wave w -> cols [w*32,w*32+32); Hn epilogue re-reads hs fp32,
//     relu(Hn) bf16 -> As[:,0:128]. Classifier: waves 0,1 -> 16 rows each.

__global__ __launch_bounds__(256) void k_cell(
    const short* __restrict__ agg16, const float* __restrict__ hs,
    const short* __restrict__ wtzr, const short* __restrict__ wth,
    const short* __restrict__ wtl, const float* __restrict__ bzp,
    const float* __restrict__ brp, const float* __restrict__ bhp,
    const float* __restrict__ bl, float* __restrict__ probs,
    float* __restrict__ Hn) {
  __shared__ __align__(16) short As[32][264];   // 16.9 KB
  const int tid = threadIdx.x;
  const int w = tid >> 6, l = tid & 63, g = l >> 4, ln = l & 15;
  const int n0 = blockIdx.x * 32;
  const int srow = tid >> 3, sc = (tid & 7) << 2;

  // ---- stage As = [bf16(agg) | bf16(hs)], single barrier ----
  {
    int n = n0 + srow;
#pragma unroll
    for (int kc = 0; kc < 8; ++kc) {
      int kg = kc * 32 + sc;
      s16x4 av = {0, 0, 0, 0};
      if (n < NN) {
        if (kg < FD) {
          av = *(const s16x4*)(agg16 + (size_t)n * FD + kg);
        } else {
          float4 f0 = *(const float4*)(hs + (size_t)n * FD + (kg - FD));
          av[0] = (short)f2bf(f0.x); av[1] = (short)f2bf(f0.y);
          av[2] = (short)f2bf(f0.z); av[3] = (short)f2bf(f0.w);
        }
      }
      *(s16x4*)&As[srow][kg] = av;
    }
  }
  __syncthreads();

  // ---- ZR GEMM: acc[2][4] ----
  f32x4 zacc[2][2];
  {
    f32x4 acc[2][4];
#pragma unroll
    for (int mi = 0; mi < 2; ++mi)
#pragma unroll
      for (int ni = 0; ni < 4; ++ni) acc[mi][ni] = (f32x4){0.f, 0.f, 0.f, 0.f};
    const s16x8* wt8 = (const s16x8*)wtzr;  // row = 256 shorts = 32 units
#pragma unroll 2
    for (int kci = 0; kci < 8; ++kci) {
      s16x8 b[4], a[2];
#pragma unroll
      for (int ni = 0; ni < 4; ++ni) {
        int col = (ni < 2) ? (w * 32 + ni * 16 + ln)
                           : (FD + w * 32 + (ni - 2) * 16 + ln);
        b[ni] = wt8[(size_t)col * 32 + kci * 4 + g];
      }
#pragma unroll
      for (int mi = 0; mi < 2; ++mi)
        a[mi] = *(const s16x8*)&As[mi * 16 + ln][kci * 32 + g * 8];
#pragma unroll
      for (int mi = 0; mi < 2; ++mi)
#pragma unroll
        for (int ni = 0; ni < 4; ++ni)
          acc[mi][ni] = __builtin_amdgcn_mfma_f32_16x16x32_bf16(a[mi], b[ni], acc[mi][ni], 0, 0, 0);
    }
    __syncthreads();  // all waves done reading As hs-half

    float bz_c[2], br_c[2];
#pragma unroll
    for (int ni = 0; ni < 2; ++ni) {
      bz_c[ni] = bzp[w * 32 + ni * 16 + ln];
      br_c[ni] = brp[w * 32 + ni * 16 + ln];
    }
#pragma unroll
    for (int mi = 0; mi < 2; ++mi) {
#pragma unroll
      for (int r = 0; r < 4; ++r) {
        int row = mi * 16 + g * 4 + r;
#pragma unroll
        for (int ni = 0; ni < 2; ++ni) {
          zacc[mi][ni][r] = fast_sigmoid(acc[mi][ni][r] + bz_c[ni]);
          int cc = w * 32 + ni * 16 + ln;
          float rv = fast_sigmoid(acc[mi][ni + 2][r] + br_c[ni]);
          float hv = bf2f((unsigned short)As[row][FD + cc]);
          As[row][FD + cc] = (short)f2bf(rv * hv);
        }
      }
    }
  }
  __syncthreads();

  // ---- Ht GEMM: acc2[2][2] ----
  f32x4 acc2[2][2];
#pragma unroll
  for (int mi = 0; mi < 2; ++mi)
#pragma unroll
    for (int ni = 0; ni < 2; ++ni) acc2[mi][ni] = (f32x4){0.f, 0.f, 0.f, 0.f};
  {
    const s16x8* wt8 = (const s16x8*)wth;  // row = 256 shorts = 32 units
#pragma unroll 2
    for (int kci = 0; kci < 8; ++kci) {
      s16x8 b[2], a[2];
#pragma unroll
      for (int ni = 0; ni < 2; ++ni) {
        int col = w * 32 + ni * 16 + ln;
        b[ni] = wt8[(size_t)col * 32 + kci * 4 + g];
      }
#pragma unroll
      for (int mi = 0; mi < 2; ++mi)
        a[mi] = *(const s16x8*)&As[mi * 16 + ln][kci * 32 + g * 8];
#pragma unroll
      for (int mi = 0; mi < 2; ++mi)
#pragma unroll
        for (int ni = 0; ni < 2; ++ni)
          acc2[mi][ni] = __builtin_amdgcn_mfma_f32_16x16x32_bf16(a[mi], b[ni], acc2[mi][ni], 0, 0, 0);
    }
  }
  __syncthreads();  // all waves done reading As before relu(Hn) overwrite

  // ---- Hn epilogue ----
  {
    float bh_c[2];
#pragma unroll
    for (int ni = 0; ni < 2; ++ni) bh_c[ni] = bhp[w * 32 + ni * 16 + ln];
#pragma unroll
    for (int mi = 0; mi < 2; ++mi) {
#pragma unroll
      for (int r = 0; r < 4; ++r) {
        int row = mi * 16 + g * 4 + r;
        int n = n0 + row;
#pragma unroll
        for (int ni = 0; ni < 2; ++ni) {
          int c = w * 32 + ni * 16 + ln;
          float z = zacc[mi][ni][r];
          float ht = fast_tanh(acc2[mi][ni][r] + bh_c[ni]);
          if (n < NN) {
            float hv = hs[(size_t)n * FD + c];
            float hn = z * hv + (1.f - z) * ht;
            Hn[(size_t)n * FD + c] = hn;
            As[row][c] = (short)f2bf(fmaxf(hn, 0.f));
          } else {
            As[row][c] = 0;
          }
        }
      }
    }
  }
  __syncthreads();

  // ---- classifier: waves 0,1 -> rows [w*16, w*16+16); 16 classes ----
  if (w < 2) {
    f32x4 ac = (f32x4){0.f, 0.f, 0.f, 0.f};
    const s16x8* wtl8 = (const s16x8*)wtl;  // row = 128 shorts = 16 units
#pragma unroll
    for (int kci = 0; kci < 4; ++kci) {
      s16x8 a = *(const s16x8*)&As[w * 16 + ln][kci * 32 + g * 8];
      s16x8 bfr = wtl8[ln * 16 + kci * 4 + g];
      ac = __builtin_amdgcn_mfma_f32_16x16x32_bf16(a, bfr, ac, 0, 0, 0);
    }
    float blv = bl[ln];
#pragma unroll
    for (int r = 0; r < 4; ++r) {
      int n = n0 + w * 16 + g * 4 + r;
      float v = ac[r] + blv;
      float m = v;
#pragma unroll
      for (int msk = 1; msk < 16; msk <<= 1) m = fmaxf(m, __shfl_xor(m, msk, 64));
      float e = exp2f(1.44269504f * (v - m));
      float s = e;
#pragma unroll
      for (int msk = 1; msk < 16; msk <<= 1) s += __shfl_xor(s, msk, 64);
      if (n < NN) probs[(size_t)n * NCLS + ln] = e * __builtin_amdgcn_rcpf(s);
    }
  }
}

// ---------------- launch ----------------

extern "C" void kernel_launch(void* const* d_in, const int* in_sizes, int n_in,
                              void* d_out, int out_size, void* d_ws, size_t ws_size,
                              hipStream_t stream) {
  (void)in_sizes; (void)n_in; (void)out_size; (void)ws_size;
  const float* x   = (const float*)d_in[0];
  const int*   ei  = (const int*)d_in[1];
  const float* ew  = (const float*)d_in[2];
  const float* hs  = (const float*)d_in[3];
  const float* Wg  = (const float*)d_in[4];
  const float* bg  = (const float*)d_in[5];
  const float* Wz0 = (const float*)d_in[6];
  const float* Wz1 = (const float*)d_in[7];
  const float* bz  = (const float*)d_in[8];
  const float* Wr0 = (const float*)d_in[9];
  const float* Wr1 = (const float*)d_in[10];
  const float* br  = (const float*)d_in[11];
  const float* Wh0 = (const float*)d_in[12];
  const float* Wh1 = (const float*)d_in[13];
  const float* bh  = (const float*)d_in[14];
  const float* Wl  = (const float*)d_in[15];
  const float* bl  = (const float*)d_in[16];

  float* out   = (float*)d_out;
  float* probs = out;                      // [NN,16]
  float* Hn    = out + (size_t)NN * NCLS;  // [NN,128]

  float* w    = (float*)d_ws;
  float* dinv = w;                             // [NN]
  short* xw16 = (short*)(w + 50048);           // [NN*FD] bf16
  short* agg16 = (short*)(w + 50048 + (size_t)NN * FD);  // [NN*FD] bf16
  float* hsrf = w + 50048 + 2 * (size_t)NN * FD;         // CSR scratch region
  float* wsp  = hsrf + (size_t)NN * FD;        // tail: bf16 weights + biases

  short* wtzr = (short*)wsp;                       // 65536 shorts
  short* wth  = (short*)(wsp + 32768);             // 32768 shorts
  short* wtg  = (short*)(wsp + 32768 + 16384);     // 16384 shorts
  short* wtl  = (short*)(wsp + 32768 + 16384 + 8192);  // 2048 shorts
  float* bzp  = wsp + 32768 + 16384 + 8192 + 1024;
  float* brp  = bzp + 128;
  float* bhp  = brp + 128;

  // CSR scratch laid out in hsrf region (6.4M floats available):
  int*   src_s = (int*)hsrf;                        // [NE]
  float* nrm_s = hsrf + NE;                         // [NE]
  int*   basep = (int*)(hsrf + 2 * NE);             // [NN+1]
  int*   bsum  = (int*)(hsrf + 1650048);            // [SCAN_B]
  int*   boff  = (int*)(hsrf + 1650304);            // [SCAN_B]
  unsigned long long* parts = (unsigned long long*)(hsrf + 1651024);  // [NCOPY*NN]
  int*   cnt   = (int*)(hsrf + 3251040);            // [NN]
  int*   off16 = (int*)(hsrf + 3301040);            // [NCOPY*NN]

  k_prep_w<<<456, 256, 0, stream>>>(Wz0, Wz1, Wr0, Wr1, Wh0, Wh1, Wg, Wl,
                                    wtzr, wth, wtg, wtl);
  k_prep_bias<<<1, 128, 0, stream>>>(bg, Wz0, Wz1, Wr0, Wr1, Wh0, Wh1,
                                     bz, br, bh, bzp, brp, bhp);
  k_zero_parts<<<1024, 256, 0, stream>>>(parts);
  k_hist<<<1024, 256, 0, stream>>>(ei + NE, ew, parts);
  k_reduce<<<SCAN_B, 256, 0, stream>>>(parts, dinv, cnt);
  k_scan1<<<SCAN_B, 256, 0, stream>>>(cnt, basep, bsum);
  k_scan2<<<1, 256, 0, stream>>>(bsum, boff, basep);
  k_scan3<<<SCAN_B, 256, 0, stream>>>(basep, boff, parts, off16);
  k_reorder<<<1024, 256, 0, stream>>>(ei, ew, dinv, off16, src_s, nrm_s);
  k_xw_mfma<<<782, 256, 0, stream>>>(x, wtg, dinv, xw16, agg16);
  k_gather<<<12500, 256, 0, stream>>>(basep, src_s, nrm_s,
                                      (const unsigned short*)xw16,
                                      (unsigned short*)agg16);
  k_cell<<<1563, 256, 0, stream>>>(agg16, hs, wtzr, wth, wtl, bzp, brp, bhp,
                                   bl, probs, Hn);
}

// Round 14
// 215.347 us; speedup vs baseline: 4.4935x; 1.0177x over previous
//
#include <hip/hip_runtime.h>
#include <math.h>

#define NN 50000
#define NE 800000
#define FD 128
#define CIN 256
#define NCLS 16
#define SCAN_B 196   // ceil(NN/256)
#define NCOPY 16

typedef short s16x8 __attribute__((ext_vector_type(8)));
typedef short s16x4 __attribute__((ext_vector_type(4)));
typedef float f32x4 __attribute__((ext_vector_type(4)));

__device__ __forceinline__ unsigned short f2bf(float f) {
  union { float f; unsigned u; } v; v.f = f;
  unsigned r = v.u + 0x7fffu + ((v.u >> 16) & 1u);
  return (unsigned short)(r >> 16);
}

__device__ __forceinline__ float bf2f(unsigned short h) {
  union { unsigned u; float f; } v; v.u = ((unsigned)h) << 16;
  return v.f;
}

// fast transcendentals: v_exp_f32 computes 2^x; rcp is 1-instr approx
__device__ __forceinline__ float fast_sigmoid(float x) {
  return __builtin_amdgcn_rcpf(1.0f + exp2f(-1.44269504f * x));
}
__device__ __forceinline__ float fast_tanh(float x) {
  return 1.0f - 2.0f * __builtin_amdgcn_rcpf(1.0f + exp2f(2.88539008f * x));
}

// ---------------- weight prep: bf16 transposed WT[col][k] ----------------

__global__ void k_prep_w(const float* __restrict__ Wz0, const float* __restrict__ Wz1,
                         const float* __restrict__ Wr0, const float* __restrict__ Wr1,
                         const float* __restrict__ Wh0, const float* __restrict__ Wh1,
                         const float* __restrict__ Wg, const float* __restrict__ Wl,
                         short* __restrict__ wtzr, short* __restrict__ wth,
                         short* __restrict__ wtg, short* __restrict__ wtl) {
  int i = blockIdx.x * blockDim.x + threadIdx.x;
  if (i < 65536) {
    int n = i >> 8, k = i & 255;
    float v = (n < 128) ? (Wz0[k * 128 + n] + Wz1[k * 128 + n])
                        : (Wr0[k * 128 + (n - 128)] + Wr1[k * 128 + (n - 128)]);
    wtzr[i] = (short)f2bf(v);
  } else if (i < 98304) {
    int j = i - 65536; int n = j >> 8, k = j & 255;
    wth[j] = (short)f2bf(Wh0[k * 128 + n] + Wh1[k * 128 + n]);
  } else if (i < 114688) {
    int j = i - 98304; int n = j >> 7, k = j & 127;
    wtg[j] = (short)f2bf(Wg[k * 128 + n]);
  } else if (i < 116736) {
    int j = i - 114688; int n = j >> 7, k = j & 127;
    wtl[j] = (short)f2bf(Wl[k * 16 + n]);
  }
}

__global__ void k_prep_bias(const float* __restrict__ bg,
                            const float* __restrict__ Wz0, const float* __restrict__ Wz1,
                            const float* __restrict__ Wr0, const float* __restrict__ Wr1,
                            const float* __restrict__ Wh0, const float* __restrict__ Wh1,
                            const float* __restrict__ bz, const float* __restrict__ br,
                            const float* __restrict__ bh,
                            float* __restrict__ bzp, float* __restrict__ brp,
                            float* __restrict__ bhp) {
  int c = threadIdx.x;
  if (c >= 128) return;
  float sz = bz[c], sr = br[c], sh = bh[c];
  for (int k = 0; k < 128; ++k) {
    float g = bg[k];
    sz += g * (Wz0[k * 128 + c] + Wz1[k * 128 + c]);
    sr += g * (Wr0[k * 128 + c] + Wr1[k * 128 + c]);
    sh += g * (Wh0[k * 128 + c] + Wh1[k * 128 + c]);
  }
  bzp[c] = sz; brp[c] = sr; bhp[c] = sh;
}

// ---------------- CSR build: privatized packed histogram ----------------

__global__ void k_zero_parts(unsigned long long* __restrict__ parts) {
  int i = blockIdx.x * blockDim.x + threadIdx.x;
  int stride = gridDim.x * blockDim.x;
  for (; i < NCOPY * NN; i += stride) parts[i] = 0ULL;
}

__global__ void k_hist(const int* __restrict__ dst, const float* __restrict__ ew,
                       unsigned long long* __restrict__ parts) {
  const int c = blockIdx.x & (NCOPY - 1);
  unsigned long long* __restrict__ p = parts + (size_t)c * NN;
  int i = blockIdx.x * blockDim.x + threadIdx.x;
  int stride = gridDim.x * blockDim.x;
  for (int e = i; e < NE; e += stride) {
    int d = dst[e];
    unsigned long long pk = (1ULL << 40) +
        (unsigned long long)(ew[e] * 4294967296.0f + 0.5f);
    atomicAdd(&p[d], pk);
  }
}

__global__ void k_reduce(const unsigned long long* __restrict__ parts,
                         float* __restrict__ dinv, int* __restrict__ cnt) {
  int i = blockIdx.x * blockDim.x + threadIdx.x;
  if (i >= NN) return;
  int ct = 0;
  double frac = 0.0;
#pragma unroll
  for (int c = 0; c < NCOPY; ++c) {
    unsigned long long v = parts[(size_t)c * NN + i];
    ct += (int)(v >> 40);
    frac += (double)(v & 0xFFFFFFFFFFULL);
  }
  cnt[i] = ct;
  double deg = 1.0 + frac * (1.0 / 4294967296.0);
  dinv[i] = rsqrtf((float)deg);
}

__global__ __launch_bounds__(256) void k_scan1(const int* __restrict__ cnt,
                                               int* __restrict__ base,
                                               int* __restrict__ bsum) {
  __shared__ int ts[256];
  const int t = threadIdx.x, b = blockIdx.x;
  const int i = b * 256 + t;
  int v = (i < NN) ? cnt[i] : 0;
  ts[t] = v;
  __syncthreads();
#pragma unroll
  for (int off = 1; off < 256; off <<= 1) {
    int u = (t >= off) ? ts[t - off] : 0;
    __syncthreads();
    ts[t] += u;
    __syncthreads();
  }
  if (i < NN) base[i] = ts[t] - v;
  if (t == 255) bsum[b] = ts[255];
}

__global__ __launch_bounds__(256) void k_scan2(const int* __restrict__ bsum,
                                               int* __restrict__ boff,
                                               int* __restrict__ base) {
  __shared__ int ts[256];
  const int t = threadIdx.x;
  int v = (t < SCAN_B) ? bsum[t] : 0;
  ts[t] = v;
  __syncthreads();
#pragma unroll
  for (int off = 1; off < 256; off <<= 1) {
    int u = (t >= off) ? ts[t - off] : 0;
    __syncthreads();
    ts[t] += u;
    __syncthreads();
  }
  if (t < SCAN_B) boff[t] = ts[t] - v;
  if (t == 255) base[NN] = ts[255];
}

__global__ __launch_bounds__(256) void k_scan3(int* __restrict__ base,
                                               const int* __restrict__ boff,
                                               const unsigned long long* __restrict__ parts,
                                               int* __restrict__ off16) {
  const int i = blockIdx.x * 256 + threadIdx.x;
  if (i >= NN) return;
  int b = base[i] + boff[blockIdx.x];
  base[i] = b;
  int run = b;
#pragma unroll
  for (int c = 0; c < NCOPY; ++c) {
    off16[(size_t)c * NN + i] = run;
    run += (int)(parts[(size_t)c * NN + i] >> 40);
  }
}

// scatter edges into dst-sorted order: ONE packed 8B store per edge
// NOTE: grid/stride and c = blockIdx&15 MUST match k_hist exactly
__global__ void k_reorder(const int* __restrict__ ei, const float* __restrict__ ew,
                          const float* __restrict__ dinv,
                          int* __restrict__ off16, int2* __restrict__ edge_s) {
  const int c = blockIdx.x & (NCOPY - 1);
  int* __restrict__ cur = off16 + (size_t)c * NN;
  int i = blockIdx.x * blockDim.x + threadIdx.x;
  int stride = gridDim.x * blockDim.x;
  const int* __restrict__ src = ei;
  const int* __restrict__ dst = ei + NE;
  for (int e = i; e < NE; e += stride) {
    int s = src[e], d = dst[e];
    int pos = atomicAdd(&cur[d], 1);
    float nrm = dinv[s] * ew[e] * dinv[d];
    edge_s[pos] = make_int2(s, __float_as_int(nrm));
  }
}

// ------- MFMA GEMM: xw16(bf16) = x @ Wg ; agg16(bf16) = xw * dinv^2 -------

__global__ __launch_bounds__(256) void k_xw_mfma(
    const float* __restrict__ x, const short* __restrict__ wtg,
    const float* __restrict__ dinv, short* __restrict__ xw16,
    short* __restrict__ agg16) {
  __shared__ __align__(16) short As[64][40];
  const int tid = threadIdx.x;
  const int w = tid >> 6, l = tid & 63, g = l >> 4, ln = l & 15;
  const int n0 = blockIdx.x * 64;
  const int srow = tid >> 2, sk0 = (tid & 3) << 3;
  const s16x8* wt8 = (const s16x8*)wtg;

  f32x4 acc[4][2];
#pragma unroll
  for (int mi = 0; mi < 4; ++mi)
#pragma unroll
    for (int ni = 0; ni < 2; ++ni) acc[mi][ni] = (f32x4){0.f, 0.f, 0.f, 0.f};

  for (int kci = 0; kci < 4; ++kci) {
    int kg = kci * 32 + sk0;
    int n = n0 + srow;
    s16x8 av = {0, 0, 0, 0, 0, 0, 0, 0};
    if (n < NN) {
      const float* src = x + (size_t)n * FD + kg;
      float4 f0 = *(const float4*)src;
      float4 f1 = *(const float4*)(src + 4);
      av[0] = (short)f2bf(f0.x); av[1] = (short)f2bf(f0.y);
      av[2] = (short)f2bf(f0.z); av[3] = (short)f2bf(f0.w);
      av[4] = (short)f2bf(f1.x); av[5] = (short)f2bf(f1.y);
      av[6] = (short)f2bf(f1.z); av[7] = (short)f2bf(f1.w);
    }
    __syncthreads();
    *(s16x8*)&As[srow][sk0] = av;
    __syncthreads();
    s16x8 b[2], a[4];
#pragma unroll
    for (int ni = 0; ni < 2; ++ni) {
      int col = w * 32 + ni * 16 + ln;
      b[ni] = wt8[(size_t)col * 16 + kci * 4 + g];
    }
#pragma unroll
    for (int mi = 0; mi < 4; ++mi) a[mi] = *(const s16x8*)&As[mi * 16 + ln][g * 8];
#pragma unroll
    for (int mi = 0; mi < 4; ++mi)
#pragma unroll
      for (int ni = 0; ni < 2; ++ni)
        acc[mi][ni] = __builtin_amdgcn_mfma_f32_16x16x32_bf16(a[mi], b[ni], acc[mi][ni], 0, 0, 0);
  }
#pragma unroll
  for (int mi = 0; mi < 4; ++mi) {
#pragma unroll
    for (int r = 0; r < 4; ++r) {
      int n = n0 + mi * 16 + g * 4 + r;
      if (n >= NN) continue;
      float di = dinv[n];
      float d2 = di * di;
#pragma unroll
      for (int ni = 0; ni < 2; ++ni) {
        int c = w * 32 + ni * 16 + ln;
        float v = acc[mi][ni][r];
        xw16[(size_t)n * FD + c] = (short)f2bf(v);
        agg16[(size_t)n * FD + c] = (short)f2bf(v * d2);
      }
    }
  }
}

// -------- CSR gather: packed edges, bf16 xw, fp32 reg accumulate ----------

__global__ __launch_bounds__(256) void k_gather(
    const int* __restrict__ base, const int2* __restrict__ edge_s,
    const unsigned short* __restrict__ xw16, unsigned short* __restrict__ agg16) {
  const int lane = threadIdx.x & 63;
  const int n = blockIdx.x * 4 + (threadIdx.x >> 6);
  if (n >= NN) return;
  const int e0 = base[n], e1 = base[n + 1];
  const int c = lane * 2;
  unsigned* ap = (unsigned*)(agg16 + (size_t)n * FD + c);
  unsigned iv = *ap;
  float2 acc = make_float2(bf2f((unsigned short)(iv & 0xffff)),
                           bf2f((unsigned short)(iv >> 16)));
  int e = e0;
  for (; e + 4 <= e1; e += 4) {
    int2 ed0 = edge_s[e], ed1 = edge_s[e + 1];
    int2 ed2 = edge_s[e + 2], ed3 = edge_s[e + 3];
    float w0 = __int_as_float(ed0.y), w1 = __int_as_float(ed1.y);
    float w2 = __int_as_float(ed2.y), w3 = __int_as_float(ed3.y);
    unsigned v0 = *(const unsigned*)(xw16 + (size_t)ed0.x * FD + c);
    unsigned v1 = *(const unsigned*)(xw16 + (size_t)ed1.x * FD + c);
    unsigned v2 = *(const unsigned*)(xw16 + (size_t)ed2.x * FD + c);
    unsigned v3 = *(const unsigned*)(xw16 + (size_t)ed3.x * FD + c);
    acc.x = fmaf(w0, bf2f((unsigned short)(v0 & 0xffff)), acc.x);
    acc.y = fmaf(w0, bf2f((unsigned short)(v0 >> 16)), acc.y);
    acc.x = fmaf(w1, bf2f((unsigned short)(v1 & 0xffff)), acc.x);
    acc.y = fmaf(w1, bf2f((unsigned short)(v1 >> 16)), acc.y);
    acc.x = fmaf(w2, bf2f((unsigned short)(v2 & 0xffff)), acc.x);
    acc.y = fmaf(w2, bf2f((unsigned short)(v2 >> 16)), acc.y);
    acc.x = fmaf(w3, bf2f((unsigned short)(v3 & 0xffff)), acc.x);
    acc.y = fmaf(w3, bf2f((unsigned short)(v3 >> 16)), acc.y);
  }
  for (; e < e1; ++e) {
    int2 ed = edge_s[e];
    float wv = __int_as_float(ed.y);
    unsigned v = *(const unsigned*)(xw16 + (size_t)ed.x * FD + c);
    acc.x = fmaf(wv, bf2f((unsigned short)(v & 0xffff)), acc.x);
    acc.y = fmaf(wv, bf2f((unsigned short)(v >> 16)), acc.y);
  }
  *ap = (unsigned)f2bf(acc.x) | ((unsigned)f2bf(acc.y) << 16);
}

// ---------------- fused DCRNN cell (32-row blocks) ----------------
// block = 32 rows, 4 waves. As[32][264] = [bf16(agg)|bf16(hs)].
// ZR: wave w -> Z cols [w*32,w*32+32) (z in registers) and R cols
//   128+[w*32,w*32+32) (hsr overwrites As hs-half; hv saved in REGISTERS —
//   same (row,col) owner consumes it in the Hn epilogue, no global re-read).
// Ht: wave w -> cols [w*32,w*32+32); relu(Hn) bf16 -> As[:,0:128].
// Classifier: waves 0,1 -> 16 rows each.

__global__ __launch_bounds__(256) void k_cell(
    const short* __restrict__ agg16, const float* __restrict__ hs,
    const short* __restrict__ wtzr, const short* __restrict__ wth,
    const short* __restrict__ wtl, const float* __restrict__ bzp,
    const float* __restrict__ brp, const float* __restrict__ bhp,
    const float* __restrict__ bl, float* __restrict__ probs,
    float* __restrict__ Hn) {
  __shared__ __align__(16) short As[32][264];   // 16.9 KB
  const int tid = threadIdx.x;
  const int w = tid >> 6, l = tid & 63, g = l >> 4, ln = l & 15;
  const int n0 = blockIdx.x * 32;
  const int srow = tid >> 3, sc = (tid & 7) << 2;

  // ---- stage As = [bf16(agg) | bf16(hs)], single barrier ----
  {
    int n = n0 + srow;
#pragma unroll
    for (int kc = 0; kc < 8; ++kc) {
      int kg = kc * 32 + sc;
      s16x4 av = {0, 0, 0, 0};
      if (n < NN) {
        if (kg < FD) {
          av = *(const s16x4*)(agg16 + (size_t)n * FD + kg);
        } else {
          float4 f0 = *(const float4*)(hs + (size_t)n * FD + (kg - FD));
          av[0] = (short)f2bf(f0.x); av[1] = (short)f2bf(f0.y);
          av[2] = (short)f2bf(f0.z); av[3] = (short)f2bf(f0.w);
        }
      }
      *(s16x4*)&As[srow][kg] = av;
    }
  }
  __syncthreads();

  // ---- ZR GEMM: acc[2][4] ----
  f32x4 zacc[2][2];
  f32x4 hvreg[2][2];  // bf16(hs) values this thread owns, live to Hn epilogue
  {
    f32x4 acc[2][4];
#pragma unroll
    for (int mi = 0; mi < 2; ++mi)
#pragma unroll
      for (int ni = 0; ni < 4; ++ni) acc[mi][ni] = (f32x4){0.f, 0.f, 0.f, 0.f};
    const s16x8* wt8 = (const s16x8*)wtzr;  // row = 256 shorts = 32 units
#pragma unroll 2
    for (int kci = 0; kci < 8; ++kci) {
      s16x8 b[4], a[2];
#pragma unroll
      for (int ni = 0; ni < 4; ++ni) {
        int col = (ni < 2) ? (w * 32 + ni * 16 + ln)
                           : (FD + w * 32 + (ni - 2) * 16 + ln);
        b[ni] = wt8[(size_t)col * 32 + kci * 4 + g];
      }
#pragma unroll
      for (int mi = 0; mi < 2; ++mi)
        a[mi] = *(const s16x8*)&As[mi * 16 + ln][kci * 32 + g * 8];
#pragma unroll
      for (int mi = 0; mi < 2; ++mi)
#pragma unroll
        for (int ni = 0; ni < 4; ++ni)
          acc[mi][ni] = __builtin_amdgcn_mfma_f32_16x16x32_bf16(a[mi], b[ni], acc[mi][ni], 0, 0, 0);
    }
    __syncthreads();  // all waves done reading As hs-half

    float bz_c[2], br_c[2];
#pragma unroll
    for (int ni = 0; ni < 2; ++ni) {
      bz_c[ni] = bzp[w * 32 + ni * 16 + ln];
      br_c[ni] = brp[w * 32 + ni * 16 + ln];
    }
#pragma unroll
    for (int mi = 0; mi < 2; ++mi) {
#pragma unroll
      for (int r = 0; r < 4; ++r) {
        int row = mi * 16 + g * 4 + r;
#pragma unroll
        for (int ni = 0; ni < 2; ++ni) {
          zacc[mi][ni][r] = fast_sigmoid(acc[mi][ni][r] + bz_c[ni]);
          int cc = w * 32 + ni * 16 + ln;
          float rv = fast_sigmoid(acc[mi][ni + 2][r] + br_c[ni]);
          float hv = bf2f((unsigned short)As[row][FD + cc]);
          hvreg[mi][ni][r] = hv;
          As[row][FD + cc] = (short)f2bf(rv * hv);
        }
      }
    }
  }
  __syncthreads();

  // ---- Ht GEMM: acc2[2][2] ----
  f32x4 acc2[2][2];
#pragma unroll
  for (int mi = 0; mi < 2; ++mi)
#pragma unroll
    for (int ni = 0; ni < 2; ++ni) acc2[mi][ni] = (f32x4){0.f, 0.f, 0.f, 0.f};
  {
    const s16x8* wt8 = (const s16x8*)wth;  // row = 256 shorts = 32 units
#pragma unroll 2
    for (int kci = 0; kci < 8; ++kci) {
      s16x8 b[2], a[2];
#pragma unroll
      for (int ni = 0; ni < 2; ++ni) {
        int col = w * 32 + ni * 16 + ln;
        b[ni] = wt8[(size_t)col * 32 + kci * 4 + g];
      }
#pragma unroll
      for (int mi = 0; mi < 2; ++mi)
        a[mi] = *(const s16x8*)&As[mi * 16 + ln][kci * 32 + g * 8];
#pragma unroll
      for (int mi = 0; mi < 2; ++mi)
#pragma unroll
        for (int ni = 0; ni < 2; ++ni)
          acc2[mi][ni] = __builtin_amdgcn_mfma_f32_16x16x32_bf16(a[mi], b[ni], acc2[mi][ni], 0, 0, 0);
    }
  }
  __syncthreads();  // all waves done reading As before relu(Hn) overwrite

  // ---- Hn epilogue: hv from registers, no global hs re-read ----
  {
    float bh_c[2];
#pragma unroll
    for (int ni = 0; ni < 2; ++ni) bh_c[ni] = bhp[w * 32 + ni * 16 + ln];
#pragma unroll
    for (int mi = 0; mi < 2; ++mi) {
#pragma unroll
      for (int r = 0; r < 4; ++r) {
        int row = mi * 16 + g * 4 + r;
        int n = n0 + row;
#pragma unroll
        for (int ni = 0; ni < 2; ++ni) {
          int c = w * 32 + ni * 16 + ln;
          float z = zacc[mi][ni][r];
          float ht = fast_tanh(acc2[mi][ni][r] + bh_c[ni]);
          float hv = hvreg[mi][ni][r];
          float hn = z * hv + (1.f - z) * ht;
          if (n < NN) {
            Hn[(size_t)n * FD + c] = hn;
            As[row][c] = (short)f2bf(fmaxf(hn, 0.f));
          } else {
            As[row][c] = 0;
          }
        }
      }
    }
  }
  __syncthreads();

  // ---- classifier: waves 0,1 -> rows [w*16, w*16+16); 16 classes ----
  if (w < 2) {
    f32x4 ac = (f32x4){0.f, 0.f, 0.f, 0.f};
    const s16x8* wtl8 = (const s16x8*)wtl;  // row = 128 shorts = 16 units
#pragma unroll
    for (int kci = 0; kci < 4; ++kci) {
      s16x8 a = *(const s16x8*)&As[w * 16 + ln][kci * 32 + g * 8];
      s16x8 bfr = wtl8[ln * 16 + kci * 4 + g];
      ac = __builtin_amdgcn_mfma_f32_16x16x32_bf16(a, bfr, ac, 0, 0, 0);
    }
    float blv = bl[ln];
#pragma unroll
    for (int r = 0; r < 4; ++r) {
      int n = n0 + w * 16 + g * 4 + r;
      float v = ac[r] + blv;
      float m = v;
#pragma unroll
      for (int msk = 1; msk < 16; msk <<= 1) m = fmaxf(m, __shfl_xor(m, msk, 64));
      float e = exp2f(1.44269504f * (v - m));
      float s = e;
#pragma unroll
      for (int msk = 1; msk < 16; msk <<= 1) s += __shfl_xor(s, msk, 64);
      if (n < NN) probs[(size_t)n * NCLS + ln] = e * __builtin_amdgcn_rcpf(s);
    }
  }
}

// ---------------- launch ----------------

extern "C" void kernel_launch(void* const* d_in, const int* in_sizes, int n_in,
                              void* d_out, int out_size, void* d_ws, size_t ws_size,
                              hipStream_t stream) {
  (void)in_sizes; (void)n_in; (void)out_size; (void)ws_size;
  const float* x   = (const float*)d_in[0];
  const int*   ei  = (const int*)d_in[1];
  const float* ew  = (const float*)d_in[2];
  const float* hs  = (const float*)d_in[3];
  const float* Wg  = (const float*)d_in[4];
  const float* bg  = (const float*)d_in[5];
  const float* Wz0 = (const float*)d_in[6];
  const float* Wz1 = (const float*)d_in[7];
  const float* bz  = (const float*)d_in[8];
  const float* Wr0 = (const float*)d_in[9];
  const float* Wr1 = (const float*)d_in[10];
  const float* br  = (const float*)d_in[11];
  const float* Wh0 = (const float*)d_in[12];
  const float* Wh1 = (const float*)d_in[13];
  const float* bh  = (const float*)d_in[14];
  const float* Wl  = (const float*)d_in[15];
  const float* bl  = (const float*)d_in[16];

  float* out   = (float*)d_out;
  float* probs = out;                      // [NN,16]
  float* Hn    = out + (size_t)NN * NCLS;  // [NN,128]

  float* w    = (float*)d_ws;
  float* dinv = w;                             // [NN]
  short* xw16 = (short*)(w + 50048);           // [NN*FD] bf16
  short* agg16 = (short*)(w + 50048 + (size_t)NN * FD);  // [NN*FD] bf16
  float* hsrf = w + 50048 + 2 * (size_t)NN * FD;         // CSR scratch region
  float* wsp  = hsrf + (size_t)NN * FD;        // tail: bf16 weights + biases

  short* wtzr = (short*)wsp;                       // 65536 shorts
  short* wth  = (short*)(wsp + 32768);             // 32768 shorts
  short* wtg  = (short*)(wsp + 32768 + 16384);     // 16384 shorts
  short* wtl  = (short*)(wsp + 32768 + 16384 + 8192);  // 2048 shorts
  float* bzp  = wsp + 32768 + 16384 + 8192 + 1024;
  float* brp  = bzp + 128;
  float* bhp  = brp + 128;

  // CSR scratch laid out in hsrf region (6.4M floats available):
  int2*  edge_s = (int2*)hsrf;                      // [NE] packed (src, nrm)
  int*   basep = (int*)(hsrf + 2 * NE);             // [NN+1]
  int*   bsum  = (int*)(hsrf + 1650048);            // [SCAN_B]
  int*   boff  = (int*)(hsrf + 1650304);            // [SCAN_B]
  unsigned long long* parts = (unsigned long long*)(hsrf + 1651024);  // [NCOPY*NN]
  int*   cnt   = (int*)(hsrf + 3251040);            // [NN]
  int*   off16 = (int*)(hsrf + 3301040);            // [NCOPY*NN]

  k_prep_w<<<456, 256, 0, stream>>>(Wz0, Wz1, Wr0, Wr1, Wh0, Wh1, Wg, Wl,
                                    wtzr, wth, wtg, wtl);
  k_prep_bias<<<1, 128, 0, stream>>>(bg, Wz0, Wz1, Wr0, Wr1, Wh0, Wh1,
                                     bz, br, bh, bzp, brp, bhp);
  k_zero_parts<<<1024, 256, 0, stream>>>(parts);
  k_hist<<<1024, 256, 0, stream>>>(ei + NE, ew, parts);
  k_reduce<<<SCAN_B, 256, 0, stream>>>(parts, dinv, cnt);
  k_scan1<<<SCAN_B, 256, 0, stream>>>(cnt, basep, bsum);
  k_scan2<<<1, 256, 0, stream>>>(bsum, boff, basep);
  k_scan3<<<SCAN_B, 256, 0, stream>>>(basep, boff, parts, off16);
  k_reorder<<<1024, 256, 0, stream>>>(ei, ew, dinv, off16, edge_s);
  k_xw_mfma<<<782, 256, 0, stream>>>(x, wtg, dinv, xw16, agg16);
  k_gather<<<12500, 256, 0, stream>>>(basep, edge_s,
                                      (const unsigned short*)xw16,
                                      (unsigned short*)agg16);
  k_cell<<<1563, 256, 0, stream>>>(agg16, hs, wtzr, wth, wtl, bzp, brp, bhp,
                                   bl, probs, Hn);
}

// Round 15
// 204.366 us; speedup vs baseline: 4.7349x; 1.0537x over previous
//
#include <hip/hip_runtime.h>
#include <math.h>

#define NN 50000
#define NE 800000
#define FD 128
#define CIN 256
#define NCLS 16
#define SCAN_B 196   // ceil(NN/256)
#define NCOPY 16

typedef short s16x8 __attribute__((ext_vector_type(8)));
typedef short s16x4 __attribute__((ext_vector_type(4)));
typedef float f32x4 __attribute__((ext_vector_type(4)));

__device__ __forceinline__ unsigned short f2bf(float f) {
  union { float f; unsigned u; } v; v.f = f;
  unsigned r = v.u + 0x7fffu + ((v.u >> 16) & 1u);
  return (unsigned short)(r >> 16);
}

__device__ __forceinline__ float bf2f(unsigned short h) {
  union { unsigned u; float f; } v; v.u = ((unsigned)h) << 16;
  return v.f;
}

// fast transcendentals: v_exp_f32 computes 2^x; rcp is 1-instr approx
__device__ __forceinline__ float fast_sigmoid(float x) {
  return __builtin_amdgcn_rcpf(1.0f + exp2f(-1.44269504f * x));
}
__device__ __forceinline__ float fast_tanh(float x) {
  return 1.0f - 2.0f * __builtin_amdgcn_rcpf(1.0f + exp2f(2.88539008f * x));
}

// ------- fused prep: zero parts + bf16 weight transpose + bias fold -------

__global__ void k_prep(const float* __restrict__ Wz0, const float* __restrict__ Wz1,
                       const float* __restrict__ Wr0, const float* __restrict__ Wr1,
                       const float* __restrict__ Wh0, const float* __restrict__ Wh1,
                       const float* __restrict__ Wg, const float* __restrict__ Wl,
                       const float* __restrict__ bg, const float* __restrict__ bz,
                       const float* __restrict__ br, const float* __restrict__ bh,
                       short* __restrict__ wtzr, short* __restrict__ wth,
                       short* __restrict__ wtg, short* __restrict__ wtl,
                       float* __restrict__ bzp, float* __restrict__ brp,
                       float* __restrict__ bhp,
                       unsigned long long* __restrict__ parts) {
  int i = blockIdx.x * blockDim.x + threadIdx.x;
  int stride = gridDim.x * blockDim.x;
  for (int j = i; j < NCOPY * NN; j += stride) parts[j] = 0ULL;
  if (i < 65536) {
    int n = i >> 8, k = i & 255;
    float v = (n < 128) ? (Wz0[k * 128 + n] + Wz1[k * 128 + n])
                        : (Wr0[k * 128 + (n - 128)] + Wr1[k * 128 + (n - 128)]);
    wtzr[i] = (short)f2bf(v);
  } else if (i < 98304) {
    int j = i - 65536; int n = j >> 8, k = j & 255;
    wth[j] = (short)f2bf(Wh0[k * 128 + n] + Wh1[k * 128 + n]);
  } else if (i < 114688) {
    int j = i - 98304; int n = j >> 7, k = j & 127;
    wtg[j] = (short)f2bf(Wg[k * 128 + n]);
  } else if (i < 116736) {
    int j = i - 114688; int n = j >> 7, k = j & 127;
    wtl[j] = (short)f2bf(Wl[k * 16 + n]);
  } else if (i < 116864) {
    int c = i - 116736;
    float sz = bz[c], sr = br[c], sh = bh[c];
    for (int k = 0; k < 128; ++k) {
      float gv = bg[k];
      sz += gv * (Wz0[k * 128 + c] + Wz1[k * 128 + c]);
      sr += gv * (Wr0[k * 128 + c] + Wr1[k * 128 + c]);
      sh += gv * (Wh0[k * 128 + c] + Wh1[k * 128 + c]);
    }
    bzp[c] = sz; brp[c] = sr; bhp[c] = sh;
  }
}

// ---------------- CSR build: privatized packed histogram ----------------

__global__ void k_hist(const int* __restrict__ dst, const float* __restrict__ ew,
                       unsigned long long* __restrict__ parts) {
  const int c = blockIdx.x & (NCOPY - 1);
  unsigned long long* __restrict__ p = parts + (size_t)c * NN;
  int i = blockIdx.x * blockDim.x + threadIdx.x;
  int stride = gridDim.x * blockDim.x;
  for (int e = i; e < NE; e += stride) {
    int d = dst[e];
    unsigned long long pk = (1ULL << 40) +
        (unsigned long long)(ew[e] * 4294967296.0f + 0.5f);
    atomicAdd(&p[d], pk);
  }
}

// fused: fold copies -> dinv ; block-local exclusive scan of counts
__global__ __launch_bounds__(256) void k_reduce_scan1(
    const unsigned long long* __restrict__ parts, float* __restrict__ dinv,
    int* __restrict__ base, int* __restrict__ bsum) {
  __shared__ int ts[256];
  const int t = threadIdx.x, b = blockIdx.x;
  const int i = b * 256 + t;
  int ct = 0;
  if (i < NN) {
    double frac = 0.0;
#pragma unroll
    for (int c = 0; c < NCOPY; ++c) {
      unsigned long long v = parts[(size_t)c * NN + i];
      ct += (int)(v >> 40);
      frac += (double)(v & 0xFFFFFFFFFFULL);
    }
    double deg = 1.0 + frac * (1.0 / 4294967296.0);
    dinv[i] = rsqrtf((float)deg);
  }
  ts[t] = ct;
  __syncthreads();
#pragma unroll
  for (int off = 1; off < 256; off <<= 1) {
    int u = (t >= off) ? ts[t - off] : 0;
    __syncthreads();
    ts[t] += u;
    __syncthreads();
  }
  if (i < NN) base[i] = ts[t] - ct;
  if (t == 255) bsum[b] = ts[255];
}

__global__ __launch_bounds__(256) void k_scan2(const int* __restrict__ bsum,
                                               int* __restrict__ boff,
                                               int* __restrict__ base) {
  __shared__ int ts[256];
  const int t = threadIdx.x;
  int v = (t < SCAN_B) ? bsum[t] : 0;
  ts[t] = v;
  __syncthreads();
#pragma unroll
  for (int off = 1; off < 256; off <<= 1) {
    int u = (t >= off) ? ts[t - off] : 0;
    __syncthreads();
    ts[t] += u;
    __syncthreads();
  }
  if (t < SCAN_B) boff[t] = ts[t] - v;
  if (t == 255) base[NN] = ts[255];
}

__global__ __launch_bounds__(256) void k_scan3(int* __restrict__ base,
                                               const int* __restrict__ boff,
                                               const unsigned long long* __restrict__ parts,
                                               int* __restrict__ off16) {
  const int i = blockIdx.x * 256 + threadIdx.x;
  if (i >= NN) return;
  int b = base[i] + boff[blockIdx.x];
  base[i] = b;
  int run = b;
#pragma unroll
  for (int c = 0; c < NCOPY; ++c) {
    off16[(size_t)c * NN + i] = run;
    run += (int)(parts[(size_t)c * NN + i] >> 40);
  }
}

// scatter edges into dst-sorted order: ONE packed 8B store per edge
// NOTE: grid/stride and c = blockIdx&15 MUST match k_hist exactly
__global__ void k_reorder(const int* __restrict__ ei, const float* __restrict__ ew,
                          const float* __restrict__ dinv,
                          int* __restrict__ off16, int2* __restrict__ edge_s) {
  const int c = blockIdx.x & (NCOPY - 1);
  int* __restrict__ cur = off16 + (size_t)c * NN;
  int i = blockIdx.x * blockDim.x + threadIdx.x;
  int stride = gridDim.x * blockDim.x;
  const int* __restrict__ src = ei;
  const int* __restrict__ dst = ei + NE;
  for (int e = i; e < NE; e += stride) {
    int s = src[e], d = dst[e];
    int pos = atomicAdd(&cur[d], 1);
    float nrm = dinv[s] * ew[e] * dinv[d];
    edge_s[pos] = make_int2(s, __float_as_int(nrm));
  }
}

// ------- MFMA GEMM: xw16(bf16) = x @ Wg ; agg16(bf16) = xw * dinv^2 -------

__global__ __launch_bounds__(256) void k_xw_mfma(
    const float* __restrict__ x, const short* __restrict__ wtg,
    const float* __restrict__ dinv, short* __restrict__ xw16,
    short* __restrict__ agg16) {
  __shared__ __align__(16) short As[64][40];
  const int tid = threadIdx.x;
  const int w = tid >> 6, l = tid & 63, g = l >> 4, ln = l & 15;
  const int n0 = blockIdx.x * 64;
  const int srow = tid >> 2, sk0 = (tid & 3) << 3;
  const s16x8* wt8 = (const s16x8*)wtg;

  f32x4 acc[4][2];
#pragma unroll
  for (int mi = 0; mi < 4; ++mi)
#pragma unroll
    for (int ni = 0; ni < 2; ++ni) acc[mi][ni] = (f32x4){0.f, 0.f, 0.f, 0.f};

  for (int kci = 0; kci < 4; ++kci) {
    int kg = kci * 32 + sk0;
    int n = n0 + srow;
    s16x8 av = {0, 0, 0, 0, 0, 0, 0, 0};
    if (n < NN) {
      const float* src = x + (size_t)n * FD + kg;
      float4 f0 = *(const float4*)src;
      float4 f1 = *(const float4*)(src + 4);
      av[0] = (short)f2bf(f0.x); av[1] = (short)f2bf(f0.y);
      av[2] = (short)f2bf(f0.z); av[3] = (short)f2bf(f0.w);
      av[4] = (short)f2bf(f1.x); av[5] = (short)f2bf(f1.y);
      av[6] = (short)f2bf(f1.z); av[7] = (short)f2bf(f1.w);
    }
    __syncthreads();
    *(s16x8*)&As[srow][sk0] = av;
    __syncthreads();
    s16x8 b[2], a[4];
#pragma unroll
    for (int ni = 0; ni < 2; ++ni) {
      int col = w * 32 + ni * 16 + ln;
      b[ni] = wt8[(size_t)col * 16 + kci * 4 + g];
    }
#pragma unroll
    for (int mi = 0; mi < 4; ++mi) a[mi] = *(const s16x8*)&As[mi * 16 + ln][g * 8];
#pragma unroll
    for (int mi = 0; mi < 4; ++mi)
#pragma unroll
      for (int ni = 0; ni < 2; ++ni)
        acc[mi][ni] = __builtin_amdgcn_mfma_f32_16x16x32_bf16(a[mi], b[ni], acc[mi][ni], 0, 0, 0);
  }
#pragma unroll
  for (int mi = 0; mi < 4; ++mi) {
#pragma unroll
    for (int r = 0; r < 4; ++r) {
      int n = n0 + mi * 16 + g * 4 + r;
      if (n >= NN) continue;
      float di = dinv[n];
      float d2 = di * di;
#pragma unroll
      for (int ni = 0; ni < 2; ++ni) {
        int c = w * 32 + ni * 16 + ln;
        float v = acc[mi][ni][r];
        xw16[(size_t)n * FD + c] = (short)f2bf(v);
        agg16[(size_t)n * FD + c] = (short)f2bf(v * d2);
      }
    }
  }
}

// -------- CSR gather: packed edges, bf16 xw, fp32 reg accumulate ----------

__global__ __launch_bounds__(256) void k_gather(
    const int* __restrict__ base, const int2* __restrict__ edge_s,
    const unsigned short* __restrict__ xw16, unsigned short* __restrict__ agg16) {
  const int lane = threadIdx.x & 63;
  const int n = blockIdx.x * 4 + (threadIdx.x >> 6);
  if (n >= NN) return;
  const int e0 = base[n], e1 = base[n + 1];
  const int c = lane * 2;
  unsigned* ap = (unsigned*)(agg16 + (size_t)n * FD + c);
  unsigned iv = *ap;
  float2 acc = make_float2(bf2f((unsigned short)(iv & 0xffff)),
                           bf2f((unsigned short)(iv >> 16)));
  int e = e0;
  for (; e + 8 <= e1; e += 8) {
#pragma unroll
    for (int q = 0; q < 8; ++q) {
      int2 ed = edge_s[e + q];
      float wv = __int_as_float(ed.y);
      unsigned v = *(const unsigned*)(xw16 + (size_t)ed.x * FD + c);
      acc.x = fmaf(wv, bf2f((unsigned short)(v & 0xffff)), acc.x);
      acc.y = fmaf(wv, bf2f((unsigned short)(v >> 16)), acc.y);
    }
  }
  for (; e < e1; ++e) {
    int2 ed = edge_s[e];
    float wv = __int_as_float(ed.y);
    unsigned v = *(const unsigned*)(xw16 + (size_t)ed.x * FD + c);
    acc.x = fmaf(wv, bf2f((unsigned short)(v & 0xffff)), acc.x);
    acc.y = fmaf(wv, bf2f((unsigned short)(v >> 16)), acc.y);
  }
  *ap = (unsigned)f2bf(acc.x) | ((unsigned)f2bf(acc.y) << 16);
}

// ---------------- fused DCRNN cell (32-row blocks, Ht phase-split) --------
// block = 32 rows, 4 waves. As[32][264] = [bf16(agg)|bf16(hs)].
// Phase 1: ZR GEMM (K=256) + Ht-top (h @ Wh[0:128], K=128 — independent of
//   R, reads only As agg-half). z stays in registers.
// R epilogue: hsr = R*hs overwrites As hs-half.
// Phase 2: Ht-bottom (hsr @ Wh[128:256], K=128). No barrier before the Hn
//   epilogue (phase 2 reads cols 128-255; epilogue writes cols 0-127).
// Hn epilogue: re-reads hs fp32 (L3-hot); relu(Hn) bf16 -> As[:,0:128].
// Classifier: waves 0,1 -> 16 rows each.

__global__ __launch_bounds__(256) void k_cell(
    const short* __restrict__ agg16, const float* __restrict__ hs,
    const short* __restrict__ wtzr, const short* __restrict__ wth,
    const short* __restrict__ wtl, const float* __restrict__ bzp,
    const float* __restrict__ brp, const float* __restrict__ bhp,
    const float* __restrict__ bl, float* __restrict__ probs,
    float* __restrict__ Hn) {
  __shared__ __align__(16) short As[32][264];   // 16.9 KB
  const int tid = threadIdx.x;
  const int w = tid >> 6, l = tid & 63, g = l >> 4, ln = l & 15;
  const int n0 = blockIdx.x * 32;
  const int srow = tid >> 3, sc = (tid & 7) << 2;

  // ---- stage As = [bf16(agg) | bf16(hs)], single barrier ----
  {
    int n = n0 + srow;
#pragma unroll
    for (int kc = 0; kc < 8; ++kc) {
      int kg = kc * 32 + sc;
      s16x4 av = {0, 0, 0, 0};
      if (n < NN) {
        if (kg < FD) {
          av = *(const s16x4*)(agg16 + (size_t)n * FD + kg);
        } else {
          float4 f0 = *(const float4*)(hs + (size_t)n * FD + (kg - FD));
          av[0] = (short)f2bf(f0.x); av[1] = (short)f2bf(f0.y);
          av[2] = (short)f2bf(f0.z); av[3] = (short)f2bf(f0.w);
        }
      }
      *(s16x4*)&As[srow][kg] = av;
    }
  }
  __syncthreads();

  f32x4 zacc[2][2];
  f32x4 acc2[2][2];   // Ht accumulator, fed in both phases
#pragma unroll
  for (int mi = 0; mi < 2; ++mi)
#pragma unroll
    for (int ni = 0; ni < 2; ++ni) acc2[mi][ni] = (f32x4){0.f, 0.f, 0.f, 0.f};

  // ---- phase 1: ZR (K=256) + Ht-top (K=128) ----
  {
    f32x4 acc[2][4];
#pragma unroll
    for (int mi = 0; mi < 2; ++mi)
#pragma unroll
      for (int ni = 0; ni < 4; ++ni) acc[mi][ni] = (f32x4){0.f, 0.f, 0.f, 0.f};
    const s16x8* wtz8 = (const s16x8*)wtzr;  // row = 256 shorts = 32 units
    const s16x8* wth8 = (const s16x8*)wth;
#pragma unroll 2
    for (int kci = 0; kci < 8; ++kci) {
      s16x8 b[4], a[2];
#pragma unroll
      for (int ni = 0; ni < 4; ++ni) {
        int col = (ni < 2) ? (w * 32 + ni * 16 + ln)
                           : (FD + w * 32 + (ni - 2) * 16 + ln);
        b[ni] = wtz8[(size_t)col * 32 + kci * 4 + g];
      }
#pragma unroll
      for (int mi = 0; mi < 2; ++mi)
        a[mi] = *(const s16x8*)&As[mi * 16 + ln][kci * 32 + g * 8];
#pragma unroll
      for (int mi = 0; mi < 2; ++mi)
#pragma unroll
        for (int ni = 0; ni < 4; ++ni)
          acc[mi][ni] = __builtin_amdgcn_mfma_f32_16x16x32_bf16(a[mi], b[ni], acc[mi][ni], 0, 0, 0);
      if (kci < 4) {  // Ht-top: same a fragments, agg half only
        s16x8 b2[2];
#pragma unroll
        for (int ni = 0; ni < 2; ++ni) {
          int col = w * 32 + ni * 16 + ln;
          b2[ni] = wth8[(size_t)col * 32 + kci * 4 + g];
        }
#pragma unroll
        for (int mi = 0; mi < 2; ++mi)
#pragma unroll
          for (int ni = 0; ni < 2; ++ni)
            acc2[mi][ni] = __builtin_amdgcn_mfma_f32_16x16x32_bf16(a[mi], b2[ni], acc2[mi][ni], 0, 0, 0);
      }
    }
    __syncthreads();  // all waves done reading As before hs-half overwrite

    // R epilogue: z -> registers; hsr = r*hs overwrites As[.][128+cc]
    float bz_c[2], br_c[2];
#pragma unroll
    for (int ni = 0; ni < 2; ++ni) {
      bz_c[ni] = bzp[w * 32 + ni * 16 + ln];
      br_c[ni] = brp[w * 32 + ni * 16 + ln];
    }
#pragma unroll
    for (int mi = 0; mi < 2; ++mi) {
#pragma unroll
      for (int r = 0; r < 4; ++r) {
        int row = mi * 16 + g * 4 + r;
#pragma unroll
        for (int ni = 0; ni < 2; ++ni) {
          zacc[mi][ni][r] = fast_sigmoid(acc[mi][ni][r] + bz_c[ni]);
          int cc = w * 32 + ni * 16 + ln;
          float rv = fast_sigmoid(acc[mi][ni + 2][r] + br_c[ni]);
          float hv = bf2f((unsigned short)As[row][FD + cc]);
          As[row][FD + cc] = (short)f2bf(rv * hv);
        }
      }
    }
  }
  __syncthreads();

  // ---- phase 2: Ht-bottom (hsr @ Wh[128:256], K=128) ----
  {
    const s16x8* wt8 = (const s16x8*)wth;
#pragma unroll 2
    for (int kci = 4; kci < 8; ++kci) {
      s16x8 b[2], a[2];
#pragma unroll
      for (int ni = 0; ni < 2; ++ni) {
        int col = w * 32 + ni * 16 + ln;
        b[ni] = wt8[(size_t)col * 32 + kci * 4 + g];
      }
#pragma unroll
      for (int mi = 0; mi < 2; ++mi)
        a[mi] = *(const s16x8*)&As[mi * 16 + ln][kci * 32 + g * 8];
#pragma unroll
      for (int mi = 0; mi < 2; ++mi)
#pragma unroll
        for (int ni = 0; ni < 2; ++ni)
          acc2[mi][ni] = __builtin_amdgcn_mfma_f32_16x16x32_bf16(a[mi], b[ni], acc2[mi][ni], 0, 0, 0);
    }
  }
  // NO barrier: phase 2 reads As cols 128-255; epilogue writes cols 0-127.

  // ---- Hn epilogue: hv re-read from global hs (L3-hot) ----
  {
    float bh_c[2];
#pragma unroll
    for (int ni = 0; ni < 2; ++ni) bh_c[ni] = bhp[w * 32 + ni * 16 + ln];
#pragma unroll
    for (int mi = 0; mi < 2; ++mi) {
#pragma unroll
      for (int r = 0; r < 4; ++r) {
        int row = mi * 16 + g * 4 + r;
        int n = n0 + row;
#pragma unroll
        for (int ni = 0; ni < 2; ++ni) {
          int c = w * 32 + ni * 16 + ln;
          float z = zacc[mi][ni][r];
          float ht = fast_tanh(acc2[mi][ni][r] + bh_c[ni]);
          if (n < NN) {
            float hv = hs[(size_t)n * FD + c];
            float hn = z * hv + (1.f - z) * ht;
            Hn[(size_t)n * FD + c] = hn;
            As[row][c] = (short)f2bf(fmaxf(hn, 0.f));
          } else {
            As[row][c] = 0;
          }
        }
      }
    }
  }
  __syncthreads();

  // ---- classifier: waves 0,1 -> rows [w*16, w*16+16); 16 classes ----
  if (w < 2) {
    f32x4 ac = (f32x4){0.f, 0.f, 0.f, 0.f};
    const s16x8* wtl8 = (const s16x8*)wtl;  // row = 128 shorts = 16 units
#pragma unroll
    for (int kci = 0; kci < 4; ++kci) {
      s16x8 a = *(const s16x8*)&As[w * 16 + ln][kci * 32 + g * 8];
      s16x8 bfr = wtl8[ln * 16 + kci * 4 + g];
      ac = __builtin_amdgcn_mfma_f32_16x16x32_bf16(a, bfr, ac, 0, 0, 0);
    }
    float blv = bl[ln];
#pragma unroll
    for (int r = 0; r < 4; ++r) {
      int n = n0 + w * 16 + g * 4 + r;
      float v = ac[r] + blv;
      float m = v;
#pragma unroll
      for (int msk = 1; msk < 16; msk <<= 1) m = fmaxf(m, __shfl_xor(m, msk, 64));
      float e = exp2f(1.44269504f * (v - m));
      float s = e;
#pragma unroll
      for (int msk = 1; msk < 16; msk <<= 1) s += __shfl_xor(s, msk, 64);
      if (n < NN) probs[(size_t)n * NCLS + ln] = e * __builtin_amdgcn_rcpf(s);
    }
  }
}

// ---------------- launch ----------------

extern "C" void kernel_launch(void* const* d_in, const int* in_sizes, int n_in,
                              void* d_out, int out_size, void* d_ws, size_t ws_size,
                              hipStream_t stream) {
  (void)in_sizes; (void)n_in; (void)out_size; (void)ws_size;
  const float* x   = (const float*)d_in[0];
  const int*   ei  = (const int*)d_in[1];
  const float* ew  = (const float*)d_in[2];
  const float* hs  = (const float*)d_in[3];
  const float* Wg  = (const float*)d_in[4];
  const float* bg  = (const float*)d_in[5];
  const float* Wz0 = (const float*)d_in[6];
  const float* Wz1 = (const float*)d_in[7];
  const float* bz  = (const float*)d_in[8];
  const float* Wr0 = (const float*)d_in[9];
  const float* Wr1 = (const float*)d_in[10];
  const float* br  = (const float*)d_in[11];
  const float* Wh0 = (const float*)d_in[12];
  const float* Wh1 = (const float*)d_in[13];
  const float* bh  = (const float*)d_in[14];
  const float* Wl  = (const float*)d_in[15];
  const float* bl  = (const float*)d_in[16];

  float* out   = (float*)d_out;
  float* probs = out;                      // [NN,16]
  float* Hn    = out + (size_t)NN * NCLS;  // [NN,128]

  float* w    = (float*)d_ws;
  float* dinv = w;                             // [NN]
  short* xw16 = (short*)(w + 50048);           // [NN*FD] bf16
  short* agg16 = (short*)(w + 50048 + (size_t)NN * FD);  // [NN*FD] bf16
  float* hsrf = w + 50048 + 2 * (size_t)NN * FD;         // CSR scratch region
  float* wsp  = hsrf + (size_t)NN * FD;        // tail: bf16 weights + biases

  short* wtzr = (short*)wsp;                       // 65536 shorts
  short* wth  = (short*)(wsp + 32768);             // 32768 shorts
  short* wtg  = (short*)(wsp + 32768 + 16384);     // 16384 shorts
  short* wtl  = (short*)(wsp + 32768 + 16384 + 8192);  // 2048 shorts
  float* bzp  = wsp + 32768 + 16384 + 8192 + 1024;
  float* brp  = bzp + 128;
  float* bhp  = brp + 128;

  // CSR scratch laid out in hsrf region (6.4M floats available):
  int2*  edge_s = (int2*)hsrf;                      // [NE] packed (src, nrm)
  int*   basep = (int*)(hsrf + 2 * NE);             // [NN+1]
  int*   bsum  = (int*)(hsrf + 1650048);            // [SCAN_B]
  int*   boff  = (int*)(hsrf + 1650304);            // [SCAN_B]
  unsigned long long* parts = (unsigned long long*)(hsrf + 1651024);  // [NCOPY*NN]
  int*   off16 = (int*)(hsrf + 3301040);            // [NCOPY*NN]

  k_prep<<<1024, 256, 0, stream>>>(Wz0, Wz1, Wr0, Wr1, Wh0, Wh1, Wg, Wl,
                                   bg, bz, br, bh, wtzr, wth, wtg, wtl,
                                   bzp, brp, bhp, parts);
  k_hist<<<1024, 256, 0, stream>>>(ei + NE, ew, parts);
  k_reduce_scan1<<<SCAN_B, 256, 0, stream>>>(parts, dinv, basep, bsum);
  k_scan2<<<1, 256, 0, stream>>>(bsum, boff, basep);
  k_scan3<<<SCAN_B, 256, 0, stream>>>(basep, boff, parts, off16);
  k_reorder<<<1024, 256, 0, stream>>>(ei, ew, dinv, off16, edge_s);
  k_xw_mfma<<<782, 256, 0, stream>>>(x, wtg, dinv, xw16, agg16);
  k_gather<<<12500, 256, 0, stream>>>(basep, edge_s,
                                      (const unsigned short*)xw16,
                                      (unsigned short*)agg16);
  k_cell<<<1563, 256, 0, stream>>>(agg16, hs, wtzr, wth, wtl, bzp, brp, bhp,
                                   bl, probs, Hn);
}

// Round 16
// 189.868 us; speedup vs baseline: 5.0965x; 1.0764x over previous
//
#include <hip/hip_runtime.h>
#include <math.h>

#define NN 50000
#define NE 800000
#define FD 128
#define CIN 256
#define NCLS 16
#define SCAN_B 196   // ceil(NN/256)
#define NCOPY 16

typedef short s16x8 __attribute__((ext_vector_type(8)));
typedef short s16x4 __attribute__((ext_vector_type(4)));
typedef float f32x4 __attribute__((ext_vector_type(4)));

__device__ __forceinline__ unsigned short f2bf(float f) {
  union { float f; unsigned u; } v; v.f = f;
  unsigned r = v.u + 0x7fffu + ((v.u >> 16) & 1u);
  return (unsigned short)(r >> 16);
}

__device__ __forceinline__ float bf2f(unsigned short h) {
  union { unsigned u; float f; } v; v.u = ((unsigned)h) << 16;
  return v.f;
}

// fast transcendentals: v_exp_f32 computes 2^x; rcp is 1-instr approx
__device__ __forceinline__ float fast_sigmoid(float x) {
  return __builtin_amdgcn_rcpf(1.0f + exp2f(-1.44269504f * x));
}
__device__ __forceinline__ float fast_tanh(float x) {
  return 1.0f - 2.0f * __builtin_amdgcn_rcpf(1.0f + exp2f(2.88539008f * x));
}

// ------- fused prep: zero parts + bf16 weight transpose + bias fold -------

__global__ void k_prep(const float* __restrict__ Wz0, const float* __restrict__ Wz1,
                       const float* __restrict__ Wr0, const float* __restrict__ Wr1,
                       const float* __restrict__ Wh0, const float* __restrict__ Wh1,
                       const float* __restrict__ Wg, const float* __restrict__ Wl,
                       const float* __restrict__ bg, const float* __restrict__ bz,
                       const float* __restrict__ br, const float* __restrict__ bh,
                       short* __restrict__ wtzr, short* __restrict__ wth,
                       short* __restrict__ wtg, short* __restrict__ wtl,
                       float* __restrict__ bzp, float* __restrict__ brp,
                       float* __restrict__ bhp,
                       unsigned long long* __restrict__ parts) {
  int i = blockIdx.x * blockDim.x + threadIdx.x;
  int stride = gridDim.x * blockDim.x;
  for (int j = i; j < NCOPY * NN; j += stride) parts[j] = 0ULL;
  if (i < 65536) {
    int n = i >> 8, k = i & 255;
    float v = (n < 128) ? (Wz0[k * 128 + n] + Wz1[k * 128 + n])
                        : (Wr0[k * 128 + (n - 128)] + Wr1[k * 128 + (n - 128)]);
    wtzr[i] = (short)f2bf(v);
  } else if (i < 98304) {
    int j = i - 65536; int n = j >> 8, k = j & 255;
    wth[j] = (short)f2bf(Wh0[k * 128 + n] + Wh1[k * 128 + n]);
  } else if (i < 114688) {
    int j = i - 98304; int n = j >> 7, k = j & 127;
    wtg[j] = (short)f2bf(Wg[k * 128 + n]);
  } else if (i < 116736) {
    int j = i - 114688; int n = j >> 7, k = j & 127;
    wtl[j] = (short)f2bf(Wl[k * 16 + n]);
  } else if (i < 116864) {
    int c = i - 116736;
    float sz = bz[c], sr = br[c], sh = bh[c];
    for (int k = 0; k < 128; ++k) {
      float gv = bg[k];
      sz += gv * (Wz0[k * 128 + c] + Wz1[k * 128 + c]);
      sr += gv * (Wr0[k * 128 + c] + Wr1[k * 128 + c]);
      sh += gv * (Wh0[k * 128 + c] + Wh1[k * 128 + c]);
    }
    bzp[c] = sz; brp[c] = sr; bhp[c] = sh;
  }
}

// ---------------- CSR build: privatized packed histogram ----------------

__global__ void k_hist(const int* __restrict__ dst, const float* __restrict__ ew,
                       unsigned long long* __restrict__ parts) {
  const int c = blockIdx.x & (NCOPY - 1);
  unsigned long long* __restrict__ p = parts + (size_t)c * NN;
  int i = blockIdx.x * blockDim.x + threadIdx.x;
  int stride = gridDim.x * blockDim.x;
  for (int e = i; e < NE; e += stride) {
    int d = dst[e];
    unsigned long long pk = (1ULL << 40) +
        (unsigned long long)(ew[e] * 4294967296.0f + 0.5f);
    atomicAdd(&p[d], pk);
  }
}

// fused: fold copies -> dinv ; block-local exclusive scan of counts
__global__ __launch_bounds__(256) void k_reduce_scan1(
    const unsigned long long* __restrict__ parts, float* __restrict__ dinv,
    int* __restrict__ base, int* __restrict__ bsum) {
  __shared__ int ts[256];
  const int t = threadIdx.x, b = blockIdx.x;
  const int i = b * 256 + t;
  int ct = 0;
  if (i < NN) {
    double frac = 0.0;
#pragma unroll
    for (int c = 0; c < NCOPY; ++c) {
      unsigned long long v = parts[(size_t)c * NN + i];
      ct += (int)(v >> 40);
      frac += (double)(v & 0xFFFFFFFFFFULL);
    }
    double deg = 1.0 + frac * (1.0 / 4294967296.0);
    dinv[i] = rsqrtf((float)deg);
  }
  ts[t] = ct;
  __syncthreads();
#pragma unroll
  for (int off = 1; off < 256; off <<= 1) {
    int u = (t >= off) ? ts[t - off] : 0;
    __syncthreads();
    ts[t] += u;
    __syncthreads();
  }
  if (i < NN) base[i] = ts[t] - ct;
  if (t == 255) bsum[b] = ts[255];
}

// scan2 folded in: every block redundantly scans bsum[196] in LDS,
// picks its own offset, finalizes base and carves per-copy cursors.
__global__ __launch_bounds__(256) void k_scan23(
    int* __restrict__ base, const int* __restrict__ bsum,
    const unsigned long long* __restrict__ parts, int* __restrict__ off16) {
  __shared__ int ts[256];
  __shared__ int bo;
  const int t = threadIdx.x;
  int v = (t < SCAN_B) ? bsum[t] : 0;
  ts[t] = v;
  __syncthreads();
#pragma unroll
  for (int off = 1; off < 256; off <<= 1) {
    int u = (t >= off) ? ts[t - off] : 0;
    __syncthreads();
    ts[t] += u;
    __syncthreads();
  }
  if (t == blockIdx.x) bo = ts[t] - v;          // boff[blockIdx]
  if (blockIdx.x == 0 && t == 255) base[NN] = ts[255];
  __syncthreads();
  const int boff = bo;
  const int i = blockIdx.x * 256 + t;
  if (i >= NN) return;
  int b = base[i] + boff;
  base[i] = b;
  int run = b;
#pragma unroll
  for (int c = 0; c < NCOPY; ++c) {
    off16[(size_t)c * NN + i] = run;
    run += (int)(parts[(size_t)c * NN + i] >> 40);
  }
}

// scatter edges into dst-sorted order: ONE packed 8B store per edge
// NOTE: grid/stride and c = blockIdx&15 MUST match k_hist exactly
__global__ void k_reorder(const int* __restrict__ ei, const float* __restrict__ ew,
                          const float* __restrict__ dinv,
                          int* __restrict__ off16, int2* __restrict__ edge_s) {
  const int c = blockIdx.x & (NCOPY - 1);
  int* __restrict__ cur = off16 + (size_t)c * NN;
  int i = blockIdx.x * blockDim.x + threadIdx.x;
  int stride = gridDim.x * blockDim.x;
  const int* __restrict__ src = ei;
  const int* __restrict__ dst = ei + NE;
  for (int e = i; e < NE; e += stride) {
    int s = src[e], d = dst[e];
    int pos = atomicAdd(&cur[d], 1);
    float nrm = dinv[s] * ew[e] * dinv[d];
    edge_s[pos] = make_int2(s, __float_as_int(nrm));
  }
}

// ------------- MFMA GEMM: xw16(bf16) = x @ Wg -------------

__global__ __launch_bounds__(256) void k_xw_mfma(
    const float* __restrict__ x, const short* __restrict__ wtg,
    short* __restrict__ xw16) {
  __shared__ __align__(16) short As[64][40];
  const int tid = threadIdx.x;
  const int w = tid >> 6, l = tid & 63, g = l >> 4, ln = l & 15;
  const int n0 = blockIdx.x * 64;
  const int srow = tid >> 2, sk0 = (tid & 3) << 3;
  const s16x8* wt8 = (const s16x8*)wtg;

  f32x4 acc[4][2];
#pragma unroll
  for (int mi = 0; mi < 4; ++mi)
#pragma unroll
    for (int ni = 0; ni < 2; ++ni) acc[mi][ni] = (f32x4){0.f, 0.f, 0.f, 0.f};

  for (int kci = 0; kci < 4; ++kci) {
    int kg = kci * 32 + sk0;
    int n = n0 + srow;
    s16x8 av = {0, 0, 0, 0, 0, 0, 0, 0};
    if (n < NN) {
      const float* src = x + (size_t)n * FD + kg;
      float4 f0 = *(const float4*)src;
      float4 f1 = *(const float4*)(src + 4);
      av[0] = (short)f2bf(f0.x); av[1] = (short)f2bf(f0.y);
      av[2] = (short)f2bf(f0.z); av[3] = (short)f2bf(f0.w);
      av[4] = (short)f2bf(f1.x); av[5] = (short)f2bf(f1.y);
      av[6] = (short)f2bf(f1.z); av[7] = (short)f2bf(f1.w);
    }
    __syncthreads();
    *(s16x8*)&As[srow][sk0] = av;
    __syncthreads();
    s16x8 b[2], a[4];
#pragma unroll
    for (int ni = 0; ni < 2; ++ni) {
      int col = w * 32 + ni * 16 + ln;
      b[ni] = wt8[(size_t)col * 16 + kci * 4 + g];
    }
#pragma unroll
    for (int mi = 0; mi < 4; ++mi) a[mi] = *(const s16x8*)&As[mi * 16 + ln][g * 8];
#pragma unroll
    for (int mi = 0; mi < 4; ++mi)
#pragma unroll
      for (int ni = 0; ni < 2; ++ni)
        acc[mi][ni] = __builtin_amdgcn_mfma_f32_16x16x32_bf16(a[mi], b[ni], acc[mi][ni], 0, 0, 0);
  }
#pragma unroll
  for (int mi = 0; mi < 4; ++mi) {
#pragma unroll
    for (int r = 0; r < 4; ++r) {
      int n = n0 + mi * 16 + g * 4 + r;
      if (n >= NN) continue;
#pragma unroll
      for (int ni = 0; ni < 2; ++ni) {
        int c = w * 32 + ni * 16 + ln;
        xw16[(size_t)n * FD + c] = (short)f2bf(acc[mi][ni][r]);
      }
    }
  }
}

// ------- fused gather + DCRNN cell (32-row blocks, Ht phase-split) --------
// Gather phase: 8 threads/row x 16 feats/thread; acc fp32 in registers:
//   acc = xw[n]*dinv^2 + sum_e nrm*xw[src]; bf16 -> As[:,0:128].
//   hs fp32 -> bf16 As[:,128:256]. One barrier.
// Phase 1: ZR GEMM (K=256) + Ht-top (K=128, agg half). z in registers.
// R epilogue: hsr = R*hs overwrites As hs-half.
// Phase 2: Ht-bottom (K=128, hsr half). No barrier before Hn epilogue
//   (phase 2 reads cols 128-255; epilogue writes cols 0-127).
// Hn epilogue: re-reads hs fp32 (L3-hot); relu(Hn) bf16 -> As[:,0:128].
// Classifier: waves 0,1 -> 16 rows each.

__global__ __launch_bounds__(256) void k_cell(
    const unsigned short* __restrict__ xw16, const float* __restrict__ dinv,
    const int* __restrict__ base, const int2* __restrict__ edge_s,
    const float* __restrict__ hs,
    const short* __restrict__ wtzr, const short* __restrict__ wth,
    const short* __restrict__ wtl, const float* __restrict__ bzp,
    const float* __restrict__ brp, const float* __restrict__ bhp,
    const float* __restrict__ bl, float* __restrict__ probs,
    float* __restrict__ Hn) {
  __shared__ __align__(16) short As[32][264];   // 16.9 KB
  const int tid = threadIdx.x;
  const int w = tid >> 6, l = tid & 63, g = l >> 4, ln = l & 15;
  const int n0 = blockIdx.x * 32;

  // ---- gather phase: row = tid>>3, 16 feats per thread ----
  {
    const int row = tid >> 3;
    const int c0 = (tid & 7) << 4;        // feature start (16 bf16)
    const int n = n0 + row;
    float acc[16];
    if (n < NN) {
      float d = dinv[n];
      float d2 = d * d;
      s16x8 x0 = *(const s16x8*)(xw16 + (size_t)n * FD + c0);
      s16x8 x1 = *(const s16x8*)(xw16 + (size_t)n * FD + c0 + 8);
#pragma unroll
      for (int j = 0; j < 8; ++j) {
        acc[j] = bf2f((unsigned short)x0[j]) * d2;
        acc[8 + j] = bf2f((unsigned short)x1[j]) * d2;
      }
      const int e0 = base[n], e1 = base[n + 1];
      int e = e0;
      for (; e + 2 <= e1; e += 2) {
        int2 eda = edge_s[e], edb = edge_s[e + 1];
        float wa = __int_as_float(eda.y), wb = __int_as_float(edb.y);
        s16x8 v0a = *(const s16x8*)(xw16 + (size_t)eda.x * FD + c0);
        s16x8 v1a = *(const s16x8*)(xw16 + (size_t)eda.x * FD + c0 + 8);
        s16x8 v0b = *(const s16x8*)(xw16 + (size_t)edb.x * FD + c0);
        s16x8 v1b = *(const s16x8*)(xw16 + (size_t)edb.x * FD + c0 + 8);
#pragma unroll
        for (int j = 0; j < 8; ++j) {
          acc[j] = fmaf(wa, bf2f((unsigned short)v0a[j]), acc[j]);
          acc[8 + j] = fmaf(wa, bf2f((unsigned short)v1a[j]), acc[8 + j]);
          acc[j] = fmaf(wb, bf2f((unsigned short)v0b[j]), acc[j]);
          acc[8 + j] = fmaf(wb, bf2f((unsigned short)v1b[j]), acc[8 + j]);
        }
      }
      for (; e < e1; ++e) {
        int2 ed = edge_s[e];
        float wv = __int_as_float(ed.y);
        s16x8 v0 = *(const s16x8*)(xw16 + (size_t)ed.x * FD + c0);
        s16x8 v1 = *(const s16x8*)(xw16 + (size_t)ed.x * FD + c0 + 8);
#pragma unroll
        for (int j = 0; j < 8; ++j) {
          acc[j] = fmaf(wv, bf2f((unsigned short)v0[j]), acc[j]);
          acc[8 + j] = fmaf(wv, bf2f((unsigned short)v1[j]), acc[8 + j]);
        }
      }
    } else {
#pragma unroll
      for (int j = 0; j < 16; ++j) acc[j] = 0.f;
    }
    s16x8 o0, o1;
#pragma unroll
    for (int j = 0; j < 8; ++j) {
      o0[j] = (short)f2bf(acc[j]);
      o1[j] = (short)f2bf(acc[8 + j]);
    }
    *(s16x8*)&As[row][c0] = o0;
    *(s16x8*)&As[row][c0 + 8] = o1;
    // stage hs half: same 16 cols at offset 128
    s16x8 h0 = {0,0,0,0,0,0,0,0}, h1 = {0,0,0,0,0,0,0,0};
    if (n < NN) {
      const float* hp = hs + (size_t)n * FD + c0;
      float4 f0 = *(const float4*)hp;
      float4 f1 = *(const float4*)(hp + 4);
      float4 f2 = *(const float4*)(hp + 8);
      float4 f3 = *(const float4*)(hp + 12);
      h0[0] = (short)f2bf(f0.x); h0[1] = (short)f2bf(f0.y);
      h0[2] = (short)f2bf(f0.z); h0[3] = (short)f2bf(f0.w);
      h0[4] = (short)f2bf(f1.x); h0[5] = (short)f2bf(f1.y);
      h0[6] = (short)f2bf(f1.z); h0[7] = (short)f2bf(f1.w);
      h1[0] = (short)f2bf(f2.x); h1[1] = (short)f2bf(f2.y);
      h1[2] = (short)f2bf(f2.z); h1[3] = (short)f2bf(f2.w);
      h1[4] = (short)f2bf(f3.x); h1[5] = (short)f2bf(f3.y);
      h1[6] = (short)f2bf(f3.z); h1[7] = (short)f2bf(f3.w);
    }
    *(s16x8*)&As[row][FD + c0] = h0;
    *(s16x8*)&As[row][FD + c0 + 8] = h1;
  }
  __syncthreads();

  f32x4 zacc[2][2];
  f32x4 acc2[2][2];   // Ht accumulator, fed in both phases
#pragma unroll
  for (int mi = 0; mi < 2; ++mi)
#pragma unroll
    for (int ni = 0; ni < 2; ++ni) acc2[mi][ni] = (f32x4){0.f, 0.f, 0.f, 0.f};

  // ---- phase 1: ZR (K=256) + Ht-top (K=128) ----
  {
    f32x4 acc[2][4];
#pragma unroll
    for (int mi = 0; mi < 2; ++mi)
#pragma unroll
      for (int ni = 0; ni < 4; ++ni) acc[mi][ni] = (f32x4){0.f, 0.f, 0.f, 0.f};
    const s16x8* wtz8 = (const s16x8*)wtzr;  // row = 256 shorts = 32 units
    const s16x8* wth8 = (const s16x8*)wth;
#pragma unroll 2
    for (int kci = 0; kci < 8; ++kci) {
      s16x8 b[4], a[2];
#pragma unroll
      for (int ni = 0; ni < 4; ++ni) {
        int col = (ni < 2) ? (w * 32 + ni * 16 + ln)
                           : (FD + w * 32 + (ni - 2) * 16 + ln);
        b[ni] = wtz8[(size_t)col * 32 + kci * 4 + g];
      }
#pragma unroll
      for (int mi = 0; mi < 2; ++mi)
        a[mi] = *(const s16x8*)&As[mi * 16 + ln][kci * 32 + g * 8];
#pragma unroll
      for (int mi = 0; mi < 2; ++mi)
#pragma unroll
        for (int ni = 0; ni < 4; ++ni)
          acc[mi][ni] = __builtin_amdgcn_mfma_f32_16x16x32_bf16(a[mi], b[ni], acc[mi][ni], 0, 0, 0);
      if (kci < 4) {  // Ht-top: same a fragments, agg half only
        s16x8 b2[2];
#pragma unroll
        for (int ni = 0; ni < 2; ++ni) {
          int col = w * 32 + ni * 16 + ln;
          b2[ni] = wth8[(size_t)col * 32 + kci * 4 + g];
        }
#pragma unroll
        for (int mi = 0; mi < 2; ++mi)
#pragma unroll
          for (int ni = 0; ni < 2; ++ni)
            acc2[mi][ni] = __builtin_amdgcn_mfma_f32_16x16x32_bf16(a[mi], b2[ni], acc2[mi][ni], 0, 0, 0);
      }
    }
    __syncthreads();  // all waves done reading As before hs-half overwrite

    // R epilogue: z -> registers; hsr = r*hs overwrites As[.][128+cc]
    float bz_c[2], br_c[2];
#pragma unroll
    for (int ni = 0; ni < 2; ++ni) {
      bz_c[ni] = bzp[w * 32 + ni * 16 + ln];
      br_c[ni] = brp[w * 32 + ni * 16 + ln];
    }
#pragma unroll
    for (int mi = 0; mi < 2; ++mi) {
#pragma unroll
      for (int r = 0; r < 4; ++r) {
        int row = mi * 16 + g * 4 + r;
#pragma unroll
        for (int ni = 0; ni < 2; ++ni) {
          zacc[mi][ni][r] = fast_sigmoid(acc[mi][ni][r] + bz_c[ni]);
          int cc = w * 32 + ni * 16 + ln;
          float rv = fast_sigmoid(acc[mi][ni + 2][r] + br_c[ni]);
          float hv = bf2f((unsigned short)As[row][FD + cc]);
          As[row][FD + cc] = (short)f2bf(rv * hv);
        }
      }
    }
  }
  __syncthreads();

  // ---- phase 2: Ht-bottom (hsr @ Wh[128:256], K=128) ----
  {
    const s16x8* wt8 = (const s16x8*)wth;
#pragma unroll 2
    for (int kci = 4; kci < 8; ++kci) {
      s16x8 b[2], a[2];
#pragma unroll
      for (int ni = 0; ni < 2; ++ni) {
        int col = w * 32 + ni * 16 + ln;
        b[ni] = wt8[(size_t)col * 32 + kci * 4 + g];
      }
#pragma unroll
      for (int mi = 0; mi < 2; ++mi)
        a[mi] = *(const s16x8*)&As[mi * 16 + ln][kci * 32 + g * 8];
#pragma unroll
      for (int mi = 0; mi < 2; ++mi)
#pragma unroll
        for (int ni = 0; ni < 2; ++ni)
          acc2[mi][ni] = __builtin_amdgcn_mfma_f32_16x16x32_bf16(a[mi], b[ni], acc2[mi][ni], 0, 0, 0);
    }
  }
  // NO barrier: phase 2 reads As cols 128-255; epilogue writes cols 0-127.

  // ---- Hn epilogue: hv re-read from global hs (L3-hot) ----
  {
    float bh_c[2];
#pragma unroll
    for (int ni = 0; ni < 2; ++ni) bh_c[ni] = bhp[w * 32 + ni * 16 + ln];
#pragma unroll
    for (int mi = 0; mi < 2; ++mi) {
#pragma unroll
      for (int r = 0; r < 4; ++r) {
        int row = mi * 16 + g * 4 + r;
        int n = n0 + row;
#pragma unroll
        for (int ni = 0; ni < 2; ++ni) {
          int c = w * 32 + ni * 16 + ln;
          float z = zacc[mi][ni][r];
          float ht = fast_tanh(acc2[mi][ni][r] + bh_c[ni]);
          if (n < NN) {
            float hv = hs[(size_t)n * FD + c];
            float hn = z * hv + (1.f - z) * ht;
            Hn[(size_t)n * FD + c] = hn;
            As[row][c] = (short)f2bf(fmaxf(hn, 0.f));
          } else {
            As[row][c] = 0;
          }
        }
      }
    }
  }
  __syncthreads();

  // ---- classifier: waves 0,1 -> rows [w*16, w*16+16); 16 classes ----
  if (w < 2) {
    f32x4 ac = (f32x4){0.f, 0.f, 0.f, 0.f};
    const s16x8* wtl8 = (const s16x8*)wtl;  // row = 128 shorts = 16 units
#pragma unroll
    for (int kci = 0; kci < 4; ++kci) {
      s16x8 a = *(const s16x8*)&As[w * 16 + ln][kci * 32 + g * 8];
      s16x8 bfr = wtl8[ln * 16 + kci * 4 + g];
      ac = __builtin_amdgcn_mfma_f32_16x16x32_bf16(a, bfr, ac, 0, 0, 0);
    }
    float blv = bl[ln];
#pragma unroll
    for (int r = 0; r < 4; ++r) {
      int n = n0 + w * 16 + g * 4 + r;
      float v = ac[r] + blv;
      float m = v;
#pragma unroll
      for (int msk = 1; msk < 16; msk <<= 1) m = fmaxf(m, __shfl_xor(m, msk, 64));
      float e = exp2f(1.44269504f * (v - m));
      float s = e;
#pragma unroll
      for (int msk = 1; msk < 16; msk <<= 1) s += __shfl_xor(s, msk, 64);
      if (n < NN) probs[(size_t)n * NCLS + ln] = e * __builtin_amdgcn_rcpf(s);
    }
  }
}

// ---------------- launch ----------------

extern "C" void kernel_launch(void* const* d_in, const int* in_sizes, int n_in,
                              void* d_out, int out_size, void* d_ws, size_t ws_size,
                              hipStream_t stream) {
  (void)in_sizes; (void)n_in; (void)out_size; (void)ws_size;
  const float* x   = (const float*)d_in[0];
  const int*   ei  = (const int*)d_in[1];
  const float* ew  = (const float*)d_in[2];
  const float* hs  = (const float*)d_in[3];
  const float* Wg  = (const float*)d_in[4];
  const float* bg  = (const float*)d_in[5];
  const float* Wz0 = (const float*)d_in[6];
  const float* Wz1 = (const float*)d_in[7];
  const float* bz  = (const float*)d_in[8];
  const float* Wr0 = (const float*)d_in[9];
  const float* Wr1 = (const float*)d_in[10];
  const float* br  = (const float*)d_in[11];
  const float* Wh0 = (const float*)d_in[12];
  const float* Wh1 = (const float*)d_in[13];
  const float* bh  = (const float*)d_in[14];
  const float* Wl  = (const float*)d_in[15];
  const float* bl  = (const float*)d_in[16];

  float* out   = (float*)d_out;
  float* probs = out;                      // [NN,16]
  float* Hn    = out + (size_t)NN * NCLS;  // [NN,128]

  float* w    = (float*)d_ws;
  float* dinv = w;                             // [NN]
  short* xw16 = (short*)(w + 50048);           // [NN*FD] bf16
  float* hsrf = w + 50048 + 2 * (size_t)NN * FD;         // CSR scratch region
  float* wsp  = hsrf + (size_t)NN * FD;        // tail: bf16 weights + biases

  short* wtzr = (short*)wsp;                       // 65536 shorts
  short* wth  = (short*)(wsp + 32768);             // 32768 shorts
  short* wtg  = (short*)(wsp + 32768 + 16384);     // 16384 shorts
  short* wtl  = (short*)(wsp + 32768 + 16384 + 8192);  // 2048 shorts
  float* bzp  = wsp + 32768 + 16384 + 8192 + 1024;
  float* brp  = bzp + 128;
  float* bhp  = brp + 128;

  // CSR scratch laid out in hsrf region (6.4M floats available):
  int2*  edge_s = (int2*)hsrf;                      // [NE] packed (src, nrm)
  int*   basep = (int*)(hsrf + 2 * NE);             // [NN+1]
  int*   bsum  = (int*)(hsrf + 1650048);            // [SCAN_B]
  unsigned long long* parts = (unsigned long long*)(hsrf + 1651024);  // [NCOPY*NN]
  int*   off16 = (int*)(hsrf + 3301040);            // [NCOPY*NN]

  k_prep<<<1024, 256, 0, stream>>>(Wz0, Wz1, Wr0, Wr1, Wh0, Wh1, Wg, Wl,
                                   bg, bz, br, bh, wtzr, wth, wtg, wtl,
                                   bzp, brp, bhp, parts);
  k_hist<<<1024, 256, 0, stream>>>(ei + NE, ew, parts);
  k_reduce_scan1<<<SCAN_B, 256, 0, stream>>>(parts, dinv, basep, bsum);
  k_scan23<<<SCAN_B, 256, 0, stream>>>(basep, bsum, parts, off16);
  k_reorder<<<1024, 256, 0, stream>>>(ei, ew, dinv, off16, edge_s);
  k_xw_mfma<<<782, 256, 0, stream>>>(x, wtg, xw16);
  k_cell<<<1563, 256, 0, stream>>>((const unsigned short*)xw16, dinv, basep,
                                   edge_s, hs, wtzr, wth, wtl, bzp, brp, bhp,
                                   bl, probs, Hn);
}